// Round 1
// 1641.363 us; speedup vs baseline: 1.1780x; 1.1780x over previous
//
#include <hip/hip_runtime.h>

#define NN 50000
#define EE 1600000

using u16 = unsigned short;
using u32 = unsigned int;

typedef float f32x4 __attribute__((ext_vector_type(4)));
typedef __bf16 bf16x8 __attribute__((ext_vector_type(8)));
typedef unsigned short u16x8 __attribute__((ext_vector_type(8)));

struct alignas(8) U16x4 { u16 a, b, c, d; };
struct PtrTab { const void* p[20]; };

// canonical fp32 weight-pad offsets
#define OW1 0
#define OB1 768
#define OG 896
#define OBB 1024
#define ORM 1152
#define ORV 1280
#define OW2 1408
#define OB2 17792
#define OCH0 17920
#define OCH1 42496
#define OCH2 54784
#define OCH3 67072
#define OCW1 79360
#define OCB1 144896
#define OCG 145152
#define OCBB 145408
#define OCRM 145664
#define OCRV 145920
#define OCW2 146176
#define OCB2 146688
#define OTOT 146690

// element offsets within d_out (dtype-independent in elements)
#define LG_OFF ((size_t)NN * 256)
#define EW_OFF ((size_t)NN * 256 + (size_t)NN * 2)

__device__ __forceinline__ float bf2f(u16 u) { return __builtin_bit_cast(float, (u32)u << 16); }
__device__ __forceinline__ float bfl(u32 u) { return __builtin_bit_cast(float, u << 16); }
__device__ __forceinline__ float bfh(u32 u) { return __builtin_bit_cast(float, u & 0xffff0000u); }
__device__ __forceinline__ u16 f2bf(float f) {
    u32 u = __builtin_bit_cast(u32, f);
    return (u16)((u + 0x7fffu + ((u >> 16) & 1u)) >> 16);
}

// Input dtype detector: flag=1 -> bf16 inputs, 0 -> fp32 inputs.
__global__ __launch_bounds__(256) void k_detect(const u16* __restrict__ f, int* __restrict__ flag) {
    __shared__ int bad;
    if (threadIdx.x == 0) bad = 0;
    __syncthreads();
    u16 u = f[threadIdx.x];
    int e = (u >> 7) & 0xFF;
    if (e >= 0x90) atomicAdd(&bad, 1);
    __syncthreads();
    if (threadIdx.x == 0) flag[0] = (bad < 16) ? 1 : 0;
}

// Convert all 20 weight arrays into canonical fp32 pad.
__global__ __launch_bounds__(256) void k_wconv(PtrTab tab, const int* __restrict__ flag,
                                               float* __restrict__ wpad) {
    const int SZ[20] = {768, 128, 128, 128, 128, 128, 16384, 128, 24576, 12288, 12288, 12288,
                        65536, 256, 256, 256, 256, 256, 512, 2};
    const int OF[20] = {OW1, OB1, OG, OBB, ORM, ORV, OW2, OB2, OCH0, OCH1, OCH2, OCH3,
                        OCW1, OCB1, OCG, OCBB, OCRM, OCRV, OCW2, OCB2};
    int a = blockIdx.x;
    int n = SZ[a];
    float* dst = wpad + OF[a];
    if (flag[0] != 0) {
        const u16* s = (const u16*)tab.p[a];
        for (int i = threadIdx.x; i < n; i += 256) dst[i] = bf2f(s[i]);
    } else {
        const float* s = (const float*)tab.p[a];
        for (int i = threadIdx.x; i < n; i += 256) dst[i] = s[i];
    }
}

// Fold PAE BN into W2 (MFMA B-frag swizzled bf16) + b2'.
__global__ __launch_bounds__(128) void k_fold(const float* __restrict__ wpad,
                                              u16* __restrict__ W2s, float* __restrict__ b2p) {
    const float* g = wpad + OG;
    const float* b = wpad + OBB;
    const float* rm = wpad + ORM;
    const float* rv = wpad + ORV;
    const float* w2 = wpad + OW2;
    const float* b2 = wpad + OB2;
    int blk = blockIdx.x, tid = threadIdx.x;
    if (blk < 32) {
        int kc = blk >> 3, jt = blk & 7;
        int lane = tid & 63, jh = tid >> 6;
        for (int jj = 0; jj < 4; jj++) {
            int j = jh * 4 + jj;
            int k = kc * 32 + (lane >> 4) * 8 + j;
            int jcol = jt * 16 + (lane & 15);
            float s = g[k] * rsqrtf(rv[k] + 1e-5f);
            W2s[((kc * 8 + jt) * 64 + lane) * 8 + j] = f2bf(s * w2[k * 128 + jcol]);
        }
    } else {
        if (tid < 128) {
            int j = tid;
            float acc = b2[j];
            for (int k = 0; k < 128; k++) {
                float s = g[k] * rsqrtf(rv[k] + 1e-5f);
                float t = b[k] - rm[k] * s;
                acc += t * w2[k * 128 + j];
            }
            b2p[j] = acc;
        }
    }
}

// features (either dtype) -> bf16 X0.
__global__ __launch_bounds__(256) void k_x0(const void* __restrict__ feat, const int* __restrict__ flag,
                                            u16* __restrict__ X0) {
    int i = blockIdx.x * 256 + threadIdx.x;
    if (flag[0] != 0) {
        ((uint4*)X0)[i] = ((const uint4*)feat)[i];
    } else {
        const float4* f = (const float4*)feat;
        float4 a = f[2 * i], b = f[2 * i + 1];
        u16x8 o;
        o[0] = f2bf(a.x); o[1] = f2bf(a.y); o[2] = f2bf(a.z); o[3] = f2bf(a.w);
        o[4] = f2bf(b.x); o[5] = f2bf(b.y); o[6] = f2bf(b.z); o[7] = f2bf(b.w);
        ((uint4*)X0)[i] = __builtin_bit_cast(uint4, o);
    }
}

// PAE: A = relu(Z@W1+b1) on VALU (fragments staged once), H = A@W2' via MFMA.
// v2 changes vs baseline (558us @ 11.7% occupancy, 39.5% VALUBusy):
//  - __launch_bounds__(256,3): VGPR 216 -> <=168, 2 -> 3 waves/SIMD; grid 768
//    = 256 CU x 3 blocks, fully resident persistent shape (no tail wave).
//  - software-pipelined Z loads (prefetch next group as 3x uint2/float4) and
//    hoisted ei[] row loads: the per-iteration global-load stall is hidden.
//  - W1 restaged k-major [k][8] (6 w + bias + pad), 2x ds_read_b128 per k
//    (was 6x ds_read_b32), XOR-swizzled by quad<<4 so the 4 quads (k stride 8
//    -> same bank set) hit disjoint bank groups.
//  - layer-1 bf16 pack via v_cvt_pk_bf16_f32 (1 inst / pair, same RNE
//    rounding as the integer f2bf sequence it replaces).
// jt loop still NOT unrolled: full unroll hoisted all 32 ds_read B-fragments
// (128 VGPRs) -> spill (earlier rounds).
__global__ __launch_bounds__(256, 3) void k_pae(const void* __restrict__ zin, const float* __restrict__ wpad,
                                                const u16* __restrict__ W2sg, const float* __restrict__ b2p,
                                                const int* __restrict__ ei, const int* __restrict__ flag,
                                                float* __restrict__ ewf, void* __restrict__ dout,
                                                float* __restrict__ deg, int* __restrict__ cnt) {
    __shared__ __align__(16) u16 sW2[16384];
    __shared__ __align__(16) float sW1k[1024];  // float m of row k at byte (k*32+m*4)^(((k>>3)&3)<<4)
    __shared__ float sB2[128];
    int tid = threadIdx.x;
    for (int i = tid; i < 8192; i += 256) ((u32*)sW2)[i] = ((const u32*)W2sg)[i];
    for (int i = tid; i < 1024; i += 256) {
        int k = i >> 3, m = i & 7;
        float v = 0.f;
        if (m < 6) v = wpad[OW1 + m * 128 + k];
        else if (m == 6) v = wpad[OB1 + k];
        int sw = ((k >> 3) & 3) << 4;
        *(float*)((char*)sW1k + ((k * 32 + m * 4) ^ sw)) = v;
    }
    if (tid < 128) sB2[tid] = b2p[tid];
    __syncthreads();

    bool isbf = flag[0] != 0;
    int wv = __builtin_amdgcn_readfirstlane(tid >> 6);
    int lane = tid & 63;
    int quad = lane >> 4, lrow = lane & 15, jc = lane & 15;
    int sq = quad << 4;  // sW1k swizzle constant for this lane's k range
    int gw = blockIdx.x * 4 + wv;
    const int ngroups = EE / 16;
    const int gstep = gridDim.x * 4;

    uint2 pb0, pb1, pb2;       // bf16 Z prefetch (24B row)
    float4 pf0, pf1, pf2;      // fp32 Z prefetch (48B row)
    if (gw < ngroups) {
        if (isbf) {
            const uint2* zp = (const uint2*)((const u16*)zin + (size_t)(gw * 16 + lrow) * 12);
            pb0 = zp[0]; pb1 = zp[1]; pb2 = zp[2];
        } else {
            const float4* zp = (const float4*)((const float*)zin + (size_t)(gw * 16 + lrow) * 12);
            pf0 = zp[0]; pf1 = zp[1]; pf2 = zp[2];
        }
    }

#pragma unroll 1
    for (int gidx = gw; gidx < ngroups; gidx += gstep) {
        int e0 = gidx * 16;
        float z1[6], z2[6];
        if (isbf) {
            z1[0] = bfl(pb0.x); z1[1] = bfh(pb0.x); z1[2] = bfl(pb0.y); z1[3] = bfh(pb0.y);
            z1[4] = bfl(pb1.x); z1[5] = bfh(pb1.x);
            z2[0] = bfl(pb1.y); z2[1] = bfh(pb1.y); z2[2] = bfl(pb2.x); z2[3] = bfh(pb2.x);
            z2[4] = bfl(pb2.y); z2[5] = bfh(pb2.y);
        } else {
            z1[0] = pf0.x; z1[1] = pf0.y; z1[2] = pf0.z; z1[3] = pf0.w; z1[4] = pf1.x; z1[5] = pf1.y;
            z2[0] = pf1.z; z2[1] = pf1.w; z2[2] = pf2.x; z2[3] = pf2.y; z2[4] = pf2.z; z2[5] = pf2.w;
        }
        // issue next group's Z loads now -- they complete under this group's compute
        int gn = gidx + gstep;
        if (gn < ngroups) {
            if (isbf) {
                const uint2* zp = (const uint2*)((const u16*)zin + (size_t)(gn * 16 + lrow) * 12);
                pb0 = zp[0]; pb1 = zp[1]; pb2 = zp[2];
            } else {
                const float4* zp = (const float4*)((const float*)zin + (size_t)(gn * 16 + lrow) * 12);
                pf0 = zp[0]; pf1 = zp[1]; pf2 = zp[2];
            }
        }
        // hoist epilogue row indices (were a cold global load after the MFMA loop)
        int rows[4];
        if (jc == 0) {
#pragma unroll
            for (int r = 0; r < 4; r++) rows[r] = ei[e0 + quad * 4 + r];
        }

        // Stage A fragments for all 4 kc chunks (32 VGPRs total)
        bf16x8 a1f[4], a2f[4];
#pragma unroll
        for (int kc = 0; kc < 4; kc++) {
            int kbase = kc * 32 + quad * 8;
            u32 r1[4], r2[4];
#pragma unroll
            for (int jh = 0; jh < 4; jh++) {
                int k = kbase + 2 * jh;
                const char* bp = (const char*)sW1k;
                float4 wa = *(const float4*)(bp + ((k * 32) ^ sq));
                float4 wb = *(const float4*)(bp + ((k * 32 + 16) ^ sq));
                float4 wc = *(const float4*)(bp + (((k + 1) * 32) ^ sq));
                float4 wd = *(const float4*)(bp + (((k + 1) * 32 + 16) ^ sq));
                float sA1 = wb.z, sA2 = wb.z, sB1 = wd.z, sB2v = wd.z;
                sA1 = fmaf(z1[0], wa.x, sA1); sA2 = fmaf(z2[0], wa.x, sA2);
                sA1 = fmaf(z1[1], wa.y, sA1); sA2 = fmaf(z2[1], wa.y, sA2);
                sA1 = fmaf(z1[2], wa.z, sA1); sA2 = fmaf(z2[2], wa.z, sA2);
                sA1 = fmaf(z1[3], wa.w, sA1); sA2 = fmaf(z2[3], wa.w, sA2);
                sA1 = fmaf(z1[4], wb.x, sA1); sA2 = fmaf(z2[4], wb.x, sA2);
                sA1 = fmaf(z1[5], wb.y, sA1); sA2 = fmaf(z2[5], wb.y, sA2);
                sB1 = fmaf(z1[0], wc.x, sB1); sB2v = fmaf(z2[0], wc.x, sB2v);
                sB1 = fmaf(z1[1], wc.y, sB1); sB2v = fmaf(z2[1], wc.y, sB2v);
                sB1 = fmaf(z1[2], wc.z, sB1); sB2v = fmaf(z2[2], wc.z, sB2v);
                sB1 = fmaf(z1[3], wc.w, sB1); sB2v = fmaf(z2[3], wc.w, sB2v);
                sB1 = fmaf(z1[4], wd.x, sB1); sB2v = fmaf(z2[4], wd.x, sB2v);
                sB1 = fmaf(z1[5], wd.y, sB1); sB2v = fmaf(z2[5], wd.y, sB2v);
                sA1 = fmaxf(sA1, 0.f); sA2 = fmaxf(sA2, 0.f);
                sB1 = fmaxf(sB1, 0.f); sB2v = fmaxf(sB2v, 0.f);
                u32 o1, o2;
                asm("v_cvt_pk_bf16_f32 %0, %1, %2" : "=v"(o1) : "v"(sA1), "v"(sB1));
                asm("v_cvt_pk_bf16_f32 %0, %1, %2" : "=v"(o2) : "v"(sA2), "v"(sB2v));
                r1[jh] = o1; r2[jh] = o2;
            }
            uint4 u1v = {r1[0], r1[1], r1[2], r1[3]};
            uint4 u2v = {r2[0], r2[1], r2[2], r2[3]};
            a1f[kc] = __builtin_bit_cast(bf16x8, u1v);
            a2f[kc] = __builtin_bit_cast(bf16x8, u2v);
        }

        float num[4] = {0, 0, 0, 0}, q1[4] = {0, 0, 0, 0}, q2[4] = {0, 0, 0, 0};
        // jt NOT unrolled (see header comment): keeps ds_read hoisting bounded.
#pragma unroll 1
        for (int jt = 0; jt < 8; jt++) {
            f32x4 acc1 = {0.f, 0.f, 0.f, 0.f}, acc2 = {0.f, 0.f, 0.f, 0.f};
#pragma unroll
            for (int kc = 0; kc < 4; kc++) {
                bf16x8 bb = *reinterpret_cast<const bf16x8*>(&sW2[((kc * 8 + jt) * 64 + lane) * 8]);
                acc1 = __builtin_amdgcn_mfma_f32_16x16x32_bf16(a1f[kc], bb, acc1, 0, 0, 0);
                acc2 = __builtin_amdgcn_mfma_f32_16x16x32_bf16(a2f[kc], bb, acc2, 0, 0, 0);
            }
            float bbias = sB2[jt * 16 + jc];
#pragma unroll
            for (int r = 0; r < 4; r++) {
                float h1 = acc1[r] + bbias;
                float h2 = acc2[r] + bbias;
                num[r] = fmaf(h1, h2, num[r]);
                q1[r] = fmaf(h1, h1, q1[r]);
                q2[r] = fmaf(h2, h2, q2[r]);
            }
        }
#pragma unroll
        for (int off = 1; off < 16; off <<= 1) {
#pragma unroll
            for (int r = 0; r < 4; r++) {
                num[r] += __shfl_xor(num[r], off);
                q1[r] += __shfl_xor(q1[r], off);
                q2[r] += __shfl_xor(q2[r], off);
            }
        }
        if (jc == 0) {
#pragma unroll
            for (int r = 0; r < 4; r++) {
                int e = e0 + quad * 4 + r;
                float den = fmaxf(sqrtf(q1[r]) * sqrtf(q2[r]), 1e-8f);
                float wgt = (num[r] / den + 1.f) * 0.5f;
                if (!(wgt == wgt)) wgt = 0.5f;  // NaN guard: makes failures localizable
                ewf[e] = wgt;
                if (isbf) ((u16*)dout)[EW_OFF + e] = f2bf(wgt);
                else ((float*)dout)[EW_OFF + e] = wgt;
                atomicAdd(deg + rows[r], wgt);
                atomicAdd(cnt + rows[r], 1);
            }
        }
    }
}

// Exclusive scan of cnt -> offs; fused dis = rsqrt(deg).
__global__ __launch_bounds__(1024) void k_scan(const int* __restrict__ cnt, const float* __restrict__ deg,
                                               int* __restrict__ offs, float* __restrict__ dis) {
    __shared__ int wsum[16];
    __shared__ int carry;
    int tid = threadIdx.x;
    int wv = tid >> 6, lane = tid & 63;
    if (tid == 0) carry = 0;
    __syncthreads();
    for (int c = 0; c < 49; c++) {
        int i = c * 1024 + tid;
        int v = (i < NN) ? cnt[i] : 0;
        if (i < NN) {
            float d = deg[i];
            dis[i] = d > 0.f ? rsqrtf(d) : 0.f;
        }
        int x = v;
#pragma unroll
        for (int off = 1; off < 64; off <<= 1) {
            int t = __shfl_up(x, off);
            if (lane >= off) x += t;
        }
        if (lane == 63) wsum[wv] = x;
        __syncthreads();
        if (tid < 16) {
            int s = wsum[tid];
#pragma unroll
            for (int off = 1; off < 16; off <<= 1) {
                int t = __shfl_up(s, off, 16);
                if (tid >= off) s += t;
            }
            wsum[tid] = s;
        }
        __syncthreads();
        int base = carry + (wv > 0 ? wsum[wv - 1] : 0);
        if (i < NN) offs[i] = base + x - v;
        __syncthreads();
        if (tid == 0) carry += wsum[15];
        __syncthreads();
    }
    if (tid == 0) offs[NN] = carry;
}

// CSR scatter: fused (col, norm) uint2 metadata — one 8B load per edge in prop.
__global__ __launch_bounds__(256) void k_csr(const int* __restrict__ ei, const float* __restrict__ ewf,
                                             const float* __restrict__ dis, const int* __restrict__ offs,
                                             int* __restrict__ cursor, uint2* __restrict__ csr_meta) {
    int e = blockIdx.x * 256 + threadIdx.x;
    int r = ei[e], c = ei[EE + e];
    float wgt = ewf[e];
    int pos = offs[r] + atomicAdd(cursor + r, 1);
    float nrm = -dis[r] * wgt * dis[c];
    csr_meta[pos] = make_uint2((u32)c, __builtin_bit_cast(u32, nrm));
}

// Propagation over bf16 node features, fp32 accumulate. One wave per node.
// F=128: 16 lanes/edge (uint4), 8 edges in flight. F=64: 8 lanes/edge (uint4),
// 16 edges in flight (was 16 lanes x uint2 -> half the VMEM instructions).
template <int F>
__global__ __launch_bounds__(256) void k_prop(const u16* __restrict__ src, const uint2* __restrict__ csr_meta,
                                              const int* __restrict__ offs,
                                              u16* __restrict__ out, const u16* __restrict__ base,
                                              float alpha, float beta) {
    int lane = threadIdx.x & 63;
    int wv = threadIdx.x >> 6;
    int node = blockIdx.x * 4 + wv;
    int s = offs[node], e = offs[node + 1];

    if (F == 128) {
        int sub = lane >> 4;   // which of 4 edges this lane group handles
        int fl = lane & 15;    // position within the feature row
        const uint4* sv = (const uint4*)src;  // row = 16 uint4 (128 bf16)
        float a[8] = {0, 0, 0, 0, 0, 0, 0, 0};
        int p = s;
        for (; p + 7 < e; p += 8) {
            uint2 m0 = csr_meta[p + sub];
            uint2 m1 = csr_meta[p + 4 + sub];
            uint4 v0 = sv[(size_t)m0.x * 16 + fl];
            uint4 v1 = sv[(size_t)m1.x * 16 + fl];
            float w0 = __builtin_bit_cast(float, m0.y);
            float w1 = __builtin_bit_cast(float, m1.y);
            a[0] = fmaf(w0, bfl(v0.x), a[0]); a[1] = fmaf(w0, bfh(v0.x), a[1]);
            a[2] = fmaf(w0, bfl(v0.y), a[2]); a[3] = fmaf(w0, bfh(v0.y), a[3]);
            a[4] = fmaf(w0, bfl(v0.z), a[4]); a[5] = fmaf(w0, bfh(v0.z), a[5]);
            a[6] = fmaf(w0, bfl(v0.w), a[6]); a[7] = fmaf(w0, bfh(v0.w), a[7]);
            a[0] = fmaf(w1, bfl(v1.x), a[0]); a[1] = fmaf(w1, bfh(v1.x), a[1]);
            a[2] = fmaf(w1, bfl(v1.y), a[2]); a[3] = fmaf(w1, bfh(v1.y), a[3]);
            a[4] = fmaf(w1, bfl(v1.z), a[4]); a[5] = fmaf(w1, bfh(v1.z), a[5]);
            a[6] = fmaf(w1, bfl(v1.w), a[6]); a[7] = fmaf(w1, bfh(v1.w), a[7]);
        }
        if (p + 3 < e) {
            uint2 m0 = csr_meta[p + sub];
            uint4 v0 = sv[(size_t)m0.x * 16 + fl];
            float w0 = __builtin_bit_cast(float, m0.y);
            a[0] = fmaf(w0, bfl(v0.x), a[0]); a[1] = fmaf(w0, bfh(v0.x), a[1]);
            a[2] = fmaf(w0, bfl(v0.y), a[2]); a[3] = fmaf(w0, bfh(v0.y), a[3]);
            a[4] = fmaf(w0, bfl(v0.z), a[4]); a[5] = fmaf(w0, bfh(v0.z), a[5]);
            a[6] = fmaf(w0, bfl(v0.w), a[6]); a[7] = fmaf(w0, bfh(v0.w), a[7]);
            p += 4;
        }
#pragma unroll
        for (int i = 0; i < 8; i++) {
            a[i] += __shfl_xor(a[i], 16);
            a[i] += __shfl_xor(a[i], 32);
        }
        if (sub == 0) {
            for (; p < e; p++) {
                uint2 m0 = csr_meta[p];
                uint4 v = sv[(size_t)m0.x * 16 + fl];
                float w = __builtin_bit_cast(float, m0.y);
                a[0] = fmaf(w, bfl(v.x), a[0]); a[1] = fmaf(w, bfh(v.x), a[1]);
                a[2] = fmaf(w, bfl(v.y), a[2]); a[3] = fmaf(w, bfh(v.y), a[3]);
                a[4] = fmaf(w, bfl(v.z), a[4]); a[5] = fmaf(w, bfh(v.z), a[5]);
                a[6] = fmaf(w, bfl(v.w), a[6]); a[7] = fmaf(w, bfh(v.w), a[7]);
            }
            float o[8];
#pragma unroll
            for (int i = 0; i < 8; i++) o[i] = alpha * a[i];
            if (beta != 0.f) {
                uint4 bv = ((const uint4*)base)[(size_t)node * 16 + fl];
                o[0] = fmaf(beta, bfl(bv.x), o[0]); o[1] = fmaf(beta, bfh(bv.x), o[1]);
                o[2] = fmaf(beta, bfl(bv.y), o[2]); o[3] = fmaf(beta, bfh(bv.y), o[3]);
                o[4] = fmaf(beta, bfl(bv.z), o[4]); o[5] = fmaf(beta, bfh(bv.z), o[5]);
                o[6] = fmaf(beta, bfl(bv.w), o[6]); o[7] = fmaf(beta, bfh(bv.w), o[7]);
            }
            uint4 ov;
            ov.x = (u32)f2bf(o[0]) | ((u32)f2bf(o[1]) << 16);
            ov.y = (u32)f2bf(o[2]) | ((u32)f2bf(o[3]) << 16);
            ov.z = (u32)f2bf(o[4]) | ((u32)f2bf(o[5]) << 16);
            ov.w = (u32)f2bf(o[6]) | ((u32)f2bf(o[7]) << 16);
            ((uint4*)out)[(size_t)node * 16 + fl] = ov;
        }
    } else {
        int sub = lane >> 3;   // which of 8 edges this lane group handles
        int fl = lane & 7;     // position within the feature row (uint4 units)
        const uint4* sv = (const uint4*)src;  // row = 8 uint4 (64 bf16)
        float a[8] = {0, 0, 0, 0, 0, 0, 0, 0};
        int p = s;
        for (; p + 15 < e; p += 16) {
            uint2 m0 = csr_meta[p + sub];
            uint2 m1 = csr_meta[p + 8 + sub];
            uint4 v0 = sv[(size_t)m0.x * 8 + fl];
            uint4 v1 = sv[(size_t)m1.x * 8 + fl];
            float w0 = __builtin_bit_cast(float, m0.y);
            float w1 = __builtin_bit_cast(float, m1.y);
            a[0] = fmaf(w0, bfl(v0.x), a[0]); a[1] = fmaf(w0, bfh(v0.x), a[1]);
            a[2] = fmaf(w0, bfl(v0.y), a[2]); a[3] = fmaf(w0, bfh(v0.y), a[3]);
            a[4] = fmaf(w0, bfl(v0.z), a[4]); a[5] = fmaf(w0, bfh(v0.z), a[5]);
            a[6] = fmaf(w0, bfl(v0.w), a[6]); a[7] = fmaf(w0, bfh(v0.w), a[7]);
            a[0] = fmaf(w1, bfl(v1.x), a[0]); a[1] = fmaf(w1, bfh(v1.x), a[1]);
            a[2] = fmaf(w1, bfl(v1.y), a[2]); a[3] = fmaf(w1, bfh(v1.y), a[3]);
            a[4] = fmaf(w1, bfl(v1.z), a[4]); a[5] = fmaf(w1, bfh(v1.z), a[5]);
            a[6] = fmaf(w1, bfl(v1.w), a[6]); a[7] = fmaf(w1, bfh(v1.w), a[7]);
        }
        if (p + 7 < e) {
            uint2 m0 = csr_meta[p + sub];
            uint4 v0 = sv[(size_t)m0.x * 8 + fl];
            float w0 = __builtin_bit_cast(float, m0.y);
            a[0] = fmaf(w0, bfl(v0.x), a[0]); a[1] = fmaf(w0, bfh(v0.x), a[1]);
            a[2] = fmaf(w0, bfl(v0.y), a[2]); a[3] = fmaf(w0, bfh(v0.y), a[3]);
            a[4] = fmaf(w0, bfl(v0.z), a[4]); a[5] = fmaf(w0, bfh(v0.z), a[5]);
            a[6] = fmaf(w0, bfl(v0.w), a[6]); a[7] = fmaf(w0, bfh(v0.w), a[7]);
            p += 8;
        }
#pragma unroll
        for (int i = 0; i < 8; i++) {
            a[i] += __shfl_xor(a[i], 8);
            a[i] += __shfl_xor(a[i], 16);
            a[i] += __shfl_xor(a[i], 32);
        }
        if (sub == 0) {
            for (; p < e; p++) {
                uint2 m0 = csr_meta[p];
                uint4 v = sv[(size_t)m0.x * 8 + fl];
                float w = __builtin_bit_cast(float, m0.y);
                a[0] = fmaf(w, bfl(v.x), a[0]); a[1] = fmaf(w, bfh(v.x), a[1]);
                a[2] = fmaf(w, bfl(v.y), a[2]); a[3] = fmaf(w, bfh(v.y), a[3]);
                a[4] = fmaf(w, bfl(v.z), a[4]); a[5] = fmaf(w, bfh(v.z), a[5]);
                a[6] = fmaf(w, bfl(v.w), a[6]); a[7] = fmaf(w, bfh(v.w), a[7]);
            }
            float o[8];
#pragma unroll
            for (int i = 0; i < 8; i++) o[i] = alpha * a[i];
            if (beta != 0.f) {
                uint4 bv = ((const uint4*)base)[(size_t)node * 8 + fl];
                o[0] = fmaf(beta, bfl(bv.x), o[0]); o[1] = fmaf(beta, bfh(bv.x), o[1]);
                o[2] = fmaf(beta, bfl(bv.y), o[2]); o[3] = fmaf(beta, bfh(bv.y), o[3]);
                o[4] = fmaf(beta, bfl(bv.z), o[4]); o[5] = fmaf(beta, bfh(bv.z), o[5]);
                o[6] = fmaf(beta, bfl(bv.w), o[6]); o[7] = fmaf(beta, bfh(bv.w), o[7]);
            }
            uint4 ov;
            ov.x = (u32)f2bf(o[0]) | ((u32)f2bf(o[1]) << 16);
            ov.y = (u32)f2bf(o[2]) | ((u32)f2bf(o[3]) << 16);
            ov.z = (u32)f2bf(o[4]) | ((u32)f2bf(o[5]) << 16);
            ov.w = (u32)f2bf(o[6]) | ((u32)f2bf(o[7]) << 16);
            ((uint4*)out)[(size_t)node * 8 + fl] = ov;
        }
    }
}

// ChebConv mix -> bf16 h + jk slice (out dtype).
template <int F>
__global__ __launch_bounds__(256) void k_gemm(const u16* __restrict__ X0, const u16* __restrict__ X1,
                                              const u16* __restrict__ X2, const float* __restrict__ Wg,
                                              u16* __restrict__ Hout, void* __restrict__ jk, int jkoff,
                                              const int* __restrict__ flag) {
    __shared__ u16 sW[3 * 64 * (F + 4)];
    int tid = threadIdx.x;
    for (int idx = tid; idx < 3 * F * 64; idx += 256) {
        int j = idx & 63;
        int rest = idx >> 6;
        int k = rest % F;
        int p = rest / F;
        sW[(p * 64 + j) * (F + 4) + k] = f2bf(Wg[(p * F + k) * 64 + j]);
    }
    __syncthreads();
    bool isbf = flag[0] != 0;
    int wv = __builtin_amdgcn_readfirstlane(tid >> 6);
    int lane = tid & 63;
    int nbase = blockIdx.x * 32 + wv * 8;
    float acc[8] = {0, 0, 0, 0, 0, 0, 0, 0};
    const u16* Xs[3] = {X0, X1, X2};
    for (int p = 0; p < 3; p++) {
        const u16* Xp = Xs[p];
        const u16* wrow = &sW[(p * 64 + lane) * (F + 4)];
        const u16* rp[8];
#pragma unroll
        for (int i = 0; i < 8; i++) {
            int n = nbase + i;
            if (n > NN - 1) n = NN - 1;
            rp[i] = Xp + (size_t)n * F;
        }
        for (int k = 0; k < F; k += 4) {
            U16x4 w4 = *(const U16x4*)&wrow[k];
            float w0 = bf2f(w4.a), w1 = bf2f(w4.b), w2 = bf2f(w4.c), w3 = bf2f(w4.d);
#pragma unroll
            for (int i = 0; i < 8; i++) {
                U16x4 xv = *(const U16x4*)(rp[i] + k);
                acc[i] = fmaf(bf2f(xv.a), w0, acc[i]);
                acc[i] = fmaf(bf2f(xv.b), w1, acc[i]);
                acc[i] = fmaf(bf2f(xv.c), w2, acc[i]);
                acc[i] = fmaf(bf2f(xv.d), w3, acc[i]);
            }
        }
    }
#pragma unroll
    for (int i = 0; i < 8; i++) {
        int n = nbase + i;
        if (n < NN) {
            float v = fmaxf(acc[i], 0.f);
            Hout[(size_t)n * 64 + lane] = f2bf(v);
            if (isbf) ((u16*)jk)[(size_t)n * 256 + jkoff + lane] = f2bf(v);
            else ((float*)jk)[(size_t)n * 256 + jkoff + lane] = v;
        }
    }
}

// Classifier stage 1 -> internal bf16 z.
__global__ __launch_bounds__(256) void k_cls1(const u16* __restrict__ h0, const u16* __restrict__ h1,
                                              const u16* __restrict__ h2, const u16* __restrict__ h3,
                                              const float* __restrict__ wpad, u16* __restrict__ zout) {
    __shared__ u16 sW[64 * 260];
    int tid = threadIdx.x;
    int jch = blockIdx.y;
    const float* w1 = wpad + OCW1;
    for (int idx = tid; idx < 64 * 256; idx += 256) {
        int j = idx & 63, k = idx >> 6;
        sW[j * 260 + k] = f2bf(w1[k * 256 + jch * 64 + j]);
    }
    __syncthreads();
    int wv = __builtin_amdgcn_readfirstlane(tid >> 6);
    int lane = tid & 63;
    int nbase = blockIdx.x * 32 + wv * 8;
    float acc[8] = {0, 0, 0, 0, 0, 0, 0, 0};
    const u16* hs[4] = {h0, h1, h2, h3};
    const u16* wrow = &sW[lane * 260];
    for (int l = 0; l < 4; l++) {
        const u16* hb = hs[l];
        const u16* rp[8];
#pragma unroll
        for (int i = 0; i < 8; i++) {
            int n = nbase + i;
            if (n > NN - 1) n = NN - 1;
            rp[i] = hb + (size_t)n * 64;
        }
        for (int kk = 0; kk < 64; kk += 4) {
            U16x4 w4 = *(const U16x4*)&wrow[l * 64 + kk];
            float w0 = bf2f(w4.a), w1f = bf2f(w4.b), w2f = bf2f(w4.c), w3f = bf2f(w4.d);
#pragma unroll
            for (int i = 0; i < 8; i++) {
                U16x4 xv = *(const U16x4*)(rp[i] + kk);
                acc[i] = fmaf(bf2f(xv.a), w0, acc[i]);
                acc[i] = fmaf(bf2f(xv.b), w1f, acc[i]);
                acc[i] = fmaf(bf2f(xv.c), w2f, acc[i]);
                acc[i] = fmaf(bf2f(xv.d), w3f, acc[i]);
            }
        }
    }
    int j = jch * 64 + lane;
    float bb1 = wpad[OCB1 + j];
    float s = wpad[OCG + j] * rsqrtf(wpad[OCRV + j] + 1e-5f);
    float t = wpad[OCBB + j] - wpad[OCRM + j] * s;
#pragma unroll
    for (int i = 0; i < 8; i++) {
        int n = nbase + i;
        if (n < NN) {
            float v = fmaxf(acc[i] + bb1, 0.f) * s + t;
            zout[(size_t)n * 256 + j] = f2bf(v);
        }
    }
}

// Classifier stage 2: logit into d_out at LG_OFF (out dtype).
__global__ __launch_bounds__(256) void k_cls2(const u16* __restrict__ z, const float* __restrict__ wpad,
                                              const int* __restrict__ flag, void* __restrict__ dout) {
    __shared__ float sw2[512];
    __shared__ float sb2[2];
    int tid = threadIdx.x;
    for (int i = tid; i < 512; i += 256) sw2[i] = wpad[OCW2 + i];
    if (tid < 2) sb2[tid] = wpad[OCB2 + tid];
    __syncthreads();
    bool isbf = flag[0] != 0;
    int wv = __builtin_amdgcn_readfirstlane(tid >> 6);
    int lane = tid & 63;
    int node = blockIdx.x * 4 + wv;
    U16x4 zv = *(const U16x4*)(z + (size_t)node * 256 + lane * 4);
    float zf[4] = {bf2f(zv.a), bf2f(zv.b), bf2f(zv.c), bf2f(zv.d)};
    float p0 = 0.f, p1 = 0.f;
#pragma unroll
    for (int m = 0; m < 4; m++) {
        int k = lane * 4 + m;
        p0 = fmaf(zf[m], sw2[k * 2 + 0], p0);
        p1 = fmaf(zf[m], sw2[k * 2 + 1], p1);
    }
#pragma unroll
    for (int off = 1; off < 64; off <<= 1) {
        p0 += __shfl_xor(p0, off);
        p1 += __shfl_xor(p1, off);
    }
    if (lane == 0) {
        float l0 = p0 + sb2[0], l1 = p1 + sb2[1];
        if (isbf) {
            u32 pack = (u32)f2bf(l0) | ((u32)f2bf(l1) << 16);
            *(u32*)((u16*)dout + LG_OFF + (size_t)node * 2) = pack;
        } else {
            float2 o = {l0, l1};
            *(float2*)((float*)dout + LG_OFF + (size_t)node * 2) = o;
        }
    }
}

extern "C" void kernel_launch(void* const* d_in, const int* in_sizes, int n_in,
                              void* d_out, int out_size, void* d_ws, size_t ws_size,
                              hipStream_t stream) {
    const void* features = d_in[0];
    const int* ei = (const int*)d_in[1];
    const void* zin = d_in[2];

    char* w = (char*)d_ws;
    auto alloc = [&](size_t bytes) -> void* {
        void* p = (void*)w;
        w += (bytes + 255) & ~(size_t)255;
        return p;
    };
    u16* X0 = (u16*)alloc((size_t)NN * 128 * 2);
    u16* Tx1 = (u16*)alloc((size_t)NN * 128 * 2);
    u16* Tx2 = (u16*)alloc((size_t)NN * 128 * 2);
    u16* h0 = (u16*)alloc((size_t)NN * 64 * 2);
    u16* h1 = (u16*)alloc((size_t)NN * 64 * 2);
    u16* h2 = (u16*)alloc((size_t)NN * 64 * 2);
    u16* h3 = (u16*)alloc((size_t)NN * 64 * 2);
    float* ewf = (float*)alloc((size_t)EE * 4);
    uint2* csr_meta = (uint2*)alloc((size_t)EE * 8);
    float* deg = (float*)alloc((size_t)NN * 4);
    int* cnt = (int*)alloc((size_t)NN * 4);
    int* cursor = (int*)alloc((size_t)NN * 4);
    float* dis = (float*)alloc((size_t)NN * 4);
    int* offs = (int*)alloc((size_t)(NN + 1) * 4);
    u16* W2s = (u16*)alloc((size_t)16384 * 2);
    float* b2p = (float*)alloc((size_t)128 * 4);
    float* wpad = (float*)alloc((size_t)OTOT * 4);
    int* flag = (int*)alloc(256);
    u16* z = X0;  // reuses X0+Tx1 region (25.6MB), free after layer-3 gemm

    hipMemsetAsync(deg, 0, (size_t)((char*)dis - (char*)deg), stream);

    PtrTab tab;
    for (int i = 0; i < 20; i++) tab.p[i] = d_in[3 + i];

    k_detect<<<1, 256, 0, stream>>>((const u16*)features, flag);
    k_wconv<<<20, 256, 0, stream>>>(tab, flag, wpad);
    k_fold<<<33, 128, 0, stream>>>(wpad, W2s, b2p);
    k_x0<<<3125, 256, 0, stream>>>(features, flag, X0);
    // 768 blocks = 256 CU x 3 resident blocks (launch_bounds(256,3)) -> no tail wave
    k_pae<<<768, 256, 0, stream>>>(zin, wpad, W2s, b2p, ei, flag, ewf, d_out, deg, cnt);
    k_scan<<<1, 1024, 0, stream>>>(cnt, deg, offs, dis);
    k_csr<<<EE / 256, 256, 0, stream>>>(ei, ewf, dis, offs, cursor, csr_meta);

    // layer 0 (F=128)
    k_prop<128><<<12500, 256, 0, stream>>>(X0, csr_meta, offs, Tx1, nullptr, 1.f, 0.f);
    k_prop<128><<<12500, 256, 0, stream>>>(Tx1, csr_meta, offs, Tx2, X0, 2.f, -1.f);
    k_gemm<128><<<1563, 256, 0, stream>>>(X0, Tx1, Tx2, wpad + OCH0, h0, d_out, 0, flag);
    // layer 1 (F=64)
    k_prop<64><<<12500, 256, 0, stream>>>(h0, csr_meta, offs, Tx1, nullptr, 1.f, 0.f);
    k_prop<64><<<12500, 256, 0, stream>>>(Tx1, csr_meta, offs, Tx2, h0, 2.f, -1.f);
    k_gemm<64><<<1563, 256, 0, stream>>>(h0, Tx1, Tx2, wpad + OCH1, h1, d_out, 64, flag);
    // layer 2
    k_prop<64><<<12500, 256, 0, stream>>>(h1, csr_meta, offs, Tx1, nullptr, 1.f, 0.f);
    k_prop<64><<<12500, 256, 0, stream>>>(Tx1, csr_meta, offs, Tx2, h1, 2.f, -1.f);
    k_gemm<64><<<1563, 256, 0, stream>>>(h1, Tx1, Tx2, wpad + OCH2, h2, d_out, 128, flag);
    // layer 3
    k_prop<64><<<12500, 256, 0, stream>>>(h2, csr_meta, offs, Tx1, nullptr, 1.f, 0.f);
    k_prop<64><<<12500, 256, 0, stream>>>(Tx1, csr_meta, offs, Tx2, h2, 2.f, -1.f);
    k_gemm<64><<<1563, 256, 0, stream>>>(h2, Tx1, Tx2, wpad + OCH3, h3, d_out, 192, flag);

    // classifier
    k_cls1<<<dim3(1563, 4), 256, 0, stream>>>(h0, h1, h2, h3, wpad, z);
    k_cls2<<<12500, 256, 0, stream>>>(z, wpad, flag, d_out);
    (void)in_sizes; (void)n_in; (void)out_size; (void)ws_size;
}

// Round 2
// 1322.872 us; speedup vs baseline: 1.4617x; 1.2408x over previous
//
#include <hip/hip_runtime.h>

#define NN 50000
#define EE 1600000

using u16 = unsigned short;
using u32 = unsigned int;

typedef float f32x4 __attribute__((ext_vector_type(4)));
typedef __bf16 bf16x8 __attribute__((ext_vector_type(8)));
typedef unsigned short u16x8 __attribute__((ext_vector_type(8)));

struct alignas(8) U16x4 { u16 a, b, c, d; };
struct PtrTab { const void* p[20]; };

// canonical fp32 weight-pad offsets
#define OW1 0
#define OB1 768
#define OG 896
#define OBB 1024
#define ORM 1152
#define ORV 1280
#define OW2 1408
#define OB2 17792
#define OCH0 17920
#define OCH1 42496
#define OCH2 54784
#define OCH3 67072
#define OCW1 79360
#define OCB1 144896
#define OCG 145152
#define OCBB 145408
#define OCRM 145664
#define OCRV 145920
#define OCW2 146176
#define OCB2 146688
#define OTOT 146690

// element offsets within d_out (dtype-independent in elements)
#define LG_OFF ((size_t)NN * 256)
#define EW_OFF ((size_t)NN * 256 + (size_t)NN * 2)

__device__ __forceinline__ float bf2f(u16 u) { return __builtin_bit_cast(float, (u32)u << 16); }
__device__ __forceinline__ float bfl(u32 u) { return __builtin_bit_cast(float, u << 16); }
__device__ __forceinline__ float bfh(u32 u) { return __builtin_bit_cast(float, u & 0xffff0000u); }
__device__ __forceinline__ u16 f2bf(float f) {
    u32 u = __builtin_bit_cast(u32, f);
    return (u16)((u + 0x7fffu + ((u >> 16) & 1u)) >> 16);
}

// Input dtype detector: flag=1 -> bf16 inputs, 0 -> fp32 inputs.
__global__ __launch_bounds__(256) void k_detect(const u16* __restrict__ f, int* __restrict__ flag) {
    __shared__ int bad;
    if (threadIdx.x == 0) bad = 0;
    __syncthreads();
    u16 u = f[threadIdx.x];
    int e = (u >> 7) & 0xFF;
    if (e >= 0x90) atomicAdd(&bad, 1);
    __syncthreads();
    if (threadIdx.x == 0) flag[0] = (bad < 16) ? 1 : 0;
}

// Convert all 20 weight arrays into canonical fp32 pad.
__global__ __launch_bounds__(256) void k_wconv(PtrTab tab, const int* __restrict__ flag,
                                               float* __restrict__ wpad) {
    const int SZ[20] = {768, 128, 128, 128, 128, 128, 16384, 128, 24576, 12288, 12288, 12288,
                        65536, 256, 256, 256, 256, 256, 512, 2};
    const int OF[20] = {OW1, OB1, OG, OBB, ORM, ORV, OW2, OB2, OCH0, OCH1, OCH2, OCH3,
                        OCW1, OCB1, OCG, OCBB, OCRM, OCRV, OCW2, OCB2};
    int a = blockIdx.x;
    int n = SZ[a];
    float* dst = wpad + OF[a];
    if (flag[0] != 0) {
        const u16* s = (const u16*)tab.p[a];
        for (int i = threadIdx.x; i < n; i += 256) dst[i] = bf2f(s[i]);
    } else {
        const float* s = (const float*)tab.p[a];
        for (int i = threadIdx.x; i < n; i += 256) dst[i] = s[i];
    }
}

// Fold PAE BN into W2 (MFMA B-frag swizzled bf16) + b2'.
__global__ __launch_bounds__(128) void k_fold(const float* __restrict__ wpad,
                                              u16* __restrict__ W2s, float* __restrict__ b2p) {
    const float* g = wpad + OG;
    const float* b = wpad + OBB;
    const float* rm = wpad + ORM;
    const float* rv = wpad + ORV;
    const float* w2 = wpad + OW2;
    const float* b2 = wpad + OB2;
    int blk = blockIdx.x, tid = threadIdx.x;
    if (blk < 32) {
        int kc = blk >> 3, jt = blk & 7;
        int lane = tid & 63, jh = tid >> 6;
        for (int jj = 0; jj < 4; jj++) {
            int j = jh * 4 + jj;
            int k = kc * 32 + (lane >> 4) * 8 + j;
            int jcol = jt * 16 + (lane & 15);
            float s = g[k] * rsqrtf(rv[k] + 1e-5f);
            W2s[((kc * 8 + jt) * 64 + lane) * 8 + j] = f2bf(s * w2[k * 128 + jcol]);
        }
    } else {
        if (tid < 128) {
            int j = tid;
            float acc = b2[j];
            for (int k = 0; k < 128; k++) {
                float s = g[k] * rsqrtf(rv[k] + 1e-5f);
                float t = b[k] - rm[k] * s;
                acc += t * w2[k * 128 + j];
            }
            b2p[j] = acc;
        }
    }
}

// Fold classifier weights: W1c = cls_w1 as MFMA B-fragments (bf16, phase-sliced),
// w2p[j][c] = s_j * cls_w2[j][c], b2p2[c] = cls_b2[c] + sum_j t_j * cls_w2[j][c]
// (BN folded past the logit matmul; relu(.)+b1 stays in the epilogue).
// W1c global index gi: j=gi&7, lane=(gi>>3)&63, ct=(gi>>9)&15, kc2=(gi>>13)&1,
// l=gi>>14; value = bf16(w1[(l*64+kc2*32+(lane>>4)*8+j)*256 + ct*16+(lane&15)]).
__global__ __launch_bounds__(256) void k_foldc(const float* __restrict__ wpad,
                                               u16* __restrict__ W1c, float* __restrict__ w2p,
                                               float* __restrict__ b2p2) {
    int tid = threadIdx.x;
    if (blockIdx.x < 64) {
        const float* w1 = wpad + OCW1;
        int base = blockIdx.x * 1024 + tid * 4;
#pragma unroll
        for (int u = 0; u < 4; u++) {
            int gi = base + u;
            int j = gi & 7;
            int lane = (gi >> 3) & 63;
            int ct = (gi >> 9) & 15;
            int kc2 = (gi >> 13) & 1;
            int l = gi >> 14;
            int k = l * 64 + kc2 * 32 + ((lane >> 4) & 3) * 8 + j;
            int col = ct * 16 + (lane & 15);
            W1c[gi] = f2bf(w1[k * 256 + col]);
        }
    } else {
        __shared__ float red[8];
        int j = tid;
        float s = wpad[OCG + j] * rsqrtf(wpad[OCRV + j] + 1e-5f);
        float t = wpad[OCBB + j] - wpad[OCRM + j] * s;
        float w0 = wpad[OCW2 + j * 2], w1v = wpad[OCW2 + j * 2 + 1];
        w2p[j * 2] = s * w0;
        w2p[j * 2 + 1] = s * w1v;
        float c0 = t * w0, c1 = t * w1v;
#pragma unroll
        for (int off = 1; off < 64; off <<= 1) {
            c0 += __shfl_xor(c0, off);
            c1 += __shfl_xor(c1, off);
        }
        int wv = tid >> 6, lane = tid & 63;
        if (lane == 0) { red[wv * 2] = c0; red[wv * 2 + 1] = c1; }
        __syncthreads();
        if (tid == 0) b2p2[0] = wpad[OCB2] + red[0] + red[2] + red[4] + red[6];
        if (tid == 1) b2p2[1] = wpad[OCB2 + 1] + red[1] + red[3] + red[5] + red[7];
    }
}

// features (either dtype) -> bf16 X0.
__global__ __launch_bounds__(256) void k_x0(const void* __restrict__ feat, const int* __restrict__ flag,
                                            u16* __restrict__ X0) {
    int i = blockIdx.x * 256 + threadIdx.x;
    if (flag[0] != 0) {
        ((uint4*)X0)[i] = ((const uint4*)feat)[i];
    } else {
        const float4* f = (const float4*)feat;
        float4 a = f[2 * i], b = f[2 * i + 1];
        u16x8 o;
        o[0] = f2bf(a.x); o[1] = f2bf(a.y); o[2] = f2bf(a.z); o[3] = f2bf(a.w);
        o[4] = f2bf(b.x); o[5] = f2bf(b.y); o[6] = f2bf(b.z); o[7] = f2bf(b.w);
        ((uint4*)X0)[i] = __builtin_bit_cast(uint4, o);
    }
}

// PAE: A = relu(Z@W1+b1) on VALU (fragments staged once), H = A@W2' via MFMA.
__global__ __launch_bounds__(256, 3) void k_pae(const void* __restrict__ zin, const float* __restrict__ wpad,
                                                const u16* __restrict__ W2sg, const float* __restrict__ b2p,
                                                const int* __restrict__ ei, const int* __restrict__ flag,
                                                float* __restrict__ ewf, void* __restrict__ dout,
                                                float* __restrict__ deg, int* __restrict__ cnt) {
    __shared__ __align__(16) u16 sW2[16384];
    __shared__ __align__(16) float sW1k[1024];  // float m of row k at byte (k*32+m*4)^(((k>>3)&3)<<4)
    __shared__ float sB2[128];
    int tid = threadIdx.x;
    for (int i = tid; i < 8192; i += 256) ((u32*)sW2)[i] = ((const u32*)W2sg)[i];
    for (int i = tid; i < 1024; i += 256) {
        int k = i >> 3, m = i & 7;
        float v = 0.f;
        if (m < 6) v = wpad[OW1 + m * 128 + k];
        else if (m == 6) v = wpad[OB1 + k];
        int sw = ((k >> 3) & 3) << 4;
        *(float*)((char*)sW1k + ((k * 32 + m * 4) ^ sw)) = v;
    }
    if (tid < 128) sB2[tid] = b2p[tid];
    __syncthreads();

    bool isbf = flag[0] != 0;
    int wv = __builtin_amdgcn_readfirstlane(tid >> 6);
    int lane = tid & 63;
    int quad = lane >> 4, lrow = lane & 15, jc = lane & 15;
    int sq = quad << 4;  // sW1k swizzle constant for this lane's k range
    int gw = blockIdx.x * 4 + wv;
    const int ngroups = EE / 16;
    const int gstep = gridDim.x * 4;

    uint2 pb0, pb1, pb2;       // bf16 Z prefetch (24B row)
    float4 pf0, pf1, pf2;      // fp32 Z prefetch (48B row)
    if (gw < ngroups) {
        if (isbf) {
            const uint2* zp = (const uint2*)((const u16*)zin + (size_t)(gw * 16 + lrow) * 12);
            pb0 = zp[0]; pb1 = zp[1]; pb2 = zp[2];
        } else {
            const float4* zp = (const float4*)((const float*)zin + (size_t)(gw * 16 + lrow) * 12);
            pf0 = zp[0]; pf1 = zp[1]; pf2 = zp[2];
        }
    }

#pragma unroll 1
    for (int gidx = gw; gidx < ngroups; gidx += gstep) {
        int e0 = gidx * 16;
        float z1[6], z2[6];
        if (isbf) {
            z1[0] = bfl(pb0.x); z1[1] = bfh(pb0.x); z1[2] = bfl(pb0.y); z1[3] = bfh(pb0.y);
            z1[4] = bfl(pb1.x); z1[5] = bfh(pb1.x);
            z2[0] = bfl(pb1.y); z2[1] = bfh(pb1.y); z2[2] = bfl(pb2.x); z2[3] = bfh(pb2.x);
            z2[4] = bfl(pb2.y); z2[5] = bfh(pb2.y);
        } else {
            z1[0] = pf0.x; z1[1] = pf0.y; z1[2] = pf0.z; z1[3] = pf0.w; z1[4] = pf1.x; z1[5] = pf1.y;
            z2[0] = pf1.z; z2[1] = pf1.w; z2[2] = pf2.x; z2[3] = pf2.y; z2[4] = pf2.z; z2[5] = pf2.w;
        }
        // issue next group's Z loads now -- they complete under this group's compute
        int gn = gidx + gstep;
        if (gn < ngroups) {
            if (isbf) {
                const uint2* zp = (const uint2*)((const u16*)zin + (size_t)(gn * 16 + lrow) * 12);
                pb0 = zp[0]; pb1 = zp[1]; pb2 = zp[2];
            } else {
                const float4* zp = (const float4*)((const float*)zin + (size_t)(gn * 16 + lrow) * 12);
                pf0 = zp[0]; pf1 = zp[1]; pf2 = zp[2];
            }
        }
        // hoist epilogue row indices (were a cold global load after the MFMA loop)
        int rows[4];
        if (jc == 0) {
#pragma unroll
            for (int r = 0; r < 4; r++) rows[r] = ei[e0 + quad * 4 + r];
        }

        // Stage A fragments for all 4 kc chunks (32 VGPRs total)
        bf16x8 a1f[4], a2f[4];
#pragma unroll
        for (int kc = 0; kc < 4; kc++) {
            int kbase = kc * 32 + quad * 8;
            u32 r1[4], r2[4];
#pragma unroll
            for (int jh = 0; jh < 4; jh++) {
                int k = kbase + 2 * jh;
                const char* bp = (const char*)sW1k;
                float4 wa = *(const float4*)(bp + ((k * 32) ^ sq));
                float4 wb = *(const float4*)(bp + ((k * 32 + 16) ^ sq));
                float4 wc = *(const float4*)(bp + (((k + 1) * 32) ^ sq));
                float4 wd = *(const float4*)(bp + (((k + 1) * 32 + 16) ^ sq));
                float sA1 = wb.z, sA2 = wb.z, sB1 = wd.z, sB2v = wd.z;
                sA1 = fmaf(z1[0], wa.x, sA1); sA2 = fmaf(z2[0], wa.x, sA2);
                sA1 = fmaf(z1[1], wa.y, sA1); sA2 = fmaf(z2[1], wa.y, sA2);
                sA1 = fmaf(z1[2], wa.z, sA1); sA2 = fmaf(z2[2], wa.z, sA2);
                sA1 = fmaf(z1[3], wa.w, sA1); sA2 = fmaf(z2[3], wa.w, sA2);
                sA1 = fmaf(z1[4], wb.x, sA1); sA2 = fmaf(z2[4], wb.x, sA2);
                sA1 = fmaf(z1[5], wb.y, sA1); sA2 = fmaf(z2[5], wb.y, sA2);
                sB1 = fmaf(z1[0], wc.x, sB1); sB2v = fmaf(z2[0], wc.x, sB2v);
                sB1 = fmaf(z1[1], wc.y, sB1); sB2v = fmaf(z2[1], wc.y, sB2v);
                sB1 = fmaf(z1[2], wc.z, sB1); sB2v = fmaf(z2[2], wc.z, sB2v);
                sB1 = fmaf(z1[3], wc.w, sB1); sB2v = fmaf(z2[3], wc.w, sB2v);
                sB1 = fmaf(z1[4], wd.x, sB1); sB2v = fmaf(z2[4], wd.x, sB2v);
                sB1 = fmaf(z1[5], wd.y, sB1); sB2v = fmaf(z2[5], wd.y, sB2v);
                sA1 = fmaxf(sA1, 0.f); sA2 = fmaxf(sA2, 0.f);
                sB1 = fmaxf(sB1, 0.f); sB2v = fmaxf(sB2v, 0.f);
                u32 o1, o2;
                asm("v_cvt_pk_bf16_f32 %0, %1, %2" : "=v"(o1) : "v"(sA1), "v"(sB1));
                asm("v_cvt_pk_bf16_f32 %0, %1, %2" : "=v"(o2) : "v"(sA2), "v"(sB2v));
                r1[jh] = o1; r2[jh] = o2;
            }
            uint4 u1v = {r1[0], r1[1], r1[2], r1[3]};
            uint4 u2v = {r2[0], r2[1], r2[2], r2[3]};
            a1f[kc] = __builtin_bit_cast(bf16x8, u1v);
            a2f[kc] = __builtin_bit_cast(bf16x8, u2v);
        }

        float num[4] = {0, 0, 0, 0}, q1[4] = {0, 0, 0, 0}, q2[4] = {0, 0, 0, 0};
        // jt NOT unrolled: keeps ds_read hoisting bounded (spill guard).
#pragma unroll 1
        for (int jt = 0; jt < 8; jt++) {
            f32x4 acc1 = {0.f, 0.f, 0.f, 0.f}, acc2 = {0.f, 0.f, 0.f, 0.f};
#pragma unroll
            for (int kc = 0; kc < 4; kc++) {
                bf16x8 bb = *reinterpret_cast<const bf16x8*>(&sW2[((kc * 8 + jt) * 64 + lane) * 8]);
                acc1 = __builtin_amdgcn_mfma_f32_16x16x32_bf16(a1f[kc], bb, acc1, 0, 0, 0);
                acc2 = __builtin_amdgcn_mfma_f32_16x16x32_bf16(a2f[kc], bb, acc2, 0, 0, 0);
            }
            float bbias = sB2[jt * 16 + jc];
#pragma unroll
            for (int r = 0; r < 4; r++) {
                float h1 = acc1[r] + bbias;
                float h2 = acc2[r] + bbias;
                num[r] = fmaf(h1, h2, num[r]);
                q1[r] = fmaf(h1, h1, q1[r]);
                q2[r] = fmaf(h2, h2, q2[r]);
            }
        }
#pragma unroll
        for (int off = 1; off < 16; off <<= 1) {
#pragma unroll
            for (int r = 0; r < 4; r++) {
                num[r] += __shfl_xor(num[r], off);
                q1[r] += __shfl_xor(q1[r], off);
                q2[r] += __shfl_xor(q2[r], off);
            }
        }
        if (jc == 0) {
#pragma unroll
            for (int r = 0; r < 4; r++) {
                int e = e0 + quad * 4 + r;
                float den = fmaxf(sqrtf(q1[r]) * sqrtf(q2[r]), 1e-8f);
                float wgt = (num[r] / den + 1.f) * 0.5f;
                if (!(wgt == wgt)) wgt = 0.5f;  // NaN guard: makes failures localizable
                ewf[e] = wgt;
                if (isbf) ((u16*)dout)[EW_OFF + e] = f2bf(wgt);
                else ((float*)dout)[EW_OFF + e] = wgt;
                atomicAdd(deg + rows[r], wgt);
                atomicAdd(cnt + rows[r], 1);
            }
        }
    }
}

// Exclusive scan of cnt -> offs; fused dis = rsqrt(deg).
__global__ __launch_bounds__(1024) void k_scan(const int* __restrict__ cnt, const float* __restrict__ deg,
                                               int* __restrict__ offs, float* __restrict__ dis) {
    __shared__ int wsum[16];
    __shared__ int carry;
    int tid = threadIdx.x;
    int wv = tid >> 6, lane = tid & 63;
    if (tid == 0) carry = 0;
    __syncthreads();
    for (int c = 0; c < 49; c++) {
        int i = c * 1024 + tid;
        int v = (i < NN) ? cnt[i] : 0;
        if (i < NN) {
            float d = deg[i];
            dis[i] = d > 0.f ? rsqrtf(d) : 0.f;
        }
        int x = v;
#pragma unroll
        for (int off = 1; off < 64; off <<= 1) {
            int t = __shfl_up(x, off);
            if (lane >= off) x += t;
        }
        if (lane == 63) wsum[wv] = x;
        __syncthreads();
        if (tid < 16) {
            int s = wsum[tid];
#pragma unroll
            for (int off = 1; off < 16; off <<= 1) {
                int t = __shfl_up(s, off, 16);
                if (tid >= off) s += t;
            }
            wsum[tid] = s;
        }
        __syncthreads();
        int base = carry + (wv > 0 ? wsum[wv - 1] : 0);
        if (i < NN) offs[i] = base + x - v;
        __syncthreads();
        if (tid == 0) carry += wsum[15];
        __syncthreads();
    }
    if (tid == 0) offs[NN] = carry;
}

// CSR scatter: fused (col, norm) uint2 metadata — one 8B load per edge in prop.
__global__ __launch_bounds__(256) void k_csr(const int* __restrict__ ei, const float* __restrict__ ewf,
                                             const float* __restrict__ dis, const int* __restrict__ offs,
                                             int* __restrict__ cursor, uint2* __restrict__ csr_meta) {
    int e = blockIdx.x * 256 + threadIdx.x;
    int r = ei[e], c = ei[EE + e];
    float wgt = ewf[e];
    int pos = offs[r] + atomicAdd(cursor + r, 1);
    float nrm = -dis[r] * wgt * dis[c];
    csr_meta[pos] = make_uint2((u32)c, __builtin_bit_cast(u32, nrm));
}

// Propagation over bf16 node features, fp32 accumulate. One wave per node.
template <int F>
__global__ __launch_bounds__(256) void k_prop(const u16* __restrict__ src, const uint2* __restrict__ csr_meta,
                                              const int* __restrict__ offs,
                                              u16* __restrict__ out, const u16* __restrict__ base,
                                              float alpha, float beta) {
    int lane = threadIdx.x & 63;
    int wv = threadIdx.x >> 6;
    int node = blockIdx.x * 4 + wv;
    int s = offs[node], e = offs[node + 1];

    if (F == 128) {
        int sub = lane >> 4;   // which of 4 edges this lane group handles
        int fl = lane & 15;    // position within the feature row
        const uint4* sv = (const uint4*)src;  // row = 16 uint4 (128 bf16)
        float a[8] = {0, 0, 0, 0, 0, 0, 0, 0};
        int p = s;
        for (; p + 7 < e; p += 8) {
            uint2 m0 = csr_meta[p + sub];
            uint2 m1 = csr_meta[p + 4 + sub];
            uint4 v0 = sv[(size_t)m0.x * 16 + fl];
            uint4 v1 = sv[(size_t)m1.x * 16 + fl];
            float w0 = __builtin_bit_cast(float, m0.y);
            float w1 = __builtin_bit_cast(float, m1.y);
            a[0] = fmaf(w0, bfl(v0.x), a[0]); a[1] = fmaf(w0, bfh(v0.x), a[1]);
            a[2] = fmaf(w0, bfl(v0.y), a[2]); a[3] = fmaf(w0, bfh(v0.y), a[3]);
            a[4] = fmaf(w0, bfl(v0.z), a[4]); a[5] = fmaf(w0, bfh(v0.z), a[5]);
            a[6] = fmaf(w0, bfl(v0.w), a[6]); a[7] = fmaf(w0, bfh(v0.w), a[7]);
            a[0] = fmaf(w1, bfl(v1.x), a[0]); a[1] = fmaf(w1, bfh(v1.x), a[1]);
            a[2] = fmaf(w1, bfl(v1.y), a[2]); a[3] = fmaf(w1, bfh(v1.y), a[3]);
            a[4] = fmaf(w1, bfl(v1.z), a[4]); a[5] = fmaf(w1, bfh(v1.z), a[5]);
            a[6] = fmaf(w1, bfl(v1.w), a[6]); a[7] = fmaf(w1, bfh(v1.w), a[7]);
        }
        if (p + 3 < e) {
            uint2 m0 = csr_meta[p + sub];
            uint4 v0 = sv[(size_t)m0.x * 16 + fl];
            float w0 = __builtin_bit_cast(float, m0.y);
            a[0] = fmaf(w0, bfl(v0.x), a[0]); a[1] = fmaf(w0, bfh(v0.x), a[1]);
            a[2] = fmaf(w0, bfl(v0.y), a[2]); a[3] = fmaf(w0, bfh(v0.y), a[3]);
            a[4] = fmaf(w0, bfl(v0.z), a[4]); a[5] = fmaf(w0, bfh(v0.z), a[5]);
            a[6] = fmaf(w0, bfl(v0.w), a[6]); a[7] = fmaf(w0, bfh(v0.w), a[7]);
            p += 4;
        }
#pragma unroll
        for (int i = 0; i < 8; i++) {
            a[i] += __shfl_xor(a[i], 16);
            a[i] += __shfl_xor(a[i], 32);
        }
        if (sub == 0) {
            for (; p < e; p++) {
                uint2 m0 = csr_meta[p];
                uint4 v = sv[(size_t)m0.x * 16 + fl];
                float w = __builtin_bit_cast(float, m0.y);
                a[0] = fmaf(w, bfl(v.x), a[0]); a[1] = fmaf(w, bfh(v.x), a[1]);
                a[2] = fmaf(w, bfl(v.y), a[2]); a[3] = fmaf(w, bfh(v.y), a[3]);
                a[4] = fmaf(w, bfl(v.z), a[4]); a[5] = fmaf(w, bfh(v.z), a[5]);
                a[6] = fmaf(w, bfl(v.w), a[6]); a[7] = fmaf(w, bfh(v.w), a[7]);
            }
            float o[8];
#pragma unroll
            for (int i = 0; i < 8; i++) o[i] = alpha * a[i];
            if (beta != 0.f) {
                uint4 bv = ((const uint4*)base)[(size_t)node * 16 + fl];
                o[0] = fmaf(beta, bfl(bv.x), o[0]); o[1] = fmaf(beta, bfh(bv.x), o[1]);
                o[2] = fmaf(beta, bfl(bv.y), o[2]); o[3] = fmaf(beta, bfh(bv.y), o[3]);
                o[4] = fmaf(beta, bfl(bv.z), o[4]); o[5] = fmaf(beta, bfh(bv.z), o[5]);
                o[6] = fmaf(beta, bfl(bv.w), o[6]); o[7] = fmaf(beta, bfh(bv.w), o[7]);
            }
            uint4 ov;
            ov.x = (u32)f2bf(o[0]) | ((u32)f2bf(o[1]) << 16);
            ov.y = (u32)f2bf(o[2]) | ((u32)f2bf(o[3]) << 16);
            ov.z = (u32)f2bf(o[4]) | ((u32)f2bf(o[5]) << 16);
            ov.w = (u32)f2bf(o[6]) | ((u32)f2bf(o[7]) << 16);
            ((uint4*)out)[(size_t)node * 16 + fl] = ov;
        }
    } else {
        int sub = lane >> 3;   // which of 8 edges this lane group handles
        int fl = lane & 7;     // position within the feature row (uint4 units)
        const uint4* sv = (const uint4*)src;  // row = 8 uint4 (64 bf16)
        float a[8] = {0, 0, 0, 0, 0, 0, 0, 0};
        int p = s;
        for (; p + 15 < e; p += 16) {
            uint2 m0 = csr_meta[p + sub];
            uint2 m1 = csr_meta[p + 8 + sub];
            uint4 v0 = sv[(size_t)m0.x * 8 + fl];
            uint4 v1 = sv[(size_t)m1.x * 8 + fl];
            float w0 = __builtin_bit_cast(float, m0.y);
            float w1 = __builtin_bit_cast(float, m1.y);
            a[0] = fmaf(w0, bfl(v0.x), a[0]); a[1] = fmaf(w0, bfh(v0.x), a[1]);
            a[2] = fmaf(w0, bfl(v0.y), a[2]); a[3] = fmaf(w0, bfh(v0.y), a[3]);
            a[4] = fmaf(w0, bfl(v0.z), a[4]); a[5] = fmaf(w0, bfh(v0.z), a[5]);
            a[6] = fmaf(w0, bfl(v0.w), a[6]); a[7] = fmaf(w0, bfh(v0.w), a[7]);
            a[0] = fmaf(w1, bfl(v1.x), a[0]); a[1] = fmaf(w1, bfh(v1.x), a[1]);
            a[2] = fmaf(w1, bfl(v1.y), a[2]); a[3] = fmaf(w1, bfh(v1.y), a[3]);
            a[4] = fmaf(w1, bfl(v1.z), a[4]); a[5] = fmaf(w1, bfh(v1.z), a[5]);
            a[6] = fmaf(w1, bfl(v1.w), a[6]); a[7] = fmaf(w1, bfh(v1.w), a[7]);
        }
        if (p + 7 < e) {
            uint2 m0 = csr_meta[p + sub];
            uint4 v0 = sv[(size_t)m0.x * 8 + fl];
            float w0 = __builtin_bit_cast(float, m0.y);
            a[0] = fmaf(w0, bfl(v0.x), a[0]); a[1] = fmaf(w0, bfh(v0.x), a[1]);
            a[2] = fmaf(w0, bfl(v0.y), a[2]); a[3] = fmaf(w0, bfh(v0.y), a[3]);
            a[4] = fmaf(w0, bfl(v0.z), a[4]); a[5] = fmaf(w0, bfh(v0.z), a[5]);
            a[6] = fmaf(w0, bfl(v0.w), a[6]); a[7] = fmaf(w0, bfh(v0.w), a[7]);
            p += 8;
        }
#pragma unroll
        for (int i = 0; i < 8; i++) {
            a[i] += __shfl_xor(a[i], 8);
            a[i] += __shfl_xor(a[i], 16);
            a[i] += __shfl_xor(a[i], 32);
        }
        if (sub == 0) {
            for (; p < e; p++) {
                uint2 m0 = csr_meta[p];
                uint4 v = sv[(size_t)m0.x * 8 + fl];
                float w = __builtin_bit_cast(float, m0.y);
                a[0] = fmaf(w, bfl(v.x), a[0]); a[1] = fmaf(w, bfh(v.x), a[1]);
                a[2] = fmaf(w, bfl(v.y), a[2]); a[3] = fmaf(w, bfh(v.y), a[3]);
                a[4] = fmaf(w, bfl(v.z), a[4]); a[5] = fmaf(w, bfh(v.z), a[5]);
                a[6] = fmaf(w, bfl(v.w), a[6]); a[7] = fmaf(w, bfh(v.w), a[7]);
            }
            float o[8];
#pragma unroll
            for (int i = 0; i < 8; i++) o[i] = alpha * a[i];
            if (beta != 0.f) {
                uint4 bv = ((const uint4*)base)[(size_t)node * 8 + fl];
                o[0] = fmaf(beta, bfl(bv.x), o[0]); o[1] = fmaf(beta, bfh(bv.x), o[1]);
                o[2] = fmaf(beta, bfl(bv.y), o[2]); o[3] = fmaf(beta, bfh(bv.y), o[3]);
                o[4] = fmaf(beta, bfl(bv.z), o[4]); o[5] = fmaf(beta, bfh(bv.z), o[5]);
                o[6] = fmaf(beta, bfl(bv.w), o[6]); o[7] = fmaf(beta, bfh(bv.w), o[7]);
            }
            uint4 ov;
            ov.x = (u32)f2bf(o[0]) | ((u32)f2bf(o[1]) << 16);
            ov.y = (u32)f2bf(o[2]) | ((u32)f2bf(o[3]) << 16);
            ov.z = (u32)f2bf(o[4]) | ((u32)f2bf(o[5]) << 16);
            ov.w = (u32)f2bf(o[6]) | ((u32)f2bf(o[7]) << 16);
            ((uint4*)out)[(size_t)node * 8 + fl] = ov;
        }
    }
}

// ChebConv mix -> bf16 h + jk slice (out dtype).
template <int F>
__global__ __launch_bounds__(256) void k_gemm(const u16* __restrict__ X0, const u16* __restrict__ X1,
                                              const u16* __restrict__ X2, const float* __restrict__ Wg,
                                              u16* __restrict__ Hout, void* __restrict__ jk, int jkoff,
                                              const int* __restrict__ flag) {
    __shared__ u16 sW[3 * 64 * (F + 4)];
    int tid = threadIdx.x;
    for (int idx = tid; idx < 3 * F * 64; idx += 256) {
        int j = idx & 63;
        int rest = idx >> 6;
        int k = rest % F;
        int p = rest / F;
        sW[(p * 64 + j) * (F + 4) + k] = f2bf(Wg[(p * F + k) * 64 + j]);
    }
    __syncthreads();
    bool isbf = flag[0] != 0;
    int wv = __builtin_amdgcn_readfirstlane(tid >> 6);
    int lane = tid & 63;
    int nbase = blockIdx.x * 32 + wv * 8;
    float acc[8] = {0, 0, 0, 0, 0, 0, 0, 0};
    const u16* Xs[3] = {X0, X1, X2};
    for (int p = 0; p < 3; p++) {
        const u16* Xp = Xs[p];
        const u16* wrow = &sW[(p * 64 + lane) * (F + 4)];
        const u16* rp[8];
#pragma unroll
        for (int i = 0; i < 8; i++) {
            int n = nbase + i;
            if (n > NN - 1) n = NN - 1;
            rp[i] = Xp + (size_t)n * F;
        }
        for (int k = 0; k < F; k += 4) {
            U16x4 w4 = *(const U16x4*)&wrow[k];
            float w0 = bf2f(w4.a), w1 = bf2f(w4.b), w2 = bf2f(w4.c), w3 = bf2f(w4.d);
#pragma unroll
            for (int i = 0; i < 8; i++) {
                U16x4 xv = *(const U16x4*)(rp[i] + k);
                acc[i] = fmaf(bf2f(xv.a), w0, acc[i]);
                acc[i] = fmaf(bf2f(xv.b), w1, acc[i]);
                acc[i] = fmaf(bf2f(xv.c), w2, acc[i]);
                acc[i] = fmaf(bf2f(xv.d), w3, acc[i]);
            }
        }
    }
#pragma unroll
    for (int i = 0; i < 8; i++) {
        int n = nbase + i;
        if (n < NN) {
            float v = fmaxf(acc[i], 0.f);
            Hout[(size_t)n * 64 + lane] = f2bf(v);
            if (isbf) ((u16*)jk)[(size_t)n * 256 + jkoff + lane] = f2bf(v);
            else ((float*)jk)[(size_t)n * 256 + jkoff + lane] = v;
        }
    }
}

// Fused classifier: logit = (relu(jk@W1+b1)*s+t)@w2 + b2, z never materialized.
// MFMA 16x16x32 bf16. Block = 32 rows x 256 cols; wave wv: rows (wv>>1)*16,
// coltiles (wv&1)*8..+8. K = 256 split into 4 phases (one h array each),
// B-fragments staged per phase (32KB LDS, conflict-free b128 reads).
// BN folded past logit: w2p = s*w2, b2p2 = b2 + sum(t*w2); relu(.)+b1 in epilogue.
__global__ __launch_bounds__(256) void k_cls(const u16* __restrict__ h0, const u16* __restrict__ h1,
                                             const u16* __restrict__ h2, const u16* __restrict__ h3,
                                             const u16* __restrict__ W1c, const float* __restrict__ wpad,
                                             const float* __restrict__ w2p, const float* __restrict__ b2p2,
                                             const int* __restrict__ flag, void* __restrict__ dout) {
    __shared__ __align__(16) u16 sB[16384];  // one phase slice of W1c (32KB)
    __shared__ float sb1[256];
    __shared__ float sw2[512];
    __shared__ float sb2[2];
    __shared__ float part[4][16][2];
    int tid = threadIdx.x;
    if (tid < 256) sb1[tid] = wpad[OCB1 + tid];
    for (int i = tid; i < 512; i += 256) sw2[i] = w2p[i];
    if (tid < 2) sb2[tid] = b2p2[tid];

    int wv = __builtin_amdgcn_readfirstlane(tid >> 6);
    int lane = tid & 63;
    int quad = lane >> 4, jc = lane & 15;
    int pair = wv >> 1;      // row group (0/1)
    int half = wv & 1;       // column half (0/1)
    int nb = blockIdx.x * 32 + pair * 16;

    f32x4 acc[8] = {{0.f, 0.f, 0.f, 0.f}, {0.f, 0.f, 0.f, 0.f}, {0.f, 0.f, 0.f, 0.f}, {0.f, 0.f, 0.f, 0.f},
                    {0.f, 0.f, 0.f, 0.f}, {0.f, 0.f, 0.f, 0.f}, {0.f, 0.f, 0.f, 0.f}, {0.f, 0.f, 0.f, 0.f}};
    const u16* hs[4] = {h0, h1, h2, h3};

    int row = nb + jc;
    if (row > NN - 1) row = NN - 1;

#pragma unroll 1
    for (int l = 0; l < 4; l++) {
        __syncthreads();
        const u32* src = (const u32*)W1c + l * 8192;
        for (int i = tid; i < 8192; i += 256) ((u32*)sB)[i] = src[i];
        __syncthreads();
        const uint4* rp = (const uint4*)(hs[l] + (size_t)row * 64);
        uint4 a0u = rp[quad], a1u = rp[4 + quad];
        bf16x8 af0 = __builtin_bit_cast(bf16x8, a0u);
        bf16x8 af1 = __builtin_bit_cast(bf16x8, a1u);
#pragma unroll
        for (int jt = 0; jt < 8; jt++) {
            int ct = half * 8 + jt;
            bf16x8 b0 = *reinterpret_cast<const bf16x8*>(&sB[((0 * 16 + ct) * 64 + lane) * 8]);
            bf16x8 b1f = *reinterpret_cast<const bf16x8*>(&sB[((1 * 16 + ct) * 64 + lane) * 8]);
            acc[jt] = __builtin_amdgcn_mfma_f32_16x16x32_bf16(af0, b0, acc[jt], 0, 0, 0);
            acc[jt] = __builtin_amdgcn_mfma_f32_16x16x32_bf16(af1, b1f, acc[jt], 0, 0, 0);
        }
    }

    // epilogue: relu(acc+b1) dot w2' -> per-row logit partials
    float p0[4] = {0, 0, 0, 0}, p1[4] = {0, 0, 0, 0};
#pragma unroll
    for (int jt = 0; jt < 8; jt++) {
        int j = (half * 8 + jt) * 16 + jc;
        float b1v = sb1[j], wa = sw2[2 * j], wb = sw2[2 * j + 1];
#pragma unroll
        for (int r = 0; r < 4; r++) {
            float h = fmaxf(acc[jt][r] + b1v, 0.f);
            p0[r] = fmaf(h, wa, p0[r]);
            p1[r] = fmaf(h, wb, p1[r]);
        }
    }
#pragma unroll
    for (int off = 1; off < 16; off <<= 1) {
#pragma unroll
        for (int r = 0; r < 4; r++) {
            p0[r] += __shfl_xor(p0[r], off);
            p1[r] += __shfl_xor(p1[r], off);
        }
    }
    if (jc == 0) {
#pragma unroll
        for (int r = 0; r < 4; r++) {
            part[wv][quad * 4 + r][0] = p0[r];
            part[wv][quad * 4 + r][1] = p1[r];
        }
    }
    __syncthreads();
    if (tid < 32) {
        int rl = tid & 15, p = tid >> 4;
        int n = blockIdx.x * 32 + tid;
        if (n < NN) {
            float l0 = part[2 * p][rl][0] + part[2 * p + 1][rl][0] + sb2[0];
            float l1 = part[2 * p][rl][1] + part[2 * p + 1][rl][1] + sb2[1];
            if (flag[0] != 0) {
                u32 pack = (u32)f2bf(l0) | ((u32)f2bf(l1) << 16);
                *(u32*)((u16*)dout + LG_OFF + (size_t)n * 2) = pack;
            } else {
                float2 o = {l0, l1};
                *(float2*)((float*)dout + LG_OFF + (size_t)n * 2) = o;
            }
        }
    }
}

extern "C" void kernel_launch(void* const* d_in, const int* in_sizes, int n_in,
                              void* d_out, int out_size, void* d_ws, size_t ws_size,
                              hipStream_t stream) {
    const void* features = d_in[0];
    const int* ei = (const int*)d_in[1];
    const void* zin = d_in[2];

    char* w = (char*)d_ws;
    auto alloc = [&](size_t bytes) -> void* {
        void* p = (void*)w;
        w += (bytes + 255) & ~(size_t)255;
        return p;
    };
    u16* X0 = (u16*)alloc((size_t)NN * 128 * 2);
    u16* Tx1 = (u16*)alloc((size_t)NN * 128 * 2);
    u16* Tx2 = (u16*)alloc((size_t)NN * 128 * 2);
    u16* h0 = (u16*)alloc((size_t)NN * 64 * 2);
    u16* h1 = (u16*)alloc((size_t)NN * 64 * 2);
    u16* h2 = (u16*)alloc((size_t)NN * 64 * 2);
    u16* h3 = (u16*)alloc((size_t)NN * 64 * 2);
    float* ewf = (float*)alloc((size_t)EE * 4);
    uint2* csr_meta = (uint2*)alloc((size_t)EE * 8);
    float* deg = (float*)alloc((size_t)NN * 4);
    int* cnt = (int*)alloc((size_t)NN * 4);
    int* cursor = (int*)alloc((size_t)NN * 4);
    float* dis = (float*)alloc((size_t)NN * 4);
    int* offs = (int*)alloc((size_t)(NN + 1) * 4);
    u16* W2s = (u16*)alloc((size_t)16384 * 2);
    float* b2p = (float*)alloc((size_t)128 * 4);
    u16* W1c = (u16*)alloc((size_t)65536 * 2);
    float* w2p = (float*)alloc((size_t)512 * 4);
    float* b2p2 = (float*)alloc((size_t)2 * 4);
    float* wpad = (float*)alloc((size_t)OTOT * 4);
    int* flag = (int*)alloc(256);

    hipMemsetAsync(deg, 0, (size_t)((char*)dis - (char*)deg), stream);

    PtrTab tab;
    for (int i = 0; i < 20; i++) tab.p[i] = d_in[3 + i];

    k_detect<<<1, 256, 0, stream>>>((const u16*)features, flag);
    k_wconv<<<20, 256, 0, stream>>>(tab, flag, wpad);
    k_fold<<<33, 128, 0, stream>>>(wpad, W2s, b2p);
    k_foldc<<<65, 256, 0, stream>>>(wpad, W1c, w2p, b2p2);
    k_x0<<<3125, 256, 0, stream>>>(features, flag, X0);
    // 768 blocks = 256 CU x 3 resident blocks (launch_bounds(256,3)) -> no tail wave
    k_pae<<<768, 256, 0, stream>>>(zin, wpad, W2s, b2p, ei, flag, ewf, d_out, deg, cnt);
    k_scan<<<1, 1024, 0, stream>>>(cnt, deg, offs, dis);
    k_csr<<<EE / 256, 256, 0, stream>>>(ei, ewf, dis, offs, cursor, csr_meta);

    // layer 0 (F=128)
    k_prop<128><<<12500, 256, 0, stream>>>(X0, csr_meta, offs, Tx1, nullptr, 1.f, 0.f);
    k_prop<128><<<12500, 256, 0, stream>>>(Tx1, csr_meta, offs, Tx2, X0, 2.f, -1.f);
    k_gemm<128><<<1563, 256, 0, stream>>>(X0, Tx1, Tx2, wpad + OCH0, h0, d_out, 0, flag);
    // layer 1 (F=64)
    k_prop<64><<<12500, 256, 0, stream>>>(h0, csr_meta, offs, Tx1, nullptr, 1.f, 0.f);
    k_prop<64><<<12500, 256, 0, stream>>>(Tx1, csr_meta, offs, Tx2, h0, 2.f, -1.f);
    k_gemm<64><<<1563, 256, 0, stream>>>(h0, Tx1, Tx2, wpad + OCH1, h1, d_out, 64, flag);
    // layer 2
    k_prop<64><<<12500, 256, 0, stream>>>(h1, csr_meta, offs, Tx1, nullptr, 1.f, 0.f);
    k_prop<64><<<12500, 256, 0, stream>>>(Tx1, csr_meta, offs, Tx2, h1, 2.f, -1.f);
    k_gemm<64><<<1563, 256, 0, stream>>>(h1, Tx1, Tx2, wpad + OCH2, h2, d_out, 128, flag);
    // layer 3
    k_prop<64><<<12500, 256, 0, stream>>>(h2, csr_meta, offs, Tx1, nullptr, 1.f, 0.f);
    k_prop<64><<<12500, 256, 0, stream>>>(Tx1, csr_meta, offs, Tx2, h2, 2.f, -1.f);
    k_gemm<64><<<1563, 256, 0, stream>>>(h2, Tx1, Tx2, wpad + OCH3, h3, d_out, 192, flag);

    // fused classifier (z never materialized; k_cls2 folded in)
    k_cls<<<1563, 256, 0, stream>>>(h0, h1, h2, h3, W1c, wpad, w2p, b2p2, flag, d_out);
    (void)in_sizes; (void)n_in; (void)out_size; (void)ws_size;
}

// Round 3
// 1076.367 us; speedup vs baseline: 1.7964x; 1.2290x over previous
//
#include <hip/hip_runtime.h>

#define NN 50000
#define EE 1600000

using u16 = unsigned short;
using u32 = unsigned int;

typedef float f32x4 __attribute__((ext_vector_type(4)));
typedef __bf16 bf16x8 __attribute__((ext_vector_type(8)));
typedef unsigned short u16x8 __attribute__((ext_vector_type(8)));

struct alignas(8) U16x4 { u16 a, b, c, d; };
struct PtrTab { const void* p[20]; };

// canonical fp32 weight-pad offsets
#define OW1 0
#define OB1 768
#define OG 896
#define OBB 1024
#define ORM 1152
#define ORV 1280
#define OW2 1408
#define OB2 17792
#define OCH0 17920
#define OCH1 42496
#define OCH2 54784
#define OCH3 67072
#define OCW1 79360
#define OCB1 144896
#define OCG 145152
#define OCBB 145408
#define OCRM 145664
#define OCRV 145920
#define OCW2 146176
#define OCB2 146688
#define OTOT 146690

// element offsets within d_out (dtype-independent in elements)
#define LG_OFF ((size_t)NN * 256)
#define EW_OFF ((size_t)NN * 256 + (size_t)NN * 2)

__device__ __forceinline__ float bf2f(u16 u) { return __builtin_bit_cast(float, (u32)u << 16); }
__device__ __forceinline__ float bfl(u32 u) { return __builtin_bit_cast(float, u << 16); }
__device__ __forceinline__ float bfh(u32 u) { return __builtin_bit_cast(float, u & 0xffff0000u); }
__device__ __forceinline__ u16 f2bf(float f) {
    u32 u = __builtin_bit_cast(u32, f);
    return (u16)((u + 0x7fffu + ((u >> 16) & 1u)) >> 16);
}

// Input dtype detector: flag=1 -> bf16 inputs, 0 -> fp32 inputs.
__global__ __launch_bounds__(256) void k_detect(const u16* __restrict__ f, int* __restrict__ flag) {
    __shared__ int bad;
    if (threadIdx.x == 0) bad = 0;
    __syncthreads();
    u16 u = f[threadIdx.x];
    int e = (u >> 7) & 0xFF;
    if (e >= 0x90) atomicAdd(&bad, 1);
    __syncthreads();
    if (threadIdx.x == 0) flag[0] = (bad < 16) ? 1 : 0;
}

// Convert all 20 weight arrays into canonical fp32 pad.
__global__ __launch_bounds__(256) void k_wconv(PtrTab tab, const int* __restrict__ flag,
                                               float* __restrict__ wpad) {
    const int SZ[20] = {768, 128, 128, 128, 128, 128, 16384, 128, 24576, 12288, 12288, 12288,
                        65536, 256, 256, 256, 256, 256, 512, 2};
    const int OF[20] = {OW1, OB1, OG, OBB, ORM, ORV, OW2, OB2, OCH0, OCH1, OCH2, OCH3,
                        OCW1, OCB1, OCG, OCBB, OCRM, OCRV, OCW2, OCB2};
    int a = blockIdx.x;
    int n = SZ[a];
    float* dst = wpad + OF[a];
    if (flag[0] != 0) {
        const u16* s = (const u16*)tab.p[a];
        for (int i = threadIdx.x; i < n; i += 256) dst[i] = bf2f(s[i]);
    } else {
        const float* s = (const float*)tab.p[a];
        for (int i = threadIdx.x; i < n; i += 256) dst[i] = s[i];
    }
}

// Fold PAE BN into W2 (MFMA B-frag swizzled bf16) + b2'.
__global__ __launch_bounds__(128) void k_fold(const float* __restrict__ wpad,
                                              u16* __restrict__ W2s, float* __restrict__ b2p) {
    const float* g = wpad + OG;
    const float* b = wpad + OBB;
    const float* rm = wpad + ORM;
    const float* rv = wpad + ORV;
    const float* w2 = wpad + OW2;
    const float* b2 = wpad + OB2;
    int blk = blockIdx.x, tid = threadIdx.x;
    if (blk < 32) {
        int kc = blk >> 3, jt = blk & 7;
        int lane = tid & 63, jh = tid >> 6;
        for (int jj = 0; jj < 4; jj++) {
            int j = jh * 4 + jj;
            int k = kc * 32 + (lane >> 4) * 8 + j;
            int jcol = jt * 16 + (lane & 15);
            float s = g[k] * rsqrtf(rv[k] + 1e-5f);
            W2s[((kc * 8 + jt) * 64 + lane) * 8 + j] = f2bf(s * w2[k * 128 + jcol]);
        }
    } else {
        if (tid < 128) {
            int j = tid;
            float acc = b2[j];
            for (int k = 0; k < 128; k++) {
                float s = g[k] * rsqrtf(rv[k] + 1e-5f);
                float t = b[k] - rm[k] * s;
                acc += t * w2[k * 128 + j];
            }
            b2p[j] = acc;
        }
    }
}

// Fold classifier weights: W1c = cls_w1 as MFMA B-fragments (bf16, phase-sliced),
// w2p[j][c] = s_j * cls_w2[j][c], b2p2[c] = cls_b2[c] + sum_j t_j * cls_w2[j][c].
__global__ __launch_bounds__(256) void k_foldc(const float* __restrict__ wpad,
                                               u16* __restrict__ W1c, float* __restrict__ w2p,
                                               float* __restrict__ b2p2) {
    int tid = threadIdx.x;
    if (blockIdx.x < 64) {
        const float* w1 = wpad + OCW1;
        int base = blockIdx.x * 1024 + tid * 4;
#pragma unroll
        for (int u = 0; u < 4; u++) {
            int gi = base + u;
            int j = gi & 7;
            int lane = (gi >> 3) & 63;
            int ct = (gi >> 9) & 15;
            int kc2 = (gi >> 13) & 1;
            int l = gi >> 14;
            int k = l * 64 + kc2 * 32 + ((lane >> 4) & 3) * 8 + j;
            int col = ct * 16 + (lane & 15);
            W1c[gi] = f2bf(w1[k * 256 + col]);
        }
    } else {
        __shared__ float red[8];
        int j = tid;
        float s = wpad[OCG + j] * rsqrtf(wpad[OCRV + j] + 1e-5f);
        float t = wpad[OCBB + j] - wpad[OCRM + j] * s;
        float w0 = wpad[OCW2 + j * 2], w1v = wpad[OCW2 + j * 2 + 1];
        w2p[j * 2] = s * w0;
        w2p[j * 2 + 1] = s * w1v;
        float c0 = t * w0, c1 = t * w1v;
#pragma unroll
        for (int off = 1; off < 64; off <<= 1) {
            c0 += __shfl_xor(c0, off);
            c1 += __shfl_xor(c1, off);
        }
        int wv = tid >> 6, lane = tid & 63;
        if (lane == 0) { red[wv * 2] = c0; red[wv * 2 + 1] = c1; }
        __syncthreads();
        if (tid == 0) b2p2[0] = wpad[OCB2] + red[0] + red[2] + red[4] + red[6];
        if (tid == 1) b2p2[1] = wpad[OCB2 + 1] + red[1] + red[3] + red[5] + red[7];
    }
}

// Fold ChebConv weights into MFMA B-fragment order (bf16).
// Per array of K total k-rows (K=384 for layer0, 192 for layers1-3), N=64:
// Wf[((kt*4+ct)*64+lane)*8+jj] = bf16(W[kt*32 + ((lane>>4)&3)*8 + jj][ct*16 + (lane&15)])
// blocks 0..23 -> Wf0 (K=384); 24..35 -> Wf1; 36..47 -> Wf2; 48..59 -> Wf3.
__global__ __launch_bounds__(256) void k_foldw(const float* __restrict__ wpad,
                                               u16* __restrict__ Wf0, u16* __restrict__ Wf1,
                                               u16* __restrict__ Wf2, u16* __restrict__ Wf3) {
    int b = blockIdx.x, tid = threadIdx.x;
    const float* src;
    u16* dst;
    int nkt;
    if (b < 24)      { src = wpad + OCH0; dst = Wf0; nkt = 12; }
    else if (b < 36) { src = wpad + OCH1; dst = Wf1; b -= 24; nkt = 6; }
    else if (b < 48) { src = wpad + OCH2; dst = Wf2; b -= 36; nkt = 6; }
    else             { src = wpad + OCH3; dst = Wf3; b -= 48; nkt = 6; }
    int base = b * 1024 + tid * 4;
#pragma unroll
    for (int u = 0; u < 4; u++) {
        int gi = base + u;
        int jj = gi & 7;
        int lane = (gi >> 3) & 63;
        int ct = (gi >> 9) & 3;
        int kt = gi >> 11;
        if (kt < nkt) {
            int k = kt * 32 + ((lane >> 4) & 3) * 8 + jj;
            int col = ct * 16 + (lane & 15);
            dst[gi] = f2bf(src[k * 64 + col]);
        }
    }
}

// features (either dtype) -> bf16 X0.
__global__ __launch_bounds__(256) void k_x0(const void* __restrict__ feat, const int* __restrict__ flag,
                                            u16* __restrict__ X0) {
    int i = blockIdx.x * 256 + threadIdx.x;
    if (flag[0] != 0) {
        ((uint4*)X0)[i] = ((const uint4*)feat)[i];
    } else {
        const float4* f = (const float4*)feat;
        float4 a = f[2 * i], b = f[2 * i + 1];
        u16x8 o;
        o[0] = f2bf(a.x); o[1] = f2bf(a.y); o[2] = f2bf(a.z); o[3] = f2bf(a.w);
        o[4] = f2bf(b.x); o[5] = f2bf(b.y); o[6] = f2bf(b.z); o[7] = f2bf(b.w);
        ((uint4*)X0)[i] = __builtin_bit_cast(uint4, o);
    }
}

// PAE: A = relu(Z@W1+b1) on VALU (fragments staged once), H = A@W2' via MFMA.
// v3: launch_bounds(256,4) + grid 1024 = 4 blocks/CU (LDS 4x37.4KB = 149.5KB
// fits; VGPR 80 <= 128) -- occupancy 30.8% -> ~44%, VALUBusy 70% -> saturation.
__global__ __launch_bounds__(256, 4) void k_pae(const void* __restrict__ zin, const float* __restrict__ wpad,
                                                const u16* __restrict__ W2sg, const float* __restrict__ b2p,
                                                const int* __restrict__ ei, const int* __restrict__ flag,
                                                float* __restrict__ ewf, void* __restrict__ dout,
                                                float* __restrict__ deg, int* __restrict__ cnt) {
    __shared__ __align__(16) u16 sW2[16384];
    __shared__ __align__(16) float sW1k[1024];  // float m of row k at byte (k*32+m*4)^(((k>>3)&3)<<4)
    __shared__ float sB2[128];
    int tid = threadIdx.x;
    for (int i = tid; i < 8192; i += 256) ((u32*)sW2)[i] = ((const u32*)W2sg)[i];
    for (int i = tid; i < 1024; i += 256) {
        int k = i >> 3, m = i & 7;
        float v = 0.f;
        if (m < 6) v = wpad[OW1 + m * 128 + k];
        else if (m == 6) v = wpad[OB1 + k];
        int sw = ((k >> 3) & 3) << 4;
        *(float*)((char*)sW1k + ((k * 32 + m * 4) ^ sw)) = v;
    }
    if (tid < 128) sB2[tid] = b2p[tid];
    __syncthreads();

    bool isbf = flag[0] != 0;
    int wv = __builtin_amdgcn_readfirstlane(tid >> 6);
    int lane = tid & 63;
    int quad = lane >> 4, lrow = lane & 15, jc = lane & 15;
    int sq = quad << 4;  // sW1k swizzle constant for this lane's k range
    int gw = blockIdx.x * 4 + wv;
    const int ngroups = EE / 16;
    const int gstep = gridDim.x * 4;

    uint2 pb0, pb1, pb2;       // bf16 Z prefetch (24B row)
    float4 pf0, pf1, pf2;      // fp32 Z prefetch (48B row)
    if (gw < ngroups) {
        if (isbf) {
            const uint2* zp = (const uint2*)((const u16*)zin + (size_t)(gw * 16 + lrow) * 12);
            pb0 = zp[0]; pb1 = zp[1]; pb2 = zp[2];
        } else {
            const float4* zp = (const float4*)((const float*)zin + (size_t)(gw * 16 + lrow) * 12);
            pf0 = zp[0]; pf1 = zp[1]; pf2 = zp[2];
        }
    }

#pragma unroll 1
    for (int gidx = gw; gidx < ngroups; gidx += gstep) {
        int e0 = gidx * 16;
        float z1[6], z2[6];
        if (isbf) {
            z1[0] = bfl(pb0.x); z1[1] = bfh(pb0.x); z1[2] = bfl(pb0.y); z1[3] = bfh(pb0.y);
            z1[4] = bfl(pb1.x); z1[5] = bfh(pb1.x);
            z2[0] = bfl(pb1.y); z2[1] = bfh(pb1.y); z2[2] = bfl(pb2.x); z2[3] = bfh(pb2.x);
            z2[4] = bfl(pb2.y); z2[5] = bfh(pb2.y);
        } else {
            z1[0] = pf0.x; z1[1] = pf0.y; z1[2] = pf0.z; z1[3] = pf0.w; z1[4] = pf1.x; z1[5] = pf1.y;
            z2[0] = pf1.z; z2[1] = pf1.w; z2[2] = pf2.x; z2[3] = pf2.y; z2[4] = pf2.z; z2[5] = pf2.w;
        }
        // issue next group's Z loads now -- they complete under this group's compute
        int gn = gidx + gstep;
        if (gn < ngroups) {
            if (isbf) {
                const uint2* zp = (const uint2*)((const u16*)zin + (size_t)(gn * 16 + lrow) * 12);
                pb0 = zp[0]; pb1 = zp[1]; pb2 = zp[2];
            } else {
                const float4* zp = (const float4*)((const float*)zin + (size_t)(gn * 16 + lrow) * 12);
                pf0 = zp[0]; pf1 = zp[1]; pf2 = zp[2];
            }
        }
        // hoist epilogue row indices (were a cold global load after the MFMA loop)
        int rows[4];
        if (jc == 0) {
#pragma unroll
            for (int r = 0; r < 4; r++) rows[r] = ei[e0 + quad * 4 + r];
        }

        // Stage A fragments for all 4 kc chunks (32 VGPRs total)
        bf16x8 a1f[4], a2f[4];
#pragma unroll
        for (int kc = 0; kc < 4; kc++) {
            int kbase = kc * 32 + quad * 8;
            u32 r1[4], r2[4];
#pragma unroll
            for (int jh = 0; jh < 4; jh++) {
                int k = kbase + 2 * jh;
                const char* bp = (const char*)sW1k;
                float4 wa = *(const float4*)(bp + ((k * 32) ^ sq));
                float4 wb = *(const float4*)(bp + ((k * 32 + 16) ^ sq));
                float4 wc = *(const float4*)(bp + (((k + 1) * 32) ^ sq));
                float4 wd = *(const float4*)(bp + (((k + 1) * 32 + 16) ^ sq));
                float sA1 = wb.z, sA2 = wb.z, sB1 = wd.z, sB2v = wd.z;
                sA1 = fmaf(z1[0], wa.x, sA1); sA2 = fmaf(z2[0], wa.x, sA2);
                sA1 = fmaf(z1[1], wa.y, sA1); sA2 = fmaf(z2[1], wa.y, sA2);
                sA1 = fmaf(z1[2], wa.z, sA1); sA2 = fmaf(z2[2], wa.z, sA2);
                sA1 = fmaf(z1[3], wa.w, sA1); sA2 = fmaf(z2[3], wa.w, sA2);
                sA1 = fmaf(z1[4], wb.x, sA1); sA2 = fmaf(z2[4], wb.x, sA2);
                sA1 = fmaf(z1[5], wb.y, sA1); sA2 = fmaf(z2[5], wb.y, sA2);
                sB1 = fmaf(z1[0], wc.x, sB1); sB2v = fmaf(z2[0], wc.x, sB2v);
                sB1 = fmaf(z1[1], wc.y, sB1); sB2v = fmaf(z2[1], wc.y, sB2v);
                sB1 = fmaf(z1[2], wc.z, sB1); sB2v = fmaf(z2[2], wc.z, sB2v);
                sB1 = fmaf(z1[3], wc.w, sB1); sB2v = fmaf(z2[3], wc.w, sB2v);
                sB1 = fmaf(z1[4], wd.x, sB1); sB2v = fmaf(z2[4], wd.x, sB2v);
                sB1 = fmaf(z1[5], wd.y, sB1); sB2v = fmaf(z2[5], wd.y, sB2v);
                sA1 = fmaxf(sA1, 0.f); sA2 = fmaxf(sA2, 0.f);
                sB1 = fmaxf(sB1, 0.f); sB2v = fmaxf(sB2v, 0.f);
                u32 o1, o2;
                asm("v_cvt_pk_bf16_f32 %0, %1, %2" : "=v"(o1) : "v"(sA1), "v"(sB1));
                asm("v_cvt_pk_bf16_f32 %0, %1, %2" : "=v"(o2) : "v"(sA2), "v"(sB2v));
                r1[jh] = o1; r2[jh] = o2;
            }
            uint4 u1v = {r1[0], r1[1], r1[2], r1[3]};
            uint4 u2v = {r2[0], r2[1], r2[2], r2[3]};
            a1f[kc] = __builtin_bit_cast(bf16x8, u1v);
            a2f[kc] = __builtin_bit_cast(bf16x8, u2v);
        }

        float num[4] = {0, 0, 0, 0}, q1[4] = {0, 0, 0, 0}, q2[4] = {0, 0, 0, 0};
        // jt NOT unrolled: keeps ds_read hoisting bounded (spill guard).
#pragma unroll 1
        for (int jt = 0; jt < 8; jt++) {
            f32x4 acc1 = {0.f, 0.f, 0.f, 0.f}, acc2 = {0.f, 0.f, 0.f, 0.f};
#pragma unroll
            for (int kc = 0; kc < 4; kc++) {
                bf16x8 bb = *reinterpret_cast<const bf16x8*>(&sW2[((kc * 8 + jt) * 64 + lane) * 8]);
                acc1 = __builtin_amdgcn_mfma_f32_16x16x32_bf16(a1f[kc], bb, acc1, 0, 0, 0);
                acc2 = __builtin_amdgcn_mfma_f32_16x16x32_bf16(a2f[kc], bb, acc2, 0, 0, 0);
            }
            float bbias = sB2[jt * 16 + jc];
#pragma unroll
            for (int r = 0; r < 4; r++) {
                float h1 = acc1[r] + bbias;
                float h2 = acc2[r] + bbias;
                num[r] = fmaf(h1, h2, num[r]);
                q1[r] = fmaf(h1, h1, q1[r]);
                q2[r] = fmaf(h2, h2, q2[r]);
            }
        }
#pragma unroll
        for (int off = 1; off < 16; off <<= 1) {
#pragma unroll
            for (int r = 0; r < 4; r++) {
                num[r] += __shfl_xor(num[r], off);
                q1[r] += __shfl_xor(q1[r], off);
                q2[r] += __shfl_xor(q2[r], off);
            }
        }
        if (jc == 0) {
#pragma unroll
            for (int r = 0; r < 4; r++) {
                int e = e0 + quad * 4 + r;
                float den = fmaxf(sqrtf(q1[r]) * sqrtf(q2[r]), 1e-8f);
                float wgt = (num[r] / den + 1.f) * 0.5f;
                if (!(wgt == wgt)) wgt = 0.5f;  // NaN guard: makes failures localizable
                ewf[e] = wgt;
                if (isbf) ((u16*)dout)[EW_OFF + e] = f2bf(wgt);
                else ((float*)dout)[EW_OFF + e] = wgt;
                atomicAdd(deg + rows[r], wgt);
                atomicAdd(cnt + rows[r], 1);
            }
        }
    }
}

// Exclusive scan of cnt -> offs; fused dis = rsqrt(deg).
__global__ __launch_bounds__(1024) void k_scan(const int* __restrict__ cnt, const float* __restrict__ deg,
                                               int* __restrict__ offs, float* __restrict__ dis) {
    __shared__ int wsum[16];
    __shared__ int carry;
    int tid = threadIdx.x;
    int wv = tid >> 6, lane = tid & 63;
    if (tid == 0) carry = 0;
    __syncthreads();
    for (int c = 0; c < 49; c++) {
        int i = c * 1024 + tid;
        int v = (i < NN) ? cnt[i] : 0;
        if (i < NN) {
            float d = deg[i];
            dis[i] = d > 0.f ? rsqrtf(d) : 0.f;
        }
        int x = v;
#pragma unroll
        for (int off = 1; off < 64; off <<= 1) {
            int t = __shfl_up(x, off);
            if (lane >= off) x += t;
        }
        if (lane == 63) wsum[wv] = x;
        __syncthreads();
        if (tid < 16) {
            int s = wsum[tid];
#pragma unroll
            for (int off = 1; off < 16; off <<= 1) {
                int t = __shfl_up(s, off, 16);
                if (tid >= off) s += t;
            }
            wsum[tid] = s;
        }
        __syncthreads();
        int base = carry + (wv > 0 ? wsum[wv - 1] : 0);
        if (i < NN) offs[i] = base + x - v;
        __syncthreads();
        if (tid == 0) carry += wsum[15];
        __syncthreads();
    }
    if (tid == 0) offs[NN] = carry;
}

// CSR scatter: fused (col, norm) uint2 metadata — one 8B load per edge in prop.
__global__ __launch_bounds__(256) void k_csr(const int* __restrict__ ei, const float* __restrict__ ewf,
                                             const float* __restrict__ dis, const int* __restrict__ offs,
                                             int* __restrict__ cursor, uint2* __restrict__ csr_meta) {
    int e = blockIdx.x * 256 + threadIdx.x;
    int r = ei[e], c = ei[EE + e];
    float wgt = ewf[e];
    int pos = offs[r] + atomicAdd(cursor + r, 1);
    float nrm = -dis[r] * wgt * dis[c];
    csr_meta[pos] = make_uint2((u32)c, __builtin_bit_cast(u32, nrm));
}

// Propagation over bf16 node features, fp32 accumulate. One wave per node.
template <int F>
__global__ __launch_bounds__(256) void k_prop(const u16* __restrict__ src, const uint2* __restrict__ csr_meta,
                                              const int* __restrict__ offs,
                                              u16* __restrict__ out, const u16* __restrict__ base,
                                              float alpha, float beta) {
    int lane = threadIdx.x & 63;
    int wv = threadIdx.x >> 6;
    int node = blockIdx.x * 4 + wv;
    int s = offs[node], e = offs[node + 1];

    if (F == 128) {
        int sub = lane >> 4;   // which of 4 edges this lane group handles
        int fl = lane & 15;    // position within the feature row
        const uint4* sv = (const uint4*)src;  // row = 16 uint4 (128 bf16)
        float a[8] = {0, 0, 0, 0, 0, 0, 0, 0};
        int p = s;
        for (; p + 7 < e; p += 8) {
            uint2 m0 = csr_meta[p + sub];
            uint2 m1 = csr_meta[p + 4 + sub];
            uint4 v0 = sv[(size_t)m0.x * 16 + fl];
            uint4 v1 = sv[(size_t)m1.x * 16 + fl];
            float w0 = __builtin_bit_cast(float, m0.y);
            float w1 = __builtin_bit_cast(float, m1.y);
            a[0] = fmaf(w0, bfl(v0.x), a[0]); a[1] = fmaf(w0, bfh(v0.x), a[1]);
            a[2] = fmaf(w0, bfl(v0.y), a[2]); a[3] = fmaf(w0, bfh(v0.y), a[3]);
            a[4] = fmaf(w0, bfl(v0.z), a[4]); a[5] = fmaf(w0, bfh(v0.z), a[5]);
            a[6] = fmaf(w0, bfl(v0.w), a[6]); a[7] = fmaf(w0, bfh(v0.w), a[7]);
            a[0] = fmaf(w1, bfl(v1.x), a[0]); a[1] = fmaf(w1, bfh(v1.x), a[1]);
            a[2] = fmaf(w1, bfl(v1.y), a[2]); a[3] = fmaf(w1, bfh(v1.y), a[3]);
            a[4] = fmaf(w1, bfl(v1.z), a[4]); a[5] = fmaf(w1, bfh(v1.z), a[5]);
            a[6] = fmaf(w1, bfl(v1.w), a[6]); a[7] = fmaf(w1, bfh(v1.w), a[7]);
        }
        if (p + 3 < e) {
            uint2 m0 = csr_meta[p + sub];
            uint4 v0 = sv[(size_t)m0.x * 16 + fl];
            float w0 = __builtin_bit_cast(float, m0.y);
            a[0] = fmaf(w0, bfl(v0.x), a[0]); a[1] = fmaf(w0, bfh(v0.x), a[1]);
            a[2] = fmaf(w0, bfl(v0.y), a[2]); a[3] = fmaf(w0, bfh(v0.y), a[3]);
            a[4] = fmaf(w0, bfl(v0.z), a[4]); a[5] = fmaf(w0, bfh(v0.z), a[5]);
            a[6] = fmaf(w0, bfl(v0.w), a[6]); a[7] = fmaf(w0, bfh(v0.w), a[7]);
            p += 4;
        }
#pragma unroll
        for (int i = 0; i < 8; i++) {
            a[i] += __shfl_xor(a[i], 16);
            a[i] += __shfl_xor(a[i], 32);
        }
        if (sub == 0) {
            for (; p < e; p++) {
                uint2 m0 = csr_meta[p];
                uint4 v = sv[(size_t)m0.x * 16 + fl];
                float w = __builtin_bit_cast(float, m0.y);
                a[0] = fmaf(w, bfl(v.x), a[0]); a[1] = fmaf(w, bfh(v.x), a[1]);
                a[2] = fmaf(w, bfl(v.y), a[2]); a[3] = fmaf(w, bfh(v.y), a[3]);
                a[4] = fmaf(w, bfl(v.z), a[4]); a[5] = fmaf(w, bfh(v.z), a[5]);
                a[6] = fmaf(w, bfl(v.w), a[6]); a[7] = fmaf(w, bfh(v.w), a[7]);
            }
            float o[8];
#pragma unroll
            for (int i = 0; i < 8; i++) o[i] = alpha * a[i];
            if (beta != 0.f) {
                uint4 bv = ((const uint4*)base)[(size_t)node * 16 + fl];
                o[0] = fmaf(beta, bfl(bv.x), o[0]); o[1] = fmaf(beta, bfh(bv.x), o[1]);
                o[2] = fmaf(beta, bfl(bv.y), o[2]); o[3] = fmaf(beta, bfh(bv.y), o[3]);
                o[4] = fmaf(beta, bfl(bv.z), o[4]); o[5] = fmaf(beta, bfh(bv.z), o[5]);
                o[6] = fmaf(beta, bfl(bv.w), o[6]); o[7] = fmaf(beta, bfh(bv.w), o[7]);
            }
            uint4 ov;
            ov.x = (u32)f2bf(o[0]) | ((u32)f2bf(o[1]) << 16);
            ov.y = (u32)f2bf(o[2]) | ((u32)f2bf(o[3]) << 16);
            ov.z = (u32)f2bf(o[4]) | ((u32)f2bf(o[5]) << 16);
            ov.w = (u32)f2bf(o[6]) | ((u32)f2bf(o[7]) << 16);
            ((uint4*)out)[(size_t)node * 16 + fl] = ov;
        }
    } else {
        int sub = lane >> 3;   // which of 8 edges this lane group handles
        int fl = lane & 7;     // position within the feature row (uint4 units)
        const uint4* sv = (const uint4*)src;  // row = 8 uint4 (64 bf16)
        float a[8] = {0, 0, 0, 0, 0, 0, 0, 0};
        int p = s;
        for (; p + 15 < e; p += 16) {
            uint2 m0 = csr_meta[p + sub];
            uint2 m1 = csr_meta[p + 8 + sub];
            uint4 v0 = sv[(size_t)m0.x * 8 + fl];
            uint4 v1 = sv[(size_t)m1.x * 8 + fl];
            float w0 = __builtin_bit_cast(float, m0.y);
            float w1 = __builtin_bit_cast(float, m1.y);
            a[0] = fmaf(w0, bfl(v0.x), a[0]); a[1] = fmaf(w0, bfh(v0.x), a[1]);
            a[2] = fmaf(w0, bfl(v0.y), a[2]); a[3] = fmaf(w0, bfh(v0.y), a[3]);
            a[4] = fmaf(w0, bfl(v0.z), a[4]); a[5] = fmaf(w0, bfh(v0.z), a[5]);
            a[6] = fmaf(w0, bfl(v0.w), a[6]); a[7] = fmaf(w0, bfh(v0.w), a[7]);
            a[0] = fmaf(w1, bfl(v1.x), a[0]); a[1] = fmaf(w1, bfh(v1.x), a[1]);
            a[2] = fmaf(w1, bfl(v1.y), a[2]); a[3] = fmaf(w1, bfh(v1.y), a[3]);
            a[4] = fmaf(w1, bfl(v1.z), a[4]); a[5] = fmaf(w1, bfh(v1.z), a[5]);
            a[6] = fmaf(w1, bfl(v1.w), a[6]); a[7] = fmaf(w1, bfh(v1.w), a[7]);
        }
        if (p + 7 < e) {
            uint2 m0 = csr_meta[p + sub];
            uint4 v0 = sv[(size_t)m0.x * 8 + fl];
            float w0 = __builtin_bit_cast(float, m0.y);
            a[0] = fmaf(w0, bfl(v0.x), a[0]); a[1] = fmaf(w0, bfh(v0.x), a[1]);
            a[2] = fmaf(w0, bfl(v0.y), a[2]); a[3] = fmaf(w0, bfh(v0.y), a[3]);
            a[4] = fmaf(w0, bfl(v0.z), a[4]); a[5] = fmaf(w0, bfh(v0.z), a[5]);
            a[6] = fmaf(w0, bfl(v0.w), a[6]); a[7] = fmaf(w0, bfh(v0.w), a[7]);
            p += 8;
        }
#pragma unroll
        for (int i = 0; i < 8; i++) {
            a[i] += __shfl_xor(a[i], 8);
            a[i] += __shfl_xor(a[i], 16);
            a[i] += __shfl_xor(a[i], 32);
        }
        if (sub == 0) {
            for (; p < e; p++) {
                uint2 m0 = csr_meta[p];
                uint4 v = sv[(size_t)m0.x * 8 + fl];
                float w = __builtin_bit_cast(float, m0.y);
                a[0] = fmaf(w, bfl(v.x), a[0]); a[1] = fmaf(w, bfh(v.x), a[1]);
                a[2] = fmaf(w, bfl(v.y), a[2]); a[3] = fmaf(w, bfh(v.y), a[3]);
                a[4] = fmaf(w, bfl(v.z), a[4]); a[5] = fmaf(w, bfh(v.z), a[5]);
                a[6] = fmaf(w, bfl(v.w), a[6]); a[7] = fmaf(w, bfh(v.w), a[7]);
            }
            float o[8];
#pragma unroll
            for (int i = 0; i < 8; i++) o[i] = alpha * a[i];
            if (beta != 0.f) {
                uint4 bv = ((const uint4*)base)[(size_t)node * 8 + fl];
                o[0] = fmaf(beta, bfl(bv.x), o[0]); o[1] = fmaf(beta, bfh(bv.x), o[1]);
                o[2] = fmaf(beta, bfl(bv.y), o[2]); o[3] = fmaf(beta, bfh(bv.y), o[3]);
                o[4] = fmaf(beta, bfl(bv.z), o[4]); o[5] = fmaf(beta, bfh(bv.z), o[5]);
                o[6] = fmaf(beta, bfl(bv.w), o[6]); o[7] = fmaf(beta, bfh(bv.w), o[7]);
            }
            uint4 ov;
            ov.x = (u32)f2bf(o[0]) | ((u32)f2bf(o[1]) << 16);
            ov.y = (u32)f2bf(o[2]) | ((u32)f2bf(o[3]) << 16);
            ov.z = (u32)f2bf(o[4]) | ((u32)f2bf(o[5]) << 16);
            ov.w = (u32)f2bf(o[6]) | ((u32)f2bf(o[7]) << 16);
            ((uint4*)out)[(size_t)node * 8 + fl] = ov;
        }
    }
}

// ChebConv mix via MFMA -> bf16 h + jk slice (out dtype).
// Block = 32 rows; wave wv: rows (wv>>1)*16, cols (wv&1)*32 (2 col-tiles).
// B-fragments (k_foldw order) staged once in LDS; A-fragments prefetched to
// registers (KT uint4/lane), then KT x 2 MFMA. relu in epilogue.
template <int F>
__global__ __launch_bounds__(256) void k_gemm(const u16* __restrict__ X0, const u16* __restrict__ X1,
                                              const u16* __restrict__ X2, const u16* __restrict__ Wf,
                                              u16* __restrict__ Hout, void* __restrict__ jk, int jkoff,
                                              const int* __restrict__ flag) {
    constexpr int KT = (3 * F) / 32;  // 12 (F=128) or 6 (F=64)
    __shared__ __align__(16) u16 sB[KT * 4 * 64 * 8];
    int tid = threadIdx.x;
    for (int i = tid; i < KT * 4 * 64 * 4; i += 256) ((u32*)sB)[i] = ((const u32*)Wf)[i];
    __syncthreads();

    bool isbf = flag[0] != 0;
    int wv = __builtin_amdgcn_readfirstlane(tid >> 6);
    int lane = tid & 63;
    int quad = lane >> 4, jc = lane & 15;
    int pair = wv >> 1;   // row group
    int half = wv & 1;    // column half (32 cols)
    int nb = blockIdx.x * 32 + pair * 16;
    int row = nb + jc;
    if (row > NN - 1) row = NN - 1;

    // prefetch all A-fragments (row = lane&15, k = kt*32 + quad*8 + j)
    uint4 av[KT];
#pragma unroll
    for (int kt = 0; kt < KT; kt++) {
        int kg = kt * 32 + quad * 8;
        const u16* Xp;
        int kk;
        if (kg < F) { Xp = X0; kk = kg; }
        else if (kg < 2 * F) { Xp = X1; kk = kg - F; }
        else { Xp = X2; kk = kg - 2 * F; }
        av[kt] = *(const uint4*)(Xp + (size_t)row * F + kk);
    }

    f32x4 acc0 = {0.f, 0.f, 0.f, 0.f}, acc1 = {0.f, 0.f, 0.f, 0.f};
#pragma unroll
    for (int kt = 0; kt < KT; kt++) {
        bf16x8 af = __builtin_bit_cast(bf16x8, av[kt]);
        bf16x8 b0 = *reinterpret_cast<const bf16x8*>(&sB[((kt * 4 + half * 2 + 0) * 64 + lane) * 8]);
        bf16x8 b1 = *reinterpret_cast<const bf16x8*>(&sB[((kt * 4 + half * 2 + 1) * 64 + lane) * 8]);
        acc0 = __builtin_amdgcn_mfma_f32_16x16x32_bf16(af, b0, acc0, 0, 0, 0);
        acc1 = __builtin_amdgcn_mfma_f32_16x16x32_bf16(af, b1, acc1, 0, 0, 0);
    }

#pragma unroll
    for (int ct = 0; ct < 2; ct++) {
        f32x4 a = ct ? acc1 : acc0;
        int j = (half * 2 + ct) * 16 + jc;
#pragma unroll
        for (int r = 0; r < 4; r++) {
            int n = nb + quad * 4 + r;
            if (n < NN) {
                float v = fmaxf(a[r], 0.f);
                Hout[(size_t)n * 64 + j] = f2bf(v);
                if (isbf) ((u16*)jk)[(size_t)n * 256 + jkoff + j] = f2bf(v);
                else ((float*)jk)[(size_t)n * 256 + jkoff + j] = v;
            }
        }
    }
}

// Fused classifier: logit = (relu(jk@W1+b1)*s+t)@w2 + b2, z never materialized.
__global__ __launch_bounds__(256) void k_cls(const u16* __restrict__ h0, const u16* __restrict__ h1,
                                             const u16* __restrict__ h2, const u16* __restrict__ h3,
                                             const u16* __restrict__ W1c, const float* __restrict__ wpad,
                                             const float* __restrict__ w2p, const float* __restrict__ b2p2,
                                             const int* __restrict__ flag, void* __restrict__ dout) {
    __shared__ __align__(16) u16 sB[16384];  // one phase slice of W1c (32KB)
    __shared__ float sb1[256];
    __shared__ float sw2[512];
    __shared__ float sb2[2];
    __shared__ float part[4][16][2];
    int tid = threadIdx.x;
    if (tid < 256) sb1[tid] = wpad[OCB1 + tid];
    for (int i = tid; i < 512; i += 256) sw2[i] = w2p[i];
    if (tid < 2) sb2[tid] = b2p2[tid];

    int wv = __builtin_amdgcn_readfirstlane(tid >> 6);
    int lane = tid & 63;
    int quad = lane >> 4, jc = lane & 15;
    int pair = wv >> 1;      // row group (0/1)
    int half = wv & 1;       // column half (0/1)
    int nb = blockIdx.x * 32 + pair * 16;

    f32x4 acc[8] = {{0.f, 0.f, 0.f, 0.f}, {0.f, 0.f, 0.f, 0.f}, {0.f, 0.f, 0.f, 0.f}, {0.f, 0.f, 0.f, 0.f},
                    {0.f, 0.f, 0.f, 0.f}, {0.f, 0.f, 0.f, 0.f}, {0.f, 0.f, 0.f, 0.f}, {0.f, 0.f, 0.f, 0.f}};
    const u16* hs[4] = {h0, h1, h2, h3};

    int row = nb + jc;
    if (row > NN - 1) row = NN - 1;

#pragma unroll 1
    for (int l = 0; l < 4; l++) {
        __syncthreads();
        const u32* src = (const u32*)W1c + l * 8192;
        for (int i = tid; i < 8192; i += 256) ((u32*)sB)[i] = src[i];
        __syncthreads();
        const uint4* rp = (const uint4*)(hs[l] + (size_t)row * 64);
        uint4 a0u = rp[quad], a1u = rp[4 + quad];
        bf16x8 af0 = __builtin_bit_cast(bf16x8, a0u);
        bf16x8 af1 = __builtin_bit_cast(bf16x8, a1u);
#pragma unroll
        for (int jt = 0; jt < 8; jt++) {
            int ct = half * 8 + jt;
            bf16x8 b0 = *reinterpret_cast<const bf16x8*>(&sB[((0 * 16 + ct) * 64 + lane) * 8]);
            bf16x8 b1f = *reinterpret_cast<const bf16x8*>(&sB[((1 * 16 + ct) * 64 + lane) * 8]);
            acc[jt] = __builtin_amdgcn_mfma_f32_16x16x32_bf16(af0, b0, acc[jt], 0, 0, 0);
            acc[jt] = __builtin_amdgcn_mfma_f32_16x16x32_bf16(af1, b1f, acc[jt], 0, 0, 0);
        }
    }

    // epilogue: relu(acc+b1) dot w2' -> per-row logit partials
    float p0[4] = {0, 0, 0, 0}, p1[4] = {0, 0, 0, 0};
#pragma unroll
    for (int jt = 0; jt < 8; jt++) {
        int j = (half * 8 + jt) * 16 + jc;
        float b1v = sb1[j], wa = sw2[2 * j], wb = sw2[2 * j + 1];
#pragma unroll
        for (int r = 0; r < 4; r++) {
            float h = fmaxf(acc[jt][r] + b1v, 0.f);
            p0[r] = fmaf(h, wa, p0[r]);
            p1[r] = fmaf(h, wb, p1[r]);
        }
    }
#pragma unroll
    for (int off = 1; off < 16; off <<= 1) {
#pragma unroll
        for (int r = 0; r < 4; r++) {
            p0[r] += __shfl_xor(p0[r], off);
            p1[r] += __shfl_xor(p1[r], off);
        }
    }
    if (jc == 0) {
#pragma unroll
        for (int r = 0; r < 4; r++) {
            part[wv][quad * 4 + r][0] = p0[r];
            part[wv][quad * 4 + r][1] = p1[r];
        }
    }
    __syncthreads();
    if (tid < 32) {
        int rl = tid & 15, p = tid >> 4;
        int n = blockIdx.x * 32 + tid;
        if (n < NN) {
            float l0 = part[2 * p][rl][0] + part[2 * p + 1][rl][0] + sb2[0];
            float l1 = part[2 * p][rl][1] + part[2 * p + 1][rl][1] + sb2[1];
            if (flag[0] != 0) {
                u32 pack = (u32)f2bf(l0) | ((u32)f2bf(l1) << 16);
                *(u32*)((u16*)dout + LG_OFF + (size_t)n * 2) = pack;
            } else {
                float2 o = {l0, l1};
                *(float2*)((float*)dout + LG_OFF + (size_t)n * 2) = o;
            }
        }
    }
}

extern "C" void kernel_launch(void* const* d_in, const int* in_sizes, int n_in,
                              void* d_out, int out_size, void* d_ws, size_t ws_size,
                              hipStream_t stream) {
    const void* features = d_in[0];
    const int* ei = (const int*)d_in[1];
    const void* zin = d_in[2];

    char* w = (char*)d_ws;
    auto alloc = [&](size_t bytes) -> void* {
        void* p = (void*)w;
        w += (bytes + 255) & ~(size_t)255;
        return p;
    };
    u16* X0 = (u16*)alloc((size_t)NN * 128 * 2);
    u16* Tx1 = (u16*)alloc((size_t)NN * 128 * 2);
    u16* Tx2 = (u16*)alloc((size_t)NN * 128 * 2);
    u16* h0 = (u16*)alloc((size_t)NN * 64 * 2);
    u16* h1 = (u16*)alloc((size_t)NN * 64 * 2);
    u16* h2 = (u16*)alloc((size_t)NN * 64 * 2);
    u16* h3 = (u16*)alloc((size_t)NN * 64 * 2);
    float* ewf = (float*)alloc((size_t)EE * 4);
    uint2* csr_meta = (uint2*)alloc((size_t)EE * 8);
    float* deg = (float*)alloc((size_t)NN * 4);
    int* cnt = (int*)alloc((size_t)NN * 4);
    int* cursor = (int*)alloc((size_t)NN * 4);
    float* dis = (float*)alloc((size_t)NN * 4);
    int* offs = (int*)alloc((size_t)(NN + 1) * 4);
    u16* W2s = (u16*)alloc((size_t)16384 * 2);
    float* b2p = (float*)alloc((size_t)128 * 4);
    u16* W1c = (u16*)alloc((size_t)65536 * 2);
    float* w2p = (float*)alloc((size_t)512 * 4);
    float* b2p2 = (float*)alloc((size_t)2 * 4);
    u16* Wf0 = (u16*)alloc((size_t)24576 * 2);
    u16* Wf1 = (u16*)alloc((size_t)12288 * 2);
    u16* Wf2 = (u16*)alloc((size_t)12288 * 2);
    u16* Wf3 = (u16*)alloc((size_t)12288 * 2);
    float* wpad = (float*)alloc((size_t)OTOT * 4);
    int* flag = (int*)alloc(256);

    hipMemsetAsync(deg, 0, (size_t)((char*)dis - (char*)deg), stream);

    PtrTab tab;
    for (int i = 0; i < 20; i++) tab.p[i] = d_in[3 + i];

    k_detect<<<1, 256, 0, stream>>>((const u16*)features, flag);
    k_wconv<<<20, 256, 0, stream>>>(tab, flag, wpad);
    k_fold<<<33, 128, 0, stream>>>(wpad, W2s, b2p);
    k_foldc<<<65, 256, 0, stream>>>(wpad, W1c, w2p, b2p2);
    k_foldw<<<60, 256, 0, stream>>>(wpad, Wf0, Wf1, Wf2, Wf3);
    k_x0<<<3125, 256, 0, stream>>>(features, flag, X0);
    // 1024 blocks = 256 CU x 4 resident blocks (launch_bounds(256,4), LDS 4x37.4KB fits)
    k_pae<<<1024, 256, 0, stream>>>(zin, wpad, W2s, b2p, ei, flag, ewf, d_out, deg, cnt);
    k_scan<<<1, 1024, 0, stream>>>(cnt, deg, offs, dis);
    k_csr<<<EE / 256, 256, 0, stream>>>(ei, ewf, dis, offs, cursor, csr_meta);

    // layer 0 (F=128)
    k_prop<128><<<12500, 256, 0, stream>>>(X0, csr_meta, offs, Tx1, nullptr, 1.f, 0.f);
    k_prop<128><<<12500, 256, 0, stream>>>(Tx1, csr_meta, offs, Tx2, X0, 2.f, -1.f);
    k_gemm<128><<<1563, 256, 0, stream>>>(X0, Tx1, Tx2, Wf0, h0, d_out, 0, flag);
    // layer 1 (F=64)
    k_prop<64><<<12500, 256, 0, stream>>>(h0, csr_meta, offs, Tx1, nullptr, 1.f, 0.f);
    k_prop<64><<<12500, 256, 0, stream>>>(Tx1, csr_meta, offs, Tx2, h0, 2.f, -1.f);
    k_gemm<64><<<1563, 256, 0, stream>>>(h0, Tx1, Tx2, Wf1, h1, d_out, 64, flag);
    // layer 2
    k_prop<64><<<12500, 256, 0, stream>>>(h1, csr_meta, offs, Tx1, nullptr, 1.f, 0.f);
    k_prop<64><<<12500, 256, 0, stream>>>(Tx1, csr_meta, offs, Tx2, h1, 2.f, -1.f);
    k_gemm<64><<<1563, 256, 0, stream>>>(h1, Tx1, Tx2, Wf2, h2, d_out, 128, flag);
    // layer 3
    k_prop<64><<<12500, 256, 0, stream>>>(h2, csr_meta, offs, Tx1, nullptr, 1.f, 0.f);
    k_prop<64><<<12500, 256, 0, stream>>>(Tx1, csr_meta, offs, Tx2, h2, 2.f, -1.f);
    k_gemm<64><<<1563, 256, 0, stream>>>(h2, Tx1, Tx2, Wf3, h3, d_out, 192, flag);

    // fused classifier (z never materialized)
    k_cls<<<1563, 256, 0, stream>>>(h0, h1, h2, h3, W1c, wpad, w2p, b2p2, flag, d_out);
    (void)in_sizes; (void)n_in; (void)out_size; (void)ws_size;
}

// Round 4
// 1028.030 us; speedup vs baseline: 1.8809x; 1.0470x over previous
//
#include <hip/hip_runtime.h>

#define NN 50000
#define EE 1600000

using u16 = unsigned short;
using u32 = unsigned int;

typedef float f32x4 __attribute__((ext_vector_type(4)));
typedef float f32x2 __attribute__((ext_vector_type(2)));
typedef __bf16 bf16x8 __attribute__((ext_vector_type(8)));
typedef unsigned short u16x8 __attribute__((ext_vector_type(8)));

struct alignas(8) U16x4 { u16 a, b, c, d; };
struct PtrTab { const void* p[20]; };

// canonical fp32 weight-pad offsets
#define OW1 0
#define OB1 768
#define OG 896
#define OBB 1024
#define ORM 1152
#define ORV 1280
#define OW2 1408
#define OB2 17792
#define OCH0 17920
#define OCH1 42496
#define OCH2 54784
#define OCH3 67072
#define OCW1 79360
#define OCB1 144896
#define OCG 145152
#define OCBB 145408
#define OCRM 145664
#define OCRV 145920
#define OCW2 146176
#define OCB2 146688
#define OTOT 146690

// element offsets within d_out (dtype-independent in elements)
#define LG_OFF ((size_t)NN * 256)
#define EW_OFF ((size_t)NN * 256 + (size_t)NN * 2)

__device__ __forceinline__ float bf2f(u16 u) { return __builtin_bit_cast(float, (u32)u << 16); }
__device__ __forceinline__ float bfl(u32 u) { return __builtin_bit_cast(float, u << 16); }
__device__ __forceinline__ float bfh(u32 u) { return __builtin_bit_cast(float, u & 0xffff0000u); }
__device__ __forceinline__ u16 f2bf(float f) {
    u32 u = __builtin_bit_cast(u32, f);
    return (u16)((u + 0x7fffu + ((u >> 16) & 1u)) >> 16);
}

// Input dtype detector: flag=1 -> bf16 inputs, 0 -> fp32 inputs.
__global__ __launch_bounds__(256) void k_detect(const u16* __restrict__ f, int* __restrict__ flag) {
    __shared__ int bad;
    if (threadIdx.x == 0) bad = 0;
    __syncthreads();
    u16 u = f[threadIdx.x];
    int e = (u >> 7) & 0xFF;
    if (e >= 0x90) atomicAdd(&bad, 1);
    __syncthreads();
    if (threadIdx.x == 0) flag[0] = (bad < 16) ? 1 : 0;
}

// Convert all 20 weight arrays into canonical fp32 pad.
__global__ __launch_bounds__(256) void k_wconv(PtrTab tab, const int* __restrict__ flag,
                                               float* __restrict__ wpad) {
    const int SZ[20] = {768, 128, 128, 128, 128, 128, 16384, 128, 24576, 12288, 12288, 12288,
                        65536, 256, 256, 256, 256, 256, 512, 2};
    const int OF[20] = {OW1, OB1, OG, OBB, ORM, ORV, OW2, OB2, OCH0, OCH1, OCH2, OCH3,
                        OCW1, OCB1, OCG, OCBB, OCRM, OCRV, OCW2, OCB2};
    int a = blockIdx.x;
    int n = SZ[a];
    float* dst = wpad + OF[a];
    if (flag[0] != 0) {
        const u16* s = (const u16*)tab.p[a];
        for (int i = threadIdx.x; i < n; i += 256) dst[i] = bf2f(s[i]);
    } else {
        const float* s = (const float*)tab.p[a];
        for (int i = threadIdx.x; i < n; i += 256) dst[i] = s[i];
    }
}

// Fold PAE BN into W2 (MFMA B-frag swizzled bf16) + b2'.
__global__ __launch_bounds__(128) void k_fold(const float* __restrict__ wpad,
                                              u16* __restrict__ W2s, float* __restrict__ b2p) {
    const float* g = wpad + OG;
    const float* b = wpad + OBB;
    const float* rm = wpad + ORM;
    const float* rv = wpad + ORV;
    const float* w2 = wpad + OW2;
    const float* b2 = wpad + OB2;
    int blk = blockIdx.x, tid = threadIdx.x;
    if (blk < 32) {
        int kc = blk >> 3, jt = blk & 7;
        int lane = tid & 63, jh = tid >> 6;
        for (int jj = 0; jj < 4; jj++) {
            int j = jh * 4 + jj;
            int k = kc * 32 + (lane >> 4) * 8 + j;
            int jcol = jt * 16 + (lane & 15);
            float s = g[k] * rsqrtf(rv[k] + 1e-5f);
            W2s[((kc * 8 + jt) * 64 + lane) * 8 + j] = f2bf(s * w2[k * 128 + jcol]);
        }
    } else {
        if (tid < 128) {
            int j = tid;
            float acc = b2[j];
            for (int k = 0; k < 128; k++) {
                float s = g[k] * rsqrtf(rv[k] + 1e-5f);
                float t = b[k] - rm[k] * s;
                acc += t * w2[k * 128 + j];
            }
            b2p[j] = acc;
        }
    }
}

// Fold classifier weights: W1c = cls_w1 as MFMA B-fragments (bf16, phase-sliced),
// w2p[j][c] = s_j * cls_w2[j][c], b2p2[c] = cls_b2[c] + sum_j t_j * cls_w2[j][c].
__global__ __launch_bounds__(256) void k_foldc(const float* __restrict__ wpad,
                                               u16* __restrict__ W1c, float* __restrict__ w2p,
                                               float* __restrict__ b2p2) {
    int tid = threadIdx.x;
    if (blockIdx.x < 64) {
        const float* w1 = wpad + OCW1;
        int base = blockIdx.x * 1024 + tid * 4;
#pragma unroll
        for (int u = 0; u < 4; u++) {
            int gi = base + u;
            int j = gi & 7;
            int lane = (gi >> 3) & 63;
            int ct = (gi >> 9) & 15;
            int kc2 = (gi >> 13) & 1;
            int l = gi >> 14;
            int k = l * 64 + kc2 * 32 + ((lane >> 4) & 3) * 8 + j;
            int col = ct * 16 + (lane & 15);
            W1c[gi] = f2bf(w1[k * 256 + col]);
        }
    } else {
        __shared__ float red[8];
        int j = tid;
        float s = wpad[OCG + j] * rsqrtf(wpad[OCRV + j] + 1e-5f);
        float t = wpad[OCBB + j] - wpad[OCRM + j] * s;
        float w0 = wpad[OCW2 + j * 2], w1v = wpad[OCW2 + j * 2 + 1];
        w2p[j * 2] = s * w0;
        w2p[j * 2 + 1] = s * w1v;
        float c0 = t * w0, c1 = t * w1v;
#pragma unroll
        for (int off = 1; off < 64; off <<= 1) {
            c0 += __shfl_xor(c0, off);
            c1 += __shfl_xor(c1, off);
        }
        int wv = tid >> 6, lane = tid & 63;
        if (lane == 0) { red[wv * 2] = c0; red[wv * 2 + 1] = c1; }
        __syncthreads();
        if (tid == 0) b2p2[0] = wpad[OCB2] + red[0] + red[2] + red[4] + red[6];
        if (tid == 1) b2p2[1] = wpad[OCB2 + 1] + red[1] + red[3] + red[5] + red[7];
    }
}

// Fold ChebConv weights into MFMA B-fragment order (bf16).
__global__ __launch_bounds__(256) void k_foldw(const float* __restrict__ wpad,
                                               u16* __restrict__ Wf0, u16* __restrict__ Wf1,
                                               u16* __restrict__ Wf2, u16* __restrict__ Wf3) {
    int b = blockIdx.x, tid = threadIdx.x;
    const float* src;
    u16* dst;
    int nkt;
    if (b < 24)      { src = wpad + OCH0; dst = Wf0; nkt = 12; }
    else if (b < 36) { src = wpad + OCH1; dst = Wf1; b -= 24; nkt = 6; }
    else if (b < 48) { src = wpad + OCH2; dst = Wf2; b -= 36; nkt = 6; }
    else             { src = wpad + OCH3; dst = Wf3; b -= 48; nkt = 6; }
    int base = b * 1024 + tid * 4;
#pragma unroll
    for (int u = 0; u < 4; u++) {
        int gi = base + u;
        int jj = gi & 7;
        int lane = (gi >> 3) & 63;
        int ct = (gi >> 9) & 3;
        int kt = gi >> 11;
        if (kt < nkt) {
            int k = kt * 32 + ((lane >> 4) & 3) * 8 + jj;
            int col = ct * 16 + (lane & 15);
            dst[gi] = f2bf(src[k * 64 + col]);
        }
    }
}

// features (either dtype) -> bf16 X0.
__global__ __launch_bounds__(256) void k_x0(const void* __restrict__ feat, const int* __restrict__ flag,
                                            u16* __restrict__ X0) {
    int i = blockIdx.x * 256 + threadIdx.x;
    if (flag[0] != 0) {
        ((uint4*)X0)[i] = ((const uint4*)feat)[i];
    } else {
        const float4* f = (const float4*)feat;
        float4 a = f[2 * i], b = f[2 * i + 1];
        u16x8 o;
        o[0] = f2bf(a.x); o[1] = f2bf(a.y); o[2] = f2bf(a.z); o[3] = f2bf(a.w);
        o[4] = f2bf(b.x); o[5] = f2bf(b.y); o[6] = f2bf(b.z); o[7] = f2bf(b.w);
        ((uint4*)X0)[i] = __builtin_bit_cast(uint4, o);
    }
}

// PAE: A = relu(Z@W1+b1) on VALU (v_pk_fma_f32 packed pairs), H = A@W2' via MFMA.
// v4: reverted to (256,3)/768 grid (R3's 4 blocks/CU REGRESSED: atomic cacheline
// bouncing, hbm_bytes 157->187MB, VALUBusy 70->57%). Layer-1 MLP now packed:
// W1 staged as adjacent-k pairs (w_m[k], w_m[k+1]) per 64B row (slot-XOR
// swizzled: quads hit disjoint bank groups); accumulate (col k, col k+1) via
// v_pk_fma_f32 (12 pk_fma vs 24 fma per jh), pair feeds v_cvt_pk_bf16_f32.
__global__ __launch_bounds__(256, 3) void k_pae(const void* __restrict__ zin, const float* __restrict__ wpad,
                                                const u16* __restrict__ W2sg, const float* __restrict__ b2p,
                                                const int* __restrict__ ei, const int* __restrict__ flag,
                                                float* __restrict__ ewf, void* __restrict__ dout,
                                                float* __restrict__ deg, int* __restrict__ cnt) {
    __shared__ __align__(16) u16 sW2[16384];
    // 64 kp-rows x 64B: slot q of row kp at byte (kp*64+q*16)^(((kp>>2)&3)<<4)
    // slots: q0=[w0 pair, w1 pair] q1=[w2,w3] q2=[w4,w5] q3=[bias pair, pad]
    __shared__ __align__(16) float sW1p[1024];
    __shared__ float sB2[128];
    int tid = threadIdx.x;
    for (int i = tid; i < 8192; i += 256) ((u32*)sW2)[i] = ((const u32*)W2sg)[i];
    for (int i = tid; i < 1024; i += 256) {
        int kp = i >> 4, j = i & 15;
        int pi = j >> 1, hf = j & 1;
        int k = kp * 2 + hf;
        float v = 0.f;
        if (pi < 6) v = wpad[OW1 + pi * 128 + k];
        else if (pi == 6) v = wpad[OB1 + k];
        int byte = ((kp * 64 + (j >> 2) * 16) ^ (((kp >> 2) & 3) << 4)) + (j & 3) * 4;
        *(float*)((char*)sW1p + byte) = v;
    }
    if (tid < 128) sB2[tid] = b2p[tid];
    __syncthreads();

    bool isbf = flag[0] != 0;
    int wv = __builtin_amdgcn_readfirstlane(tid >> 6);
    int lane = tid & 63;
    int quad = lane >> 4, lrow = lane & 15, jc = lane & 15;
    int sq = quad << 4;  // sW1p swizzle constant for this lane's kp range
    int gw = blockIdx.x * 4 + wv;
    const int ngroups = EE / 16;
    const int gstep = gridDim.x * 4;

    uint2 pb0, pb1, pb2;       // bf16 Z prefetch (24B row)
    float4 pf0, pf1, pf2;      // fp32 Z prefetch (48B row)
    if (gw < ngroups) {
        if (isbf) {
            const uint2* zp = (const uint2*)((const u16*)zin + (size_t)(gw * 16 + lrow) * 12);
            pb0 = zp[0]; pb1 = zp[1]; pb2 = zp[2];
        } else {
            const float4* zp = (const float4*)((const float*)zin + (size_t)(gw * 16 + lrow) * 12);
            pf0 = zp[0]; pf1 = zp[1]; pf2 = zp[2];
        }
    }

#pragma unroll 1
    for (int gidx = gw; gidx < ngroups; gidx += gstep) {
        int e0 = gidx * 16;
        float z1[6], z2[6];
        if (isbf) {
            z1[0] = bfl(pb0.x); z1[1] = bfh(pb0.x); z1[2] = bfl(pb0.y); z1[3] = bfh(pb0.y);
            z1[4] = bfl(pb1.x); z1[5] = bfh(pb1.x);
            z2[0] = bfl(pb1.y); z2[1] = bfh(pb1.y); z2[2] = bfl(pb2.x); z2[3] = bfh(pb2.x);
            z2[4] = bfl(pb2.y); z2[5] = bfh(pb2.y);
        } else {
            z1[0] = pf0.x; z1[1] = pf0.y; z1[2] = pf0.z; z1[3] = pf0.w; z1[4] = pf1.x; z1[5] = pf1.y;
            z2[0] = pf1.z; z2[1] = pf1.w; z2[2] = pf2.x; z2[3] = pf2.y; z2[4] = pf2.z; z2[5] = pf2.w;
        }
        // issue next group's Z loads now -- they complete under this group's compute
        int gn = gidx + gstep;
        if (gn < ngroups) {
            if (isbf) {
                const uint2* zp = (const uint2*)((const u16*)zin + (size_t)(gn * 16 + lrow) * 12);
                pb0 = zp[0]; pb1 = zp[1]; pb2 = zp[2];
            } else {
                const float4* zp = (const float4*)((const float*)zin + (size_t)(gn * 16 + lrow) * 12);
                pf0 = zp[0]; pf1 = zp[1]; pf2 = zp[2];
            }
        }
        // hoist epilogue row indices
        int rows[4];
        if (jc == 0) {
#pragma unroll
            for (int r = 0; r < 4; r++) rows[r] = ei[e0 + quad * 4 + r];
        }

        // packed z duplicates for v_pk_fma_f32
        f32x2 zA[6], zB[6];
#pragma unroll
        for (int m = 0; m < 6; m++) {
            zA[m] = (f32x2){z1[m], z1[m]};
            zB[m] = (f32x2){z2[m], z2[m]};
        }

        // Stage A fragments for all 4 kc chunks (32 VGPRs total)
        bf16x8 a1f[4], a2f[4];
#pragma unroll
        for (int kc = 0; kc < 4; kc++) {
            int kpb = kc * 16 + quad * 4;
            u32 r1[4], r2[4];
#pragma unroll
            for (int jh = 0; jh < 4; jh++) {
                int base = (kpb + jh) * 64;
                const char* bp = (const char*)sW1p;
                float4 q0 = *(const float4*)(bp + ((base + 0) ^ sq));
                float4 q1 = *(const float4*)(bp + ((base + 16) ^ sq));
                float4 q2 = *(const float4*)(bp + ((base + 32) ^ sq));
                f32x2 pA = *(const f32x2*)(bp + ((base + 48) ^ sq));
                f32x2 pB = pA;
                f32x2 w0p = {q0.x, q0.y}, w1p = {q0.z, q0.w};
                f32x2 w2p_ = {q1.x, q1.y}, w3p_ = {q1.z, q1.w};
                f32x2 w4p_ = {q2.x, q2.y}, w5p_ = {q2.z, q2.w};
                asm("v_pk_fma_f32 %0, %1, %2, %0" : "+v"(pA) : "v"(w0p), "v"(zA[0]));
                asm("v_pk_fma_f32 %0, %1, %2, %0" : "+v"(pB) : "v"(w0p), "v"(zB[0]));
                asm("v_pk_fma_f32 %0, %1, %2, %0" : "+v"(pA) : "v"(w1p), "v"(zA[1]));
                asm("v_pk_fma_f32 %0, %1, %2, %0" : "+v"(pB) : "v"(w1p), "v"(zB[1]));
                asm("v_pk_fma_f32 %0, %1, %2, %0" : "+v"(pA) : "v"(w2p_), "v"(zA[2]));
                asm("v_pk_fma_f32 %0, %1, %2, %0" : "+v"(pB) : "v"(w2p_), "v"(zB[2]));
                asm("v_pk_fma_f32 %0, %1, %2, %0" : "+v"(pA) : "v"(w3p_), "v"(zA[3]));
                asm("v_pk_fma_f32 %0, %1, %2, %0" : "+v"(pB) : "v"(w3p_), "v"(zB[3]));
                asm("v_pk_fma_f32 %0, %1, %2, %0" : "+v"(pA) : "v"(w4p_), "v"(zA[4]));
                asm("v_pk_fma_f32 %0, %1, %2, %0" : "+v"(pB) : "v"(w4p_), "v"(zB[4]));
                asm("v_pk_fma_f32 %0, %1, %2, %0" : "+v"(pA) : "v"(w5p_), "v"(zA[5]));
                asm("v_pk_fma_f32 %0, %1, %2, %0" : "+v"(pB) : "v"(w5p_), "v"(zB[5]));
                float sA1 = fmaxf(pA.x, 0.f), sB1 = fmaxf(pA.y, 0.f);
                float sA2 = fmaxf(pB.x, 0.f), sB2v = fmaxf(pB.y, 0.f);
                u32 o1, o2;
                asm("v_cvt_pk_bf16_f32 %0, %1, %2" : "=v"(o1) : "v"(sA1), "v"(sB1));
                asm("v_cvt_pk_bf16_f32 %0, %1, %2" : "=v"(o2) : "v"(sA2), "v"(sB2v));
                r1[jh] = o1; r2[jh] = o2;
            }
            uint4 u1v = {r1[0], r1[1], r1[2], r1[3]};
            uint4 u2v = {r2[0], r2[1], r2[2], r2[3]};
            a1f[kc] = __builtin_bit_cast(bf16x8, u1v);
            a2f[kc] = __builtin_bit_cast(bf16x8, u2v);
        }

        float num[4] = {0, 0, 0, 0}, q1[4] = {0, 0, 0, 0}, q2[4] = {0, 0, 0, 0};
        // jt NOT unrolled: keeps ds_read hoisting bounded (spill guard).
#pragma unroll 1
        for (int jt = 0; jt < 8; jt++) {
            f32x4 acc1 = {0.f, 0.f, 0.f, 0.f}, acc2 = {0.f, 0.f, 0.f, 0.f};
#pragma unroll
            for (int kc = 0; kc < 4; kc++) {
                bf16x8 bb = *reinterpret_cast<const bf16x8*>(&sW2[((kc * 8 + jt) * 64 + lane) * 8]);
                acc1 = __builtin_amdgcn_mfma_f32_16x16x32_bf16(a1f[kc], bb, acc1, 0, 0, 0);
                acc2 = __builtin_amdgcn_mfma_f32_16x16x32_bf16(a2f[kc], bb, acc2, 0, 0, 0);
            }
            float bbias = sB2[jt * 16 + jc];
#pragma unroll
            for (int r = 0; r < 4; r++) {
                float h1 = acc1[r] + bbias;
                float h2 = acc2[r] + bbias;
                num[r] = fmaf(h1, h2, num[r]);
                q1[r] = fmaf(h1, h1, q1[r]);
                q2[r] = fmaf(h2, h2, q2[r]);
            }
        }
#pragma unroll
        for (int off = 1; off < 16; off <<= 1) {
#pragma unroll
            for (int r = 0; r < 4; r++) {
                num[r] += __shfl_xor(num[r], off);
                q1[r] += __shfl_xor(q1[r], off);
                q2[r] += __shfl_xor(q2[r], off);
            }
        }
        if (jc == 0) {
#pragma unroll
            for (int r = 0; r < 4; r++) {
                int e = e0 + quad * 4 + r;
                float den = fmaxf(sqrtf(q1[r]) * sqrtf(q2[r]), 1e-8f);
                float wgt = (num[r] / den + 1.f) * 0.5f;
                if (!(wgt == wgt)) wgt = 0.5f;  // NaN guard: makes failures localizable
                ewf[e] = wgt;
                if (isbf) ((u16*)dout)[EW_OFF + e] = f2bf(wgt);
                else ((float*)dout)[EW_OFF + e] = wgt;
                atomicAdd(deg + rows[r], wgt);
                atomicAdd(cnt + rows[r], 1);
            }
        }
    }
}

// Exclusive scan of cnt -> offs; fused dis = rsqrt(deg).
__global__ __launch_bounds__(1024) void k_scan(const int* __restrict__ cnt, const float* __restrict__ deg,
                                               int* __restrict__ offs, float* __restrict__ dis) {
    __shared__ int wsum[16];
    __shared__ int carry;
    int tid = threadIdx.x;
    int wv = tid >> 6, lane = tid & 63;
    if (tid == 0) carry = 0;
    __syncthreads();
    for (int c = 0; c < 49; c++) {
        int i = c * 1024 + tid;
        int v = (i < NN) ? cnt[i] : 0;
        if (i < NN) {
            float d = deg[i];
            dis[i] = d > 0.f ? rsqrtf(d) : 0.f;
        }
        int x = v;
#pragma unroll
        for (int off = 1; off < 64; off <<= 1) {
            int t = __shfl_up(x, off);
            if (lane >= off) x += t;
        }
        if (lane == 63) wsum[wv] = x;
        __syncthreads();
        if (tid < 16) {
            int s = wsum[tid];
#pragma unroll
            for (int off = 1; off < 16; off <<= 1) {
                int t = __shfl_up(s, off, 16);
                if (tid >= off) s += t;
            }
            wsum[tid] = s;
        }
        __syncthreads();
        int base = carry + (wv > 0 ? wsum[wv - 1] : 0);
        if (i < NN) offs[i] = base + x - v;
        __syncthreads();
        if (tid == 0) carry += wsum[15];
        __syncthreads();
    }
    if (tid == 0) offs[NN] = carry;
}

// CSR scatter: fused (col, norm) uint2 metadata — one 8B load per edge in prop.
__global__ __launch_bounds__(256) void k_csr(const int* __restrict__ ei, const float* __restrict__ ewf,
                                             const float* __restrict__ dis, const int* __restrict__ offs,
                                             int* __restrict__ cursor, uint2* __restrict__ csr_meta) {
    int e = blockIdx.x * 256 + threadIdx.x;
    int r = ei[e], c = ei[EE + e];
    float wgt = ewf[e];
    int pos = offs[r] + atomicAdd(cursor + r, 1);
    float nrm = -dis[r] * wgt * dis[c];
    csr_meta[pos] = make_uint2((u32)c, __builtin_bit_cast(u32, nrm));
}

// Propagation over bf16 node features, fp32 accumulate. One wave per node.
// v4: depth-1 csr_meta software pipeline -- next iteration's metadata is loaded
// during the current FMA block, halving the serial meta->feature chain.
template <int F>
__global__ __launch_bounds__(256) void k_prop(const u16* __restrict__ src, const uint2* __restrict__ csr_meta,
                                              const int* __restrict__ offs,
                                              u16* __restrict__ out, const u16* __restrict__ base,
                                              float alpha, float beta) {
    int lane = threadIdx.x & 63;
    int wv = threadIdx.x >> 6;
    int node = blockIdx.x * 4 + wv;
    int s = offs[node], e = offs[node + 1];

    if (F == 128) {
        int sub = lane >> 4;   // which of 4 edges this lane group handles
        int fl = lane & 15;    // position within the feature row
        const uint4* sv = (const uint4*)src;  // row = 16 uint4 (128 bf16)
        float a[8] = {0, 0, 0, 0, 0, 0, 0, 0};
        int p = s;
        if (p + 7 < e) {
            uint2 m0 = csr_meta[p + sub];
            uint2 m1 = csr_meta[p + 4 + sub];
            while (true) {
                uint4 v0 = sv[(size_t)m0.x * 16 + fl];
                uint4 v1 = sv[(size_t)m1.x * 16 + fl];
                float w0 = __builtin_bit_cast(float, m0.y);
                float w1 = __builtin_bit_cast(float, m1.y);
                p += 8;
                bool more = (p + 7 < e);
                if (more) {
                    m0 = csr_meta[p + sub];
                    m1 = csr_meta[p + 4 + sub];
                }
                a[0] = fmaf(w0, bfl(v0.x), a[0]); a[1] = fmaf(w0, bfh(v0.x), a[1]);
                a[2] = fmaf(w0, bfl(v0.y), a[2]); a[3] = fmaf(w0, bfh(v0.y), a[3]);
                a[4] = fmaf(w0, bfl(v0.z), a[4]); a[5] = fmaf(w0, bfh(v0.z), a[5]);
                a[6] = fmaf(w0, bfl(v0.w), a[6]); a[7] = fmaf(w0, bfh(v0.w), a[7]);
                a[0] = fmaf(w1, bfl(v1.x), a[0]); a[1] = fmaf(w1, bfh(v1.x), a[1]);
                a[2] = fmaf(w1, bfl(v1.y), a[2]); a[3] = fmaf(w1, bfh(v1.y), a[3]);
                a[4] = fmaf(w1, bfl(v1.z), a[4]); a[5] = fmaf(w1, bfh(v1.z), a[5]);
                a[6] = fmaf(w1, bfl(v1.w), a[6]); a[7] = fmaf(w1, bfh(v1.w), a[7]);
                if (!more) break;
            }
        }
        if (p + 3 < e) {
            uint2 m0 = csr_meta[p + sub];
            uint4 v0 = sv[(size_t)m0.x * 16 + fl];
            float w0 = __builtin_bit_cast(float, m0.y);
            a[0] = fmaf(w0, bfl(v0.x), a[0]); a[1] = fmaf(w0, bfh(v0.x), a[1]);
            a[2] = fmaf(w0, bfl(v0.y), a[2]); a[3] = fmaf(w0, bfh(v0.y), a[3]);
            a[4] = fmaf(w0, bfl(v0.z), a[4]); a[5] = fmaf(w0, bfh(v0.z), a[5]);
            a[6] = fmaf(w0, bfl(v0.w), a[6]); a[7] = fmaf(w0, bfh(v0.w), a[7]);
            p += 4;
        }
#pragma unroll
        for (int i = 0; i < 8; i++) {
            a[i] += __shfl_xor(a[i], 16);
            a[i] += __shfl_xor(a[i], 32);
        }
        if (sub == 0) {
            for (; p < e; p++) {
                uint2 m0 = csr_meta[p];
                uint4 v = sv[(size_t)m0.x * 16 + fl];
                float w = __builtin_bit_cast(float, m0.y);
                a[0] = fmaf(w, bfl(v.x), a[0]); a[1] = fmaf(w, bfh(v.x), a[1]);
                a[2] = fmaf(w, bfl(v.y), a[2]); a[3] = fmaf(w, bfh(v.y), a[3]);
                a[4] = fmaf(w, bfl(v.z), a[4]); a[5] = fmaf(w, bfh(v.z), a[5]);
                a[6] = fmaf(w, bfl(v.w), a[6]); a[7] = fmaf(w, bfh(v.w), a[7]);
            }
            float o[8];
#pragma unroll
            for (int i = 0; i < 8; i++) o[i] = alpha * a[i];
            if (beta != 0.f) {
                uint4 bv = ((const uint4*)base)[(size_t)node * 16 + fl];
                o[0] = fmaf(beta, bfl(bv.x), o[0]); o[1] = fmaf(beta, bfh(bv.x), o[1]);
                o[2] = fmaf(beta, bfl(bv.y), o[2]); o[3] = fmaf(beta, bfh(bv.y), o[3]);
                o[4] = fmaf(beta, bfl(bv.z), o[4]); o[5] = fmaf(beta, bfh(bv.z), o[5]);
                o[6] = fmaf(beta, bfl(bv.w), o[6]); o[7] = fmaf(beta, bfh(bv.w), o[7]);
            }
            uint4 ov;
            ov.x = (u32)f2bf(o[0]) | ((u32)f2bf(o[1]) << 16);
            ov.y = (u32)f2bf(o[2]) | ((u32)f2bf(o[3]) << 16);
            ov.z = (u32)f2bf(o[4]) | ((u32)f2bf(o[5]) << 16);
            ov.w = (u32)f2bf(o[6]) | ((u32)f2bf(o[7]) << 16);
            ((uint4*)out)[(size_t)node * 16 + fl] = ov;
        }
    } else {
        int sub = lane >> 3;   // which of 8 edges this lane group handles
        int fl = lane & 7;     // position within the feature row (uint4 units)
        const uint4* sv = (const uint4*)src;  // row = 8 uint4 (64 bf16)
        float a[8] = {0, 0, 0, 0, 0, 0, 0, 0};
        int p = s;
        if (p + 15 < e) {
            uint2 m0 = csr_meta[p + sub];
            uint2 m1 = csr_meta[p + 8 + sub];
            while (true) {
                uint4 v0 = sv[(size_t)m0.x * 8 + fl];
                uint4 v1 = sv[(size_t)m1.x * 8 + fl];
                float w0 = __builtin_bit_cast(float, m0.y);
                float w1 = __builtin_bit_cast(float, m1.y);
                p += 16;
                bool more = (p + 15 < e);
                if (more) {
                    m0 = csr_meta[p + sub];
                    m1 = csr_meta[p + 8 + sub];
                }
                a[0] = fmaf(w0, bfl(v0.x), a[0]); a[1] = fmaf(w0, bfh(v0.x), a[1]);
                a[2] = fmaf(w0, bfl(v0.y), a[2]); a[3] = fmaf(w0, bfh(v0.y), a[3]);
                a[4] = fmaf(w0, bfl(v0.z), a[4]); a[5] = fmaf(w0, bfh(v0.z), a[5]);
                a[6] = fmaf(w0, bfl(v0.w), a[6]); a[7] = fmaf(w0, bfh(v0.w), a[7]);
                a[0] = fmaf(w1, bfl(v1.x), a[0]); a[1] = fmaf(w1, bfh(v1.x), a[1]);
                a[2] = fmaf(w1, bfl(v1.y), a[2]); a[3] = fmaf(w1, bfh(v1.y), a[3]);
                a[4] = fmaf(w1, bfl(v1.z), a[4]); a[5] = fmaf(w1, bfh(v1.z), a[5]);
                a[6] = fmaf(w1, bfl(v1.w), a[6]); a[7] = fmaf(w1, bfh(v1.w), a[7]);
                if (!more) break;
            }
        }
        if (p + 7 < e) {
            uint2 m0 = csr_meta[p + sub];
            uint4 v0 = sv[(size_t)m0.x * 8 + fl];
            float w0 = __builtin_bit_cast(float, m0.y);
            a[0] = fmaf(w0, bfl(v0.x), a[0]); a[1] = fmaf(w0, bfh(v0.x), a[1]);
            a[2] = fmaf(w0, bfl(v0.y), a[2]); a[3] = fmaf(w0, bfh(v0.y), a[3]);
            a[4] = fmaf(w0, bfl(v0.z), a[4]); a[5] = fmaf(w0, bfh(v0.z), a[5]);
            a[6] = fmaf(w0, bfl(v0.w), a[6]); a[7] = fmaf(w0, bfh(v0.w), a[7]);
            p += 8;
        }
#pragma unroll
        for (int i = 0; i < 8; i++) {
            a[i] += __shfl_xor(a[i], 8);
            a[i] += __shfl_xor(a[i], 16);
            a[i] += __shfl_xor(a[i], 32);
        }
        if (sub == 0) {
            for (; p < e; p++) {
                uint2 m0 = csr_meta[p];
                uint4 v = sv[(size_t)m0.x * 8 + fl];
                float w = __builtin_bit_cast(float, m0.y);
                a[0] = fmaf(w, bfl(v.x), a[0]); a[1] = fmaf(w, bfh(v.x), a[1]);
                a[2] = fmaf(w, bfl(v.y), a[2]); a[3] = fmaf(w, bfh(v.y), a[3]);
                a[4] = fmaf(w, bfl(v.z), a[4]); a[5] = fmaf(w, bfh(v.z), a[5]);
                a[6] = fmaf(w, bfl(v.w), a[6]); a[7] = fmaf(w, bfh(v.w), a[7]);
            }
            float o[8];
#pragma unroll
            for (int i = 0; i < 8; i++) o[i] = alpha * a[i];
            if (beta != 0.f) {
                uint4 bv = ((const uint4*)base)[(size_t)node * 8 + fl];
                o[0] = fmaf(beta, bfl(bv.x), o[0]); o[1] = fmaf(beta, bfh(bv.x), o[1]);
                o[2] = fmaf(beta, bfl(bv.y), o[2]); o[3] = fmaf(beta, bfh(bv.y), o[3]);
                o[4] = fmaf(beta, bfl(bv.z), o[4]); o[5] = fmaf(beta, bfh(bv.z), o[5]);
                o[6] = fmaf(beta, bfl(bv.w), o[6]); o[7] = fmaf(beta, bfh(bv.w), o[7]);
            }
            uint4 ov;
            ov.x = (u32)f2bf(o[0]) | ((u32)f2bf(o[1]) << 16);
            ov.y = (u32)f2bf(o[2]) | ((u32)f2bf(o[3]) << 16);
            ov.z = (u32)f2bf(o[4]) | ((u32)f2bf(o[5]) << 16);
            ov.w = (u32)f2bf(o[6]) | ((u32)f2bf(o[7]) << 16);
            ((uint4*)out)[(size_t)node * 8 + fl] = ov;
        }
    }
}

// ChebConv mix via MFMA -> bf16 h + jk slice (out dtype).
template <int F>
__global__ __launch_bounds__(256) void k_gemm(const u16* __restrict__ X0, const u16* __restrict__ X1,
                                              const u16* __restrict__ X2, const u16* __restrict__ Wf,
                                              u16* __restrict__ Hout, void* __restrict__ jk, int jkoff,
                                              const int* __restrict__ flag) {
    constexpr int KT = (3 * F) / 32;  // 12 (F=128) or 6 (F=64)
    __shared__ __align__(16) u16 sB[KT * 4 * 64 * 8];
    int tid = threadIdx.x;
    for (int i = tid; i < KT * 4 * 64 * 4; i += 256) ((u32*)sB)[i] = ((const u32*)Wf)[i];
    __syncthreads();

    bool isbf = flag[0] != 0;
    int wv = __builtin_amdgcn_readfirstlane(tid >> 6);
    int lane = tid & 63;
    int quad = lane >> 4, jc = lane & 15;
    int pair = wv >> 1;   // row group
    int half = wv & 1;    // column half (32 cols)
    int nb = blockIdx.x * 32 + pair * 16;
    int row = nb + jc;
    if (row > NN - 1) row = NN - 1;

    // prefetch all A-fragments (row = lane&15, k = kt*32 + quad*8 + j)
    uint4 av[KT];
#pragma unroll
    for (int kt = 0; kt < KT; kt++) {
        int kg = kt * 32 + quad * 8;
        const u16* Xp;
        int kk;
        if (kg < F) { Xp = X0; kk = kg; }
        else if (kg < 2 * F) { Xp = X1; kk = kg - F; }
        else { Xp = X2; kk = kg - 2 * F; }
        av[kt] = *(const uint4*)(Xp + (size_t)row * F + kk);
    }

    f32x4 acc0 = {0.f, 0.f, 0.f, 0.f}, acc1 = {0.f, 0.f, 0.f, 0.f};
#pragma unroll
    for (int kt = 0; kt < KT; kt++) {
        bf16x8 af = __builtin_bit_cast(bf16x8, av[kt]);
        bf16x8 b0 = *reinterpret_cast<const bf16x8*>(&sB[((kt * 4 + half * 2 + 0) * 64 + lane) * 8]);
        bf16x8 b1 = *reinterpret_cast<const bf16x8*>(&sB[((kt * 4 + half * 2 + 1) * 64 + lane) * 8]);
        acc0 = __builtin_amdgcn_mfma_f32_16x16x32_bf16(af, b0, acc0, 0, 0, 0);
        acc1 = __builtin_amdgcn_mfma_f32_16x16x32_bf16(af, b1, acc1, 0, 0, 0);
    }

#pragma unroll
    for (int ct = 0; ct < 2; ct++) {
        f32x4 a = ct ? acc1 : acc0;
        int j = (half * 2 + ct) * 16 + jc;
#pragma unroll
        for (int r = 0; r < 4; r++) {
            int n = nb + quad * 4 + r;
            if (n < NN) {
                float v = fmaxf(a[r], 0.f);
                Hout[(size_t)n * 64 + j] = f2bf(v);
                if (isbf) ((u16*)jk)[(size_t)n * 256 + jkoff + j] = f2bf(v);
                else ((float*)jk)[(size_t)n * 256 + jkoff + j] = v;
            }
        }
    }
}

// Fused classifier: logit = (relu(jk@W1+b1)*s+t)@w2 + b2, z never materialized.
__global__ __launch_bounds__(256) void k_cls(const u16* __restrict__ h0, const u16* __restrict__ h1,
                                             const u16* __restrict__ h2, const u16* __restrict__ h3,
                                             const u16* __restrict__ W1c, const float* __restrict__ wpad,
                                             const float* __restrict__ w2p, const float* __restrict__ b2p2,
                                             const int* __restrict__ flag, void* __restrict__ dout) {
    __shared__ __align__(16) u16 sB[16384];  // one phase slice of W1c (32KB)
    __shared__ float sb1[256];
    __shared__ float sw2[512];
    __shared__ float sb2[2];
    __shared__ float part[4][16][2];
    int tid = threadIdx.x;
    if (tid < 256) sb1[tid] = wpad[OCB1 + tid];
    for (int i = tid; i < 512; i += 256) sw2[i] = w2p[i];
    if (tid < 2) sb2[tid] = b2p2[tid];

    int wv = __builtin_amdgcn_readfirstlane(tid >> 6);
    int lane = tid & 63;
    int quad = lane >> 4, jc = lane & 15;
    int pair = wv >> 1;      // row group (0/1)
    int half = wv & 1;       // column half (0/1)
    int nb = blockIdx.x * 32 + pair * 16;

    f32x4 acc[8] = {{0.f, 0.f, 0.f, 0.f}, {0.f, 0.f, 0.f, 0.f}, {0.f, 0.f, 0.f, 0.f}, {0.f, 0.f, 0.f, 0.f},
                    {0.f, 0.f, 0.f, 0.f}, {0.f, 0.f, 0.f, 0.f}, {0.f, 0.f, 0.f, 0.f}, {0.f, 0.f, 0.f, 0.f}};
    const u16* hs[4] = {h0, h1, h2, h3};

    int row = nb + jc;
    if (row > NN - 1) row = NN - 1;

#pragma unroll 1
    for (int l = 0; l < 4; l++) {
        __syncthreads();
        const u32* src = (const u32*)W1c + l * 8192;
        for (int i = tid; i < 8192; i += 256) ((u32*)sB)[i] = src[i];
        __syncthreads();
        const uint4* rp = (const uint4*)(hs[l] + (size_t)row * 64);
        uint4 a0u = rp[quad], a1u = rp[4 + quad];
        bf16x8 af0 = __builtin_bit_cast(bf16x8, a0u);
        bf16x8 af1 = __builtin_bit_cast(bf16x8, a1u);
#pragma unroll
        for (int jt = 0; jt < 8; jt++) {
            int ct = half * 8 + jt;
            bf16x8 b0 = *reinterpret_cast<const bf16x8*>(&sB[((0 * 16 + ct) * 64 + lane) * 8]);
            bf16x8 b1f = *reinterpret_cast<const bf16x8*>(&sB[((1 * 16 + ct) * 64 + lane) * 8]);
            acc[jt] = __builtin_amdgcn_mfma_f32_16x16x32_bf16(af0, b0, acc[jt], 0, 0, 0);
            acc[jt] = __builtin_amdgcn_mfma_f32_16x16x32_bf16(af1, b1f, acc[jt], 0, 0, 0);
        }
    }

    // epilogue: relu(acc+b1) dot w2' -> per-row logit partials
    float p0[4] = {0, 0, 0, 0}, p1[4] = {0, 0, 0, 0};
#pragma unroll
    for (int jt = 0; jt < 8; jt++) {
        int j = (half * 8 + jt) * 16 + jc;
        float b1v = sb1[j], wa = sw2[2 * j], wb = sw2[2 * j + 1];
#pragma unroll
        for (int r = 0; r < 4; r++) {
            float h = fmaxf(acc[jt][r] + b1v, 0.f);
            p0[r] = fmaf(h, wa, p0[r]);
            p1[r] = fmaf(h, wb, p1[r]);
        }
    }
#pragma unroll
    for (int off = 1; off < 16; off <<= 1) {
#pragma unroll
        for (int r = 0; r < 4; r++) {
            p0[r] += __shfl_xor(p0[r], off);
            p1[r] += __shfl_xor(p1[r], off);
        }
    }
    if (jc == 0) {
#pragma unroll
        for (int r = 0; r < 4; r++) {
            part[wv][quad * 4 + r][0] = p0[r];
            part[wv][quad * 4 + r][1] = p1[r];
        }
    }
    __syncthreads();
    if (tid < 32) {
        int rl = tid & 15, p = tid >> 4;
        int n = blockIdx.x * 32 + tid;
        if (n < NN) {
            float l0 = part[2 * p][rl][0] + part[2 * p + 1][rl][0] + sb2[0];
            float l1 = part[2 * p][rl][1] + part[2 * p + 1][rl][1] + sb2[1];
            if (flag[0] != 0) {
                u32 pack = (u32)f2bf(l0) | ((u32)f2bf(l1) << 16);
                *(u32*)((u16*)dout + LG_OFF + (size_t)n * 2) = pack;
            } else {
                float2 o = {l0, l1};
                *(float2*)((float*)dout + LG_OFF + (size_t)n * 2) = o;
            }
        }
    }
}

extern "C" void kernel_launch(void* const* d_in, const int* in_sizes, int n_in,
                              void* d_out, int out_size, void* d_ws, size_t ws_size,
                              hipStream_t stream) {
    const void* features = d_in[0];
    const int* ei = (const int*)d_in[1];
    const void* zin = d_in[2];

    char* w = (char*)d_ws;
    auto alloc = [&](size_t bytes) -> void* {
        void* p = (void*)w;
        w += (bytes + 255) & ~(size_t)255;
        return p;
    };
    u16* X0 = (u16*)alloc((size_t)NN * 128 * 2);
    u16* Tx1 = (u16*)alloc((size_t)NN * 128 * 2);
    u16* Tx2 = (u16*)alloc((size_t)NN * 128 * 2);
    u16* h0 = (u16*)alloc((size_t)NN * 64 * 2);
    u16* h1 = (u16*)alloc((size_t)NN * 64 * 2);
    u16* h2 = (u16*)alloc((size_t)NN * 64 * 2);
    u16* h3 = (u16*)alloc((size_t)NN * 64 * 2);
    float* ewf = (float*)alloc((size_t)EE * 4);
    uint2* csr_meta = (uint2*)alloc((size_t)EE * 8);
    float* deg = (float*)alloc((size_t)NN * 4);
    int* cnt = (int*)alloc((size_t)NN * 4);
    int* cursor = (int*)alloc((size_t)NN * 4);
    float* dis = (float*)alloc((size_t)NN * 4);
    int* offs = (int*)alloc((size_t)(NN + 1) * 4);
    u16* W2s = (u16*)alloc((size_t)16384 * 2);
    float* b2p = (float*)alloc((size_t)128 * 4);
    u16* W1c = (u16*)alloc((size_t)65536 * 2);
    float* w2p = (float*)alloc((size_t)512 * 4);
    float* b2p2 = (float*)alloc((size_t)2 * 4);
    u16* Wf0 = (u16*)alloc((size_t)24576 * 2);
    u16* Wf1 = (u16*)alloc((size_t)12288 * 2);
    u16* Wf2 = (u16*)alloc((size_t)12288 * 2);
    u16* Wf3 = (u16*)alloc((size_t)12288 * 2);
    float* wpad = (float*)alloc((size_t)OTOT * 4);
    int* flag = (int*)alloc(256);

    hipMemsetAsync(deg, 0, (size_t)((char*)dis - (char*)deg), stream);

    PtrTab tab;
    for (int i = 0; i < 20; i++) tab.p[i] = d_in[3 + i];

    k_detect<<<1, 256, 0, stream>>>((const u16*)features, flag);
    k_wconv<<<20, 256, 0, stream>>>(tab, flag, wpad);
    k_fold<<<33, 128, 0, stream>>>(wpad, W2s, b2p);
    k_foldc<<<65, 256, 0, stream>>>(wpad, W1c, w2p, b2p2);
    k_foldw<<<60, 256, 0, stream>>>(wpad, Wf0, Wf1, Wf2, Wf3);
    k_x0<<<3125, 256, 0, stream>>>(features, flag, X0);
    // 768 blocks = 256 CU x 3 resident blocks (measured optimum; 4/CU regressed
    // via atomic cacheline contention, R3)
    k_pae<<<768, 256, 0, stream>>>(zin, wpad, W2s, b2p, ei, flag, ewf, d_out, deg, cnt);
    k_scan<<<1, 1024, 0, stream>>>(cnt, deg, offs, dis);
    k_csr<<<EE / 256, 256, 0, stream>>>(ei, ewf, dis, offs, cursor, csr_meta);

    // layer 0 (F=128)
    k_prop<128><<<12500, 256, 0, stream>>>(X0, csr_meta, offs, Tx1, nullptr, 1.f, 0.f);
    k_prop<128><<<12500, 256, 0, stream>>>(Tx1, csr_meta, offs, Tx2, X0, 2.f, -1.f);
    k_gemm<128><<<1563, 256, 0, stream>>>(X0, Tx1, Tx2, Wf0, h0, d_out, 0, flag);
    // layer 1 (F=64)
    k_prop<64><<<12500, 256, 0, stream>>>(h0, csr_meta, offs, Tx1, nullptr, 1.f, 0.f);
    k_prop<64><<<12500, 256, 0, stream>>>(Tx1, csr_meta, offs, Tx2, h0, 2.f, -1.f);
    k_gemm<64><<<1563, 256, 0, stream>>>(h0, Tx1, Tx2, Wf1, h1, d_out, 64, flag);
    // layer 2
    k_prop<64><<<12500, 256, 0, stream>>>(h1, csr_meta, offs, Tx1, nullptr, 1.f, 0.f);
    k_prop<64><<<12500, 256, 0, stream>>>(Tx1, csr_meta, offs, Tx2, h1, 2.f, -1.f);
    k_gemm<64><<<1563, 256, 0, stream>>>(h1, Tx1, Tx2, Wf2, h2, d_out, 128, flag);
    // layer 3
    k_prop<64><<<12500, 256, 0, stream>>>(h2, csr_meta, offs, Tx1, nullptr, 1.f, 0.f);
    k_prop<64><<<12500, 256, 0, stream>>>(Tx1, csr_meta, offs, Tx2, h2, 2.f, -1.f);
    k_gemm<64><<<1563, 256, 0, stream>>>(h2, Tx1, Tx2, Wf3, h3, d_out, 192, flag);

    // fused classifier (z never materialized)
    k_cls<<<1563, 256, 0, stream>>>(h0, h1, h2, h3, W1c, wpad, w2p, b2p2, flag, d_out);
    (void)in_sizes; (void)n_in; (void)out_size; (void)ws_size;
}

// Round 5
// 1010.686 us; speedup vs baseline: 1.9131x; 1.0172x over previous
//
#include <hip/hip_runtime.h>

#define NN 50000
#define EE 1600000

using u16 = unsigned short;
using u32 = unsigned int;
using u64 = unsigned long long;

typedef float f32x4 __attribute__((ext_vector_type(4)));
typedef __bf16 bf16x8 __attribute__((ext_vector_type(8)));
typedef unsigned short u16x8 __attribute__((ext_vector_type(8)));

struct alignas(8) U16x4 { u16 a, b, c, d; };
struct PtrTab { const void* p[20]; };

// canonical fp32 weight-pad offsets
#define OW1 0
#define OB1 768
#define OG 896
#define OBB 1024
#define ORM 1152
#define ORV 1280
#define OW2 1408
#define OB2 17792
#define OCH0 17920
#define OCH1 42496
#define OCH2 54784
#define OCH3 67072
#define OCW1 79360
#define OCB1 144896
#define OCG 145152
#define OCBB 145408
#define OCRM 145664
#define OCRV 145920
#define OCW2 146176
#define OCB2 146688
#define OTOT 146690

// element offsets within d_out (dtype-independent in elements)
#define LG_OFF ((size_t)NN * 256)
#define EW_OFF ((size_t)NN * 256 + (size_t)NN * 2)

__device__ __forceinline__ float bf2f(u16 u) { return __builtin_bit_cast(float, (u32)u << 16); }
__device__ __forceinline__ float bfl(u32 u) { return __builtin_bit_cast(float, u << 16); }
__device__ __forceinline__ float bfh(u32 u) { return __builtin_bit_cast(float, u & 0xffff0000u); }
__device__ __forceinline__ u16 f2bf(float f) {
    u32 u = __builtin_bit_cast(u32, f);
    return (u16)((u + 0x7fffu + ((u >> 16) & 1u)) >> 16);
}

// Input dtype detector: flag=1 -> bf16 inputs, 0 -> fp32 inputs.
__global__ __launch_bounds__(256) void k_detect(const u16* __restrict__ f, int* __restrict__ flag) {
    __shared__ int bad;
    if (threadIdx.x == 0) bad = 0;
    __syncthreads();
    u16 u = f[threadIdx.x];
    int e = (u >> 7) & 0xFF;
    if (e >= 0x90) atomicAdd(&bad, 1);
    __syncthreads();
    if (threadIdx.x == 0) flag[0] = (bad < 16) ? 1 : 0;
}

// Convert all 20 weight arrays into canonical fp32 pad.
__global__ __launch_bounds__(256) void k_wconv(PtrTab tab, const int* __restrict__ flag,
                                               float* __restrict__ wpad) {
    const int SZ[20] = {768, 128, 128, 128, 128, 128, 16384, 128, 24576, 12288, 12288, 12288,
                        65536, 256, 256, 256, 256, 256, 512, 2};
    const int OF[20] = {OW1, OB1, OG, OBB, ORM, ORV, OW2, OB2, OCH0, OCH1, OCH2, OCH3,
                        OCW1, OCB1, OCG, OCBB, OCRM, OCRV, OCW2, OCB2};
    int a = blockIdx.x;
    int n = SZ[a];
    float* dst = wpad + OF[a];
    if (flag[0] != 0) {
        const u16* s = (const u16*)tab.p[a];
        for (int i = threadIdx.x; i < n; i += 256) dst[i] = bf2f(s[i]);
    } else {
        const float* s = (const float*)tab.p[a];
        for (int i = threadIdx.x; i < n; i += 256) dst[i] = s[i];
    }
}

// Fold PAE BN into W2 (MFMA B-frag swizzled bf16) + b2'.
__global__ __launch_bounds__(128) void k_fold(const float* __restrict__ wpad,
                                              u16* __restrict__ W2s, float* __restrict__ b2p) {
    const float* g = wpad + OG;
    const float* b = wpad + OBB;
    const float* rm = wpad + ORM;
    const float* rv = wpad + ORV;
    const float* w2 = wpad + OW2;
    const float* b2 = wpad + OB2;
    int blk = blockIdx.x, tid = threadIdx.x;
    if (blk < 32) {
        int kc = blk >> 3, jt = blk & 7;
        int lane = tid & 63, jh = tid >> 6;
        for (int jj = 0; jj < 4; jj++) {
            int j = jh * 4 + jj;
            int k = kc * 32 + (lane >> 4) * 8 + j;
            int jcol = jt * 16 + (lane & 15);
            float s = g[k] * rsqrtf(rv[k] + 1e-5f);
            W2s[((kc * 8 + jt) * 64 + lane) * 8 + j] = f2bf(s * w2[k * 128 + jcol]);
        }
    } else {
        if (tid < 128) {
            int j = tid;
            float acc = b2[j];
            for (int k = 0; k < 128; k++) {
                float s = g[k] * rsqrtf(rv[k] + 1e-5f);
                float t = b[k] - rm[k] * s;
                acc += t * w2[k * 128 + j];
            }
            b2p[j] = acc;
        }
    }
}

// Fold classifier weights: W1c = cls_w1 as MFMA B-fragments (bf16, phase-sliced),
// w2p[j][c] = s_j * cls_w2[j][c], b2p2[c] = cls_b2[c] + sum_j t_j * cls_w2[j][c].
__global__ __launch_bounds__(256) void k_foldc(const float* __restrict__ wpad,
                                               u16* __restrict__ W1c, float* __restrict__ w2p,
                                               float* __restrict__ b2p2) {
    int tid = threadIdx.x;
    if (blockIdx.x < 64) {
        const float* w1 = wpad + OCW1;
        int base = blockIdx.x * 1024 + tid * 4;
#pragma unroll
        for (int u = 0; u < 4; u++) {
            int gi = base + u;
            int j = gi & 7;
            int lane = (gi >> 3) & 63;
            int ct = (gi >> 9) & 15;
            int kc2 = (gi >> 13) & 1;
            int l = gi >> 14;
            int k = l * 64 + kc2 * 32 + ((lane >> 4) & 3) * 8 + j;
            int col = ct * 16 + (lane & 15);
            W1c[gi] = f2bf(w1[k * 256 + col]);
        }
    } else {
        __shared__ float red[8];
        int j = tid;
        float s = wpad[OCG + j] * rsqrtf(wpad[OCRV + j] + 1e-5f);
        float t = wpad[OCBB + j] - wpad[OCRM + j] * s;
        float w0 = wpad[OCW2 + j * 2], w1v = wpad[OCW2 + j * 2 + 1];
        w2p[j * 2] = s * w0;
        w2p[j * 2 + 1] = s * w1v;
        float c0 = t * w0, c1 = t * w1v;
#pragma unroll
        for (int off = 1; off < 64; off <<= 1) {
            c0 += __shfl_xor(c0, off);
            c1 += __shfl_xor(c1, off);
        }
        int wv = tid >> 6, lane = tid & 63;
        if (lane == 0) { red[wv * 2] = c0; red[wv * 2 + 1] = c1; }
        __syncthreads();
        if (tid == 0) b2p2[0] = wpad[OCB2] + red[0] + red[2] + red[4] + red[6];
        if (tid == 1) b2p2[1] = wpad[OCB2 + 1] + red[1] + red[3] + red[5] + red[7];
    }
}

// Fold ChebConv weights into MFMA B-fragment order (bf16).
__global__ __launch_bounds__(256) void k_foldw(const float* __restrict__ wpad,
                                               u16* __restrict__ Wf0, u16* __restrict__ Wf1,
                                               u16* __restrict__ Wf2, u16* __restrict__ Wf3) {
    int b = blockIdx.x, tid = threadIdx.x;
    const float* src;
    u16* dst;
    int nkt;
    if (b < 24)      { src = wpad + OCH0; dst = Wf0; nkt = 12; }
    else if (b < 36) { src = wpad + OCH1; dst = Wf1; b -= 24; nkt = 6; }
    else if (b < 48) { src = wpad + OCH2; dst = Wf2; b -= 36; nkt = 6; }
    else             { src = wpad + OCH3; dst = Wf3; b -= 48; nkt = 6; }
    int base = b * 1024 + tid * 4;
#pragma unroll
    for (int u = 0; u < 4; u++) {
        int gi = base + u;
        int jj = gi & 7;
        int lane = (gi >> 3) & 63;
        int ct = (gi >> 9) & 3;
        int kt = gi >> 11;
        if (kt < nkt) {
            int k = kt * 32 + ((lane >> 4) & 3) * 8 + jj;
            int col = ct * 16 + (lane & 15);
            dst[gi] = f2bf(src[k * 64 + col]);
        }
    }
}

// features (either dtype) -> bf16 X0.
__global__ __launch_bounds__(256) void k_x0(const void* __restrict__ feat, const int* __restrict__ flag,
                                            u16* __restrict__ X0) {
    int i = blockIdx.x * 256 + threadIdx.x;
    if (flag[0] != 0) {
        ((uint4*)X0)[i] = ((const uint4*)feat)[i];
    } else {
        const float4* f = (const float4*)feat;
        float4 a = f[2 * i], b = f[2 * i + 1];
        u16x8 o;
        o[0] = f2bf(a.x); o[1] = f2bf(a.y); o[2] = f2bf(a.z); o[3] = f2bf(a.w);
        o[4] = f2bf(b.x); o[5] = f2bf(b.y); o[6] = f2bf(b.z); o[7] = f2bf(b.w);
        ((uint4*)X0)[i] = __builtin_bit_cast(uint4, o);
    }
}

// PAE: A = relu(Z@W1+b1) on VALU (fragments staged once), H = A@W2' via MFMA.
// v5: staging reverted to the R2 scalar-fma form (measured 262us; the R4
// pk_fma inline-asm version regressed to 290us -- two 6-deep SERIAL chains
// vs 4 independent chains the compiler interleaves, VALUBusy 70->55%).
// Grid stays 768 = 3 blocks/CU (4/CU regressed via atomic contention, R3).
// deg+cnt now ONE u64 atomic: lo32 = sum(wgt) in 8.23 fixed point (max
// 64 edges * 2^23 = 2^29, no carry into hi), hi32 = edge count. Halves the
// 3.2M device-scope atomic messages (R4 WRITE_SIZE showed ~100MB of atomic
// traffic vs ~10MB of real writes).
__global__ __launch_bounds__(256, 3) void k_pae(const void* __restrict__ zin, const float* __restrict__ wpad,
                                                const u16* __restrict__ W2sg, const float* __restrict__ b2p,
                                                const int* __restrict__ ei, const int* __restrict__ flag,
                                                float* __restrict__ ewf, void* __restrict__ dout,
                                                u64* __restrict__ dc) {
    __shared__ __align__(16) u16 sW2[16384];
    __shared__ __align__(16) float sW1k[1024];  // float m of row k at byte (k*32+m*4)^(((k>>3)&3)<<4)
    __shared__ float sB2[128];
    int tid = threadIdx.x;
    for (int i = tid; i < 8192; i += 256) ((u32*)sW2)[i] = ((const u32*)W2sg)[i];
    for (int i = tid; i < 1024; i += 256) {
        int k = i >> 3, m = i & 7;
        float v = 0.f;
        if (m < 6) v = wpad[OW1 + m * 128 + k];
        else if (m == 6) v = wpad[OB1 + k];
        int sw = ((k >> 3) & 3) << 4;
        *(float*)((char*)sW1k + ((k * 32 + m * 4) ^ sw)) = v;
    }
    if (tid < 128) sB2[tid] = b2p[tid];
    __syncthreads();

    bool isbf = flag[0] != 0;
    int wv = __builtin_amdgcn_readfirstlane(tid >> 6);
    int lane = tid & 63;
    int quad = lane >> 4, lrow = lane & 15, jc = lane & 15;
    int sq = quad << 4;  // sW1k swizzle constant for this lane's k range
    int gw = blockIdx.x * 4 + wv;
    const int ngroups = EE / 16;
    const int gstep = gridDim.x * 4;

    uint2 pb0, pb1, pb2;       // bf16 Z prefetch (24B row)
    float4 pf0, pf1, pf2;      // fp32 Z prefetch (48B row)
    if (gw < ngroups) {
        if (isbf) {
            const uint2* zp = (const uint2*)((const u16*)zin + (size_t)(gw * 16 + lrow) * 12);
            pb0 = zp[0]; pb1 = zp[1]; pb2 = zp[2];
        } else {
            const float4* zp = (const float4*)((const float*)zin + (size_t)(gw * 16 + lrow) * 12);
            pf0 = zp[0]; pf1 = zp[1]; pf2 = zp[2];
        }
    }

#pragma unroll 1
    for (int gidx = gw; gidx < ngroups; gidx += gstep) {
        int e0 = gidx * 16;
        float z1[6], z2[6];
        if (isbf) {
            z1[0] = bfl(pb0.x); z1[1] = bfh(pb0.x); z1[2] = bfl(pb0.y); z1[3] = bfh(pb0.y);
            z1[4] = bfl(pb1.x); z1[5] = bfh(pb1.x);
            z2[0] = bfl(pb1.y); z2[1] = bfh(pb1.y); z2[2] = bfl(pb2.x); z2[3] = bfh(pb2.x);
            z2[4] = bfl(pb2.y); z2[5] = bfh(pb2.y);
        } else {
            z1[0] = pf0.x; z1[1] = pf0.y; z1[2] = pf0.z; z1[3] = pf0.w; z1[4] = pf1.x; z1[5] = pf1.y;
            z2[0] = pf1.z; z2[1] = pf1.w; z2[2] = pf2.x; z2[3] = pf2.y; z2[4] = pf2.z; z2[5] = pf2.w;
        }
        // issue next group's Z loads now -- they complete under this group's compute
        int gn = gidx + gstep;
        if (gn < ngroups) {
            if (isbf) {
                const uint2* zp = (const uint2*)((const u16*)zin + (size_t)(gn * 16 + lrow) * 12);
                pb0 = zp[0]; pb1 = zp[1]; pb2 = zp[2];
            } else {
                const float4* zp = (const float4*)((const float*)zin + (size_t)(gn * 16 + lrow) * 12);
                pf0 = zp[0]; pf1 = zp[1]; pf2 = zp[2];
            }
        }
        // hoist epilogue row indices (were a cold global load after the MFMA loop)
        int rows[4];
        if (jc == 0) {
#pragma unroll
            for (int r = 0; r < 4; r++) rows[r] = ei[e0 + quad * 4 + r];
        }

        // Stage A fragments for all 4 kc chunks (32 VGPRs total)
        bf16x8 a1f[4], a2f[4];
#pragma unroll
        for (int kc = 0; kc < 4; kc++) {
            int kbase = kc * 32 + quad * 8;
            u32 r1[4], r2[4];
#pragma unroll
            for (int jh = 0; jh < 4; jh++) {
                int k = kbase + 2 * jh;
                const char* bp = (const char*)sW1k;
                float4 wa = *(const float4*)(bp + ((k * 32) ^ sq));
                float4 wb = *(const float4*)(bp + ((k * 32 + 16) ^ sq));
                float4 wc = *(const float4*)(bp + (((k + 1) * 32) ^ sq));
                float4 wd = *(const float4*)(bp + (((k + 1) * 32 + 16) ^ sq));
                float sA1 = wb.z, sA2 = wb.z, sB1 = wd.z, sB2v = wd.z;
                sA1 = fmaf(z1[0], wa.x, sA1); sA2 = fmaf(z2[0], wa.x, sA2);
                sA1 = fmaf(z1[1], wa.y, sA1); sA2 = fmaf(z2[1], wa.y, sA2);
                sA1 = fmaf(z1[2], wa.z, sA1); sA2 = fmaf(z2[2], wa.z, sA2);
                sA1 = fmaf(z1[3], wa.w, sA1); sA2 = fmaf(z2[3], wa.w, sA2);
                sA1 = fmaf(z1[4], wb.x, sA1); sA2 = fmaf(z2[4], wb.x, sA2);
                sA1 = fmaf(z1[5], wb.y, sA1); sA2 = fmaf(z2[5], wb.y, sA2);
                sB1 = fmaf(z1[0], wc.x, sB1); sB2v = fmaf(z2[0], wc.x, sB2v);
                sB1 = fmaf(z1[1], wc.y, sB1); sB2v = fmaf(z2[1], wc.y, sB2v);
                sB1 = fmaf(z1[2], wc.z, sB1); sB2v = fmaf(z2[2], wc.z, sB2v);
                sB1 = fmaf(z1[3], wc.w, sB1); sB2v = fmaf(z2[3], wc.w, sB2v);
                sB1 = fmaf(z1[4], wd.x, sB1); sB2v = fmaf(z2[4], wd.x, sB2v);
                sB1 = fmaf(z1[5], wd.y, sB1); sB2v = fmaf(z2[5], wd.y, sB2v);
                sA1 = fmaxf(sA1, 0.f); sA2 = fmaxf(sA2, 0.f);
                sB1 = fmaxf(sB1, 0.f); sB2v = fmaxf(sB2v, 0.f);
                u32 o1, o2;
                asm("v_cvt_pk_bf16_f32 %0, %1, %2" : "=v"(o1) : "v"(sA1), "v"(sB1));
                asm("v_cvt_pk_bf16_f32 %0, %1, %2" : "=v"(o2) : "v"(sA2), "v"(sB2v));
                r1[jh] = o1; r2[jh] = o2;
            }
            uint4 u1v = {r1[0], r1[1], r1[2], r1[3]};
            uint4 u2v = {r2[0], r2[1], r2[2], r2[3]};
            a1f[kc] = __builtin_bit_cast(bf16x8, u1v);
            a2f[kc] = __builtin_bit_cast(bf16x8, u2v);
        }

        float num[4] = {0, 0, 0, 0}, q1[4] = {0, 0, 0, 0}, q2[4] = {0, 0, 0, 0};
        // jt NOT unrolled: keeps ds_read hoisting bounded (spill guard).
#pragma unroll 1
        for (int jt = 0; jt < 8; jt++) {
            f32x4 acc1 = {0.f, 0.f, 0.f, 0.f}, acc2 = {0.f, 0.f, 0.f, 0.f};
#pragma unroll
            for (int kc = 0; kc < 4; kc++) {
                bf16x8 bb = *reinterpret_cast<const bf16x8*>(&sW2[((kc * 8 + jt) * 64 + lane) * 8]);
                acc1 = __builtin_amdgcn_mfma_f32_16x16x32_bf16(a1f[kc], bb, acc1, 0, 0, 0);
                acc2 = __builtin_amdgcn_mfma_f32_16x16x32_bf16(a2f[kc], bb, acc2, 0, 0, 0);
            }
            float bbias = sB2[jt * 16 + jc];
#pragma unroll
            for (int r = 0; r < 4; r++) {
                float h1 = acc1[r] + bbias;
                float h2 = acc2[r] + bbias;
                num[r] = fmaf(h1, h2, num[r]);
                q1[r] = fmaf(h1, h1, q1[r]);
                q2[r] = fmaf(h2, h2, q2[r]);
            }
        }
#pragma unroll
        for (int off = 1; off < 16; off <<= 1) {
#pragma unroll
            for (int r = 0; r < 4; r++) {
                num[r] += __shfl_xor(num[r], off);
                q1[r] += __shfl_xor(q1[r], off);
                q2[r] += __shfl_xor(q2[r], off);
            }
        }
        if (jc == 0) {
#pragma unroll
            for (int r = 0; r < 4; r++) {
                int e = e0 + quad * 4 + r;
                float den = fmaxf(sqrtf(q1[r]) * sqrtf(q2[r]), 1e-8f);
                float wgt = (num[r] / den + 1.f) * 0.5f;
                if (!(wgt == wgt)) wgt = 0.5f;  // NaN guard: makes failures localizable
                ewf[e] = wgt;
                if (isbf) ((u16*)dout)[EW_OFF + e] = f2bf(wgt);
                else ((float*)dout)[EW_OFF + e] = wgt;
                // one u64 atomic: hi32 = count(+1), lo32 = wgt in 8.23 fixed point
                u32 fx = (u32)(wgt * 8388608.f + 0.5f);
                atomicAdd(dc + rows[r], (((u64)1) << 32) | (u64)fx);
            }
        }
    }
}

// Exclusive scan of cnt (hi32 of dc) -> offs; fused dis = rsqrt(deg) with
// deg = lo32 of dc * 2^-23.
__global__ __launch_bounds__(1024) void k_scan(const u64* __restrict__ dc,
                                               int* __restrict__ offs, float* __restrict__ dis) {
    __shared__ int wsum[16];
    __shared__ int carry;
    int tid = threadIdx.x;
    int wv = tid >> 6, lane = tid & 63;
    if (tid == 0) carry = 0;
    __syncthreads();
    for (int c = 0; c < 49; c++) {
        int i = c * 1024 + tid;
        u64 v64 = (i < NN) ? dc[i] : 0ull;
        int v = (int)(v64 >> 32);
        if (i < NN) {
            float d = (float)(u32)v64 * (1.f / 8388608.f);
            dis[i] = d > 0.f ? rsqrtf(d) : 0.f;
        }
        int x = v;
#pragma unroll
        for (int off = 1; off < 64; off <<= 1) {
            int t = __shfl_up(x, off);
            if (lane >= off) x += t;
        }
        if (lane == 63) wsum[wv] = x;
        __syncthreads();
        if (tid < 16) {
            int s = wsum[tid];
#pragma unroll
            for (int off = 1; off < 16; off <<= 1) {
                int t = __shfl_up(s, off, 16);
                if (tid >= off) s += t;
            }
            wsum[tid] = s;
        }
        __syncthreads();
        int base = carry + (wv > 0 ? wsum[wv - 1] : 0);
        if (i < NN) offs[i] = base + x - v;
        __syncthreads();
        if (tid == 0) carry += wsum[15];
        __syncthreads();
    }
    if (tid == 0) offs[NN] = carry;
}

// CSR scatter: fused (col, norm) uint2 metadata — one 8B load per edge in prop.
__global__ __launch_bounds__(256) void k_csr(const int* __restrict__ ei, const float* __restrict__ ewf,
                                             const float* __restrict__ dis, const int* __restrict__ offs,
                                             int* __restrict__ cursor, uint2* __restrict__ csr_meta) {
    int e = blockIdx.x * 256 + threadIdx.x;
    int r = ei[e], c = ei[EE + e];
    float wgt = ewf[e];
    int pos = offs[r] + atomicAdd(cursor + r, 1);
    float nrm = -dis[r] * wgt * dis[c];
    csr_meta[pos] = make_uint2((u32)c, __builtin_bit_cast(u32, nrm));
}

// Propagation over bf16 node features, fp32 accumulate. One wave per node.
// depth-1 csr_meta software pipeline (R4).
template <int F>
__global__ __launch_bounds__(256) void k_prop(const u16* __restrict__ src, const uint2* __restrict__ csr_meta,
                                              const int* __restrict__ offs,
                                              u16* __restrict__ out, const u16* __restrict__ base,
                                              float alpha, float beta) {
    int lane = threadIdx.x & 63;
    int wv = threadIdx.x >> 6;
    int node = blockIdx.x * 4 + wv;
    int s = offs[node], e = offs[node + 1];

    if (F == 128) {
        int sub = lane >> 4;   // which of 4 edges this lane group handles
        int fl = lane & 15;    // position within the feature row
        const uint4* sv = (const uint4*)src;  // row = 16 uint4 (128 bf16)
        float a[8] = {0, 0, 0, 0, 0, 0, 0, 0};
        int p = s;
        if (p + 7 < e) {
            uint2 m0 = csr_meta[p + sub];
            uint2 m1 = csr_meta[p + 4 + sub];
            while (true) {
                uint4 v0 = sv[(size_t)m0.x * 16 + fl];
                uint4 v1 = sv[(size_t)m1.x * 16 + fl];
                float w0 = __builtin_bit_cast(float, m0.y);
                float w1 = __builtin_bit_cast(float, m1.y);
                p += 8;
                bool more = (p + 7 < e);
                if (more) {
                    m0 = csr_meta[p + sub];
                    m1 = csr_meta[p + 4 + sub];
                }
                a[0] = fmaf(w0, bfl(v0.x), a[0]); a[1] = fmaf(w0, bfh(v0.x), a[1]);
                a[2] = fmaf(w0, bfl(v0.y), a[2]); a[3] = fmaf(w0, bfh(v0.y), a[3]);
                a[4] = fmaf(w0, bfl(v0.z), a[4]); a[5] = fmaf(w0, bfh(v0.z), a[5]);
                a[6] = fmaf(w0, bfl(v0.w), a[6]); a[7] = fmaf(w0, bfh(v0.w), a[7]);
                a[0] = fmaf(w1, bfl(v1.x), a[0]); a[1] = fmaf(w1, bfh(v1.x), a[1]);
                a[2] = fmaf(w1, bfl(v1.y), a[2]); a[3] = fmaf(w1, bfh(v1.y), a[3]);
                a[4] = fmaf(w1, bfl(v1.z), a[4]); a[5] = fmaf(w1, bfh(v1.z), a[5]);
                a[6] = fmaf(w1, bfl(v1.w), a[6]); a[7] = fmaf(w1, bfh(v1.w), a[7]);
                if (!more) break;
            }
        }
        if (p + 3 < e) {
            uint2 m0 = csr_meta[p + sub];
            uint4 v0 = sv[(size_t)m0.x * 16 + fl];
            float w0 = __builtin_bit_cast(float, m0.y);
            a[0] = fmaf(w0, bfl(v0.x), a[0]); a[1] = fmaf(w0, bfh(v0.x), a[1]);
            a[2] = fmaf(w0, bfl(v0.y), a[2]); a[3] = fmaf(w0, bfh(v0.y), a[3]);
            a[4] = fmaf(w0, bfl(v0.z), a[4]); a[5] = fmaf(w0, bfh(v0.z), a[5]);
            a[6] = fmaf(w0, bfl(v0.w), a[6]); a[7] = fmaf(w0, bfh(v0.w), a[7]);
            p += 4;
        }
#pragma unroll
        for (int i = 0; i < 8; i++) {
            a[i] += __shfl_xor(a[i], 16);
            a[i] += __shfl_xor(a[i], 32);
        }
        if (sub == 0) {
            for (; p < e; p++) {
                uint2 m0 = csr_meta[p];
                uint4 v = sv[(size_t)m0.x * 16 + fl];
                float w = __builtin_bit_cast(float, m0.y);
                a[0] = fmaf(w, bfl(v.x), a[0]); a[1] = fmaf(w, bfh(v.x), a[1]);
                a[2] = fmaf(w, bfl(v.y), a[2]); a[3] = fmaf(w, bfh(v.y), a[3]);
                a[4] = fmaf(w, bfl(v.z), a[4]); a[5] = fmaf(w, bfh(v.z), a[5]);
                a[6] = fmaf(w, bfl(v.w), a[6]); a[7] = fmaf(w, bfh(v.w), a[7]);
            }
            float o[8];
#pragma unroll
            for (int i = 0; i < 8; i++) o[i] = alpha * a[i];
            if (beta != 0.f) {
                uint4 bv = ((const uint4*)base)[(size_t)node * 16 + fl];
                o[0] = fmaf(beta, bfl(bv.x), o[0]); o[1] = fmaf(beta, bfh(bv.x), o[1]);
                o[2] = fmaf(beta, bfl(bv.y), o[2]); o[3] = fmaf(beta, bfh(bv.y), o[3]);
                o[4] = fmaf(beta, bfl(bv.z), o[4]); o[5] = fmaf(beta, bfh(bv.z), o[5]);
                o[6] = fmaf(beta, bfl(bv.w), o[6]); o[7] = fmaf(beta, bfh(bv.w), o[7]);
            }
            uint4 ov;
            ov.x = (u32)f2bf(o[0]) | ((u32)f2bf(o[1]) << 16);
            ov.y = (u32)f2bf(o[2]) | ((u32)f2bf(o[3]) << 16);
            ov.z = (u32)f2bf(o[4]) | ((u32)f2bf(o[5]) << 16);
            ov.w = (u32)f2bf(o[6]) | ((u32)f2bf(o[7]) << 16);
            ((uint4*)out)[(size_t)node * 16 + fl] = ov;
        }
    } else {
        int sub = lane >> 3;   // which of 8 edges this lane group handles
        int fl = lane & 7;     // position within the feature row (uint4 units)
        const uint4* sv = (const uint4*)src;  // row = 8 uint4 (64 bf16)
        float a[8] = {0, 0, 0, 0, 0, 0, 0, 0};
        int p = s;
        if (p + 15 < e) {
            uint2 m0 = csr_meta[p + sub];
            uint2 m1 = csr_meta[p + 8 + sub];
            while (true) {
                uint4 v0 = sv[(size_t)m0.x * 8 + fl];
                uint4 v1 = sv[(size_t)m1.x * 8 + fl];
                float w0 = __builtin_bit_cast(float, m0.y);
                float w1 = __builtin_bit_cast(float, m1.y);
                p += 16;
                bool more = (p + 15 < e);
                if (more) {
                    m0 = csr_meta[p + sub];
                    m1 = csr_meta[p + 8 + sub];
                }
                a[0] = fmaf(w0, bfl(v0.x), a[0]); a[1] = fmaf(w0, bfh(v0.x), a[1]);
                a[2] = fmaf(w0, bfl(v0.y), a[2]); a[3] = fmaf(w0, bfh(v0.y), a[3]);
                a[4] = fmaf(w0, bfl(v0.z), a[4]); a[5] = fmaf(w0, bfh(v0.z), a[5]);
                a[6] = fmaf(w0, bfl(v0.w), a[6]); a[7] = fmaf(w0, bfh(v0.w), a[7]);
                a[0] = fmaf(w1, bfl(v1.x), a[0]); a[1] = fmaf(w1, bfh(v1.x), a[1]);
                a[2] = fmaf(w1, bfl(v1.y), a[2]); a[3] = fmaf(w1, bfh(v1.y), a[3]);
                a[4] = fmaf(w1, bfl(v1.z), a[4]); a[5] = fmaf(w1, bfh(v1.z), a[5]);
                a[6] = fmaf(w1, bfl(v1.w), a[6]); a[7] = fmaf(w1, bfh(v1.w), a[7]);
                if (!more) break;
            }
        }
        if (p + 7 < e) {
            uint2 m0 = csr_meta[p + sub];
            uint4 v0 = sv[(size_t)m0.x * 8 + fl];
            float w0 = __builtin_bit_cast(float, m0.y);
            a[0] = fmaf(w0, bfl(v0.x), a[0]); a[1] = fmaf(w0, bfh(v0.x), a[1]);
            a[2] = fmaf(w0, bfl(v0.y), a[2]); a[3] = fmaf(w0, bfh(v0.y), a[3]);
            a[4] = fmaf(w0, bfl(v0.z), a[4]); a[5] = fmaf(w0, bfh(v0.z), a[5]);
            a[6] = fmaf(w0, bfl(v0.w), a[6]); a[7] = fmaf(w0, bfh(v0.w), a[7]);
            p += 8;
        }
#pragma unroll
        for (int i = 0; i < 8; i++) {
            a[i] += __shfl_xor(a[i], 8);
            a[i] += __shfl_xor(a[i], 16);
            a[i] += __shfl_xor(a[i], 32);
        }
        if (sub == 0) {
            for (; p < e; p++) {
                uint2 m0 = csr_meta[p];
                uint4 v = sv[(size_t)m0.x * 8 + fl];
                float w = __builtin_bit_cast(float, m0.y);
                a[0] = fmaf(w, bfl(v.x), a[0]); a[1] = fmaf(w, bfh(v.x), a[1]);
                a[2] = fmaf(w, bfl(v.y), a[2]); a[3] = fmaf(w, bfh(v.y), a[3]);
                a[4] = fmaf(w, bfl(v.z), a[4]); a[5] = fmaf(w, bfh(v.z), a[5]);
                a[6] = fmaf(w, bfl(v.w), a[6]); a[7] = fmaf(w, bfh(v.w), a[7]);
            }
            float o[8];
#pragma unroll
            for (int i = 0; i < 8; i++) o[i] = alpha * a[i];
            if (beta != 0.f) {
                uint4 bv = ((const uint4*)base)[(size_t)node * 8 + fl];
                o[0] = fmaf(beta, bfl(bv.x), o[0]); o[1] = fmaf(beta, bfh(bv.x), o[1]);
                o[2] = fmaf(beta, bfl(bv.y), o[2]); o[3] = fmaf(beta, bfh(bv.y), o[3]);
                o[4] = fmaf(beta, bfl(bv.z), o[4]); o[5] = fmaf(beta, bfh(bv.z), o[5]);
                o[6] = fmaf(beta, bfl(bv.w), o[6]); o[7] = fmaf(beta, bfh(bv.w), o[7]);
            }
            uint4 ov;
            ov.x = (u32)f2bf(o[0]) | ((u32)f2bf(o[1]) << 16);
            ov.y = (u32)f2bf(o[2]) | ((u32)f2bf(o[3]) << 16);
            ov.z = (u32)f2bf(o[4]) | ((u32)f2bf(o[5]) << 16);
            ov.w = (u32)f2bf(o[6]) | ((u32)f2bf(o[7]) << 16);
            ((uint4*)out)[(size_t)node * 8 + fl] = ov;
        }
    }
}

// ChebConv mix via MFMA -> bf16 h + jk slice (out dtype).
template <int F>
__global__ __launch_bounds__(256) void k_gemm(const u16* __restrict__ X0, const u16* __restrict__ X1,
                                              const u16* __restrict__ X2, const u16* __restrict__ Wf,
                                              u16* __restrict__ Hout, void* __restrict__ jk, int jkoff,
                                              const int* __restrict__ flag) {
    constexpr int KT = (3 * F) / 32;  // 12 (F=128) or 6 (F=64)
    __shared__ __align__(16) u16 sB[KT * 4 * 64 * 8];
    int tid = threadIdx.x;
    for (int i = tid; i < KT * 4 * 64 * 4; i += 256) ((u32*)sB)[i] = ((const u32*)Wf)[i];
    __syncthreads();

    bool isbf = flag[0] != 0;
    int wv = __builtin_amdgcn_readfirstlane(tid >> 6);
    int lane = tid & 63;
    int quad = lane >> 4, jc = lane & 15;
    int pair = wv >> 1;   // row group
    int half = wv & 1;    // column half (32 cols)
    int nb = blockIdx.x * 32 + pair * 16;
    int row = nb + jc;
    if (row > NN - 1) row = NN - 1;

    // prefetch all A-fragments (row = lane&15, k = kt*32 + quad*8 + j)
    uint4 av[KT];
#pragma unroll
    for (int kt = 0; kt < KT; kt++) {
        int kg = kt * 32 + quad * 8;
        const u16* Xp;
        int kk;
        if (kg < F) { Xp = X0; kk = kg; }
        else if (kg < 2 * F) { Xp = X1; kk = kg - F; }
        else { Xp = X2; kk = kg - 2 * F; }
        av[kt] = *(const uint4*)(Xp + (size_t)row * F + kk);
    }

    f32x4 acc0 = {0.f, 0.f, 0.f, 0.f}, acc1 = {0.f, 0.f, 0.f, 0.f};
#pragma unroll
    for (int kt = 0; kt < KT; kt++) {
        bf16x8 af = __builtin_bit_cast(bf16x8, av[kt]);
        bf16x8 b0 = *reinterpret_cast<const bf16x8*>(&sB[((kt * 4 + half * 2 + 0) * 64 + lane) * 8]);
        bf16x8 b1 = *reinterpret_cast<const bf16x8*>(&sB[((kt * 4 + half * 2 + 1) * 64 + lane) * 8]);
        acc0 = __builtin_amdgcn_mfma_f32_16x16x32_bf16(af, b0, acc0, 0, 0, 0);
        acc1 = __builtin_amdgcn_mfma_f32_16x16x32_bf16(af, b1, acc1, 0, 0, 0);
    }

#pragma unroll
    for (int ct = 0; ct < 2; ct++) {
        f32x4 a = ct ? acc1 : acc0;
        int j = (half * 2 + ct) * 16 + jc;
#pragma unroll
        for (int r = 0; r < 4; r++) {
            int n = nb + quad * 4 + r;
            if (n < NN) {
                float v = fmaxf(a[r], 0.f);
                Hout[(size_t)n * 64 + j] = f2bf(v);
                if (isbf) ((u16*)jk)[(size_t)n * 256 + jkoff + j] = f2bf(v);
                else ((float*)jk)[(size_t)n * 256 + jkoff + j] = v;
            }
        }
    }
}

// Fused classifier: logit = (relu(jk@W1+b1)*s+t)@w2 + b2, z never materialized.
__global__ __launch_bounds__(256) void k_cls(const u16* __restrict__ h0, const u16* __restrict__ h1,
                                             const u16* __restrict__ h2, const u16* __restrict__ h3,
                                             const u16* __restrict__ W1c, const float* __restrict__ wpad,
                                             const float* __restrict__ w2p, const float* __restrict__ b2p2,
                                             const int* __restrict__ flag, void* __restrict__ dout) {
    __shared__ __align__(16) u16 sB[16384];  // one phase slice of W1c (32KB)
    __shared__ float sb1[256];
    __shared__ float sw2[512];
    __shared__ float sb2[2];
    __shared__ float part[4][16][2];
    int tid = threadIdx.x;
    if (tid < 256) sb1[tid] = wpad[OCB1 + tid];
    for (int i = tid; i < 512; i += 256) sw2[i] = w2p[i];
    if (tid < 2) sb2[tid] = b2p2[tid];

    int wv = __builtin_amdgcn_readfirstlane(tid >> 6);
    int lane = tid & 63;
    int quad = lane >> 4, jc = lane & 15;
    int pair = wv >> 1;      // row group (0/1)
    int half = wv & 1;       // column half (0/1)
    int nb = blockIdx.x * 32 + pair * 16;

    f32x4 acc[8] = {{0.f, 0.f, 0.f, 0.f}, {0.f, 0.f, 0.f, 0.f}, {0.f, 0.f, 0.f, 0.f}, {0.f, 0.f, 0.f, 0.f},
                    {0.f, 0.f, 0.f, 0.f}, {0.f, 0.f, 0.f, 0.f}, {0.f, 0.f, 0.f, 0.f}, {0.f, 0.f, 0.f, 0.f}};
    const u16* hs[4] = {h0, h1, h2, h3};

    int row = nb + jc;
    if (row > NN - 1) row = NN - 1;

#pragma unroll 1
    for (int l = 0; l < 4; l++) {
        __syncthreads();
        const u32* src = (const u32*)W1c + l * 8192;
        for (int i = tid; i < 8192; i += 256) ((u32*)sB)[i] = src[i];
        __syncthreads();
        const uint4* rp = (const uint4*)(hs[l] + (size_t)row * 64);
        uint4 a0u = rp[quad], a1u = rp[4 + quad];
        bf16x8 af0 = __builtin_bit_cast(bf16x8, a0u);
        bf16x8 af1 = __builtin_bit_cast(bf16x8, a1u);
#pragma unroll
        for (int jt = 0; jt < 8; jt++) {
            int ct = half * 8 + jt;
            bf16x8 b0 = *reinterpret_cast<const bf16x8*>(&sB[((0 * 16 + ct) * 64 + lane) * 8]);
            bf16x8 b1f = *reinterpret_cast<const bf16x8*>(&sB[((1 * 16 + ct) * 64 + lane) * 8]);
            acc[jt] = __builtin_amdgcn_mfma_f32_16x16x32_bf16(af0, b0, acc[jt], 0, 0, 0);
            acc[jt] = __builtin_amdgcn_mfma_f32_16x16x32_bf16(af1, b1f, acc[jt], 0, 0, 0);
        }
    }

    // epilogue: relu(acc+b1) dot w2' -> per-row logit partials
    float p0[4] = {0, 0, 0, 0}, p1[4] = {0, 0, 0, 0};
#pragma unroll
    for (int jt = 0; jt < 8; jt++) {
        int j = (half * 8 + jt) * 16 + jc;
        float b1v = sb1[j], wa = sw2[2 * j], wb = sw2[2 * j + 1];
#pragma unroll
        for (int r = 0; r < 4; r++) {
            float h = fmaxf(acc[jt][r] + b1v, 0.f);
            p0[r] = fmaf(h, wa, p0[r]);
            p1[r] = fmaf(h, wb, p1[r]);
        }
    }
#pragma unroll
    for (int off = 1; off < 16; off <<= 1) {
#pragma unroll
        for (int r = 0; r < 4; r++) {
            p0[r] += __shfl_xor(p0[r], off);
            p1[r] += __shfl_xor(p1[r], off);
        }
    }
    if (jc == 0) {
#pragma unroll
        for (int r = 0; r < 4; r++) {
            part[wv][quad * 4 + r][0] = p0[r];
            part[wv][quad * 4 + r][1] = p1[r];
        }
    }
    __syncthreads();
    if (tid < 32) {
        int rl = tid & 15, p = tid >> 4;
        int n = blockIdx.x * 32 + tid;
        if (n < NN) {
            float l0 = part[2 * p][rl][0] + part[2 * p + 1][rl][0] + sb2[0];
            float l1 = part[2 * p][rl][1] + part[2 * p + 1][rl][1] + sb2[1];
            if (flag[0] != 0) {
                u32 pack = (u32)f2bf(l0) | ((u32)f2bf(l1) << 16);
                *(u32*)((u16*)dout + LG_OFF + (size_t)n * 2) = pack;
            } else {
                float2 o = {l0, l1};
                *(float2*)((float*)dout + LG_OFF + (size_t)n * 2) = o;
            }
        }
    }
}

extern "C" void kernel_launch(void* const* d_in, const int* in_sizes, int n_in,
                              void* d_out, int out_size, void* d_ws, size_t ws_size,
                              hipStream_t stream) {
    const void* features = d_in[0];
    const int* ei = (const int*)d_in[1];
    const void* zin = d_in[2];

    char* w = (char*)d_ws;
    auto alloc = [&](size_t bytes) -> void* {
        void* p = (void*)w;
        w += (bytes + 255) & ~(size_t)255;
        return p;
    };
    u16* X0 = (u16*)alloc((size_t)NN * 128 * 2);
    u16* Tx1 = (u16*)alloc((size_t)NN * 128 * 2);
    u16* Tx2 = (u16*)alloc((size_t)NN * 128 * 2);
    u16* h0 = (u16*)alloc((size_t)NN * 64 * 2);
    u16* h1 = (u16*)alloc((size_t)NN * 64 * 2);
    u16* h2 = (u16*)alloc((size_t)NN * 64 * 2);
    u16* h3 = (u16*)alloc((size_t)NN * 64 * 2);
    float* ewf = (float*)alloc((size_t)EE * 4);
    uint2* csr_meta = (uint2*)alloc((size_t)EE * 8);
    u64* dc = (u64*)alloc((size_t)NN * 8);       // packed (cnt<<32 | deg fixed-point)
    int* cursor = (int*)alloc((size_t)NN * 4);
    float* dis = (float*)alloc((size_t)NN * 4);
    int* offs = (int*)alloc((size_t)(NN + 1) * 4);
    u16* W2s = (u16*)alloc((size_t)16384 * 2);
    float* b2p = (float*)alloc((size_t)128 * 4);
    u16* W1c = (u16*)alloc((size_t)65536 * 2);
    float* w2p = (float*)alloc((size_t)512 * 4);
    float* b2p2 = (float*)alloc((size_t)2 * 4);
    u16* Wf0 = (u16*)alloc((size_t)24576 * 2);
    u16* Wf1 = (u16*)alloc((size_t)12288 * 2);
    u16* Wf2 = (u16*)alloc((size_t)12288 * 2);
    u16* Wf3 = (u16*)alloc((size_t)12288 * 2);
    float* wpad = (float*)alloc((size_t)OTOT * 4);
    int* flag = (int*)alloc(256);

    // zero dc + cursor (contiguous allocations)
    hipMemsetAsync(dc, 0, (size_t)((char*)dis - (char*)dc), stream);

    PtrTab tab;
    for (int i = 0; i < 20; i++) tab.p[i] = d_in[3 + i];

    k_detect<<<1, 256, 0, stream>>>((const u16*)features, flag);
    k_wconv<<<20, 256, 0, stream>>>(tab, flag, wpad);
    k_fold<<<33, 128, 0, stream>>>(wpad, W2s, b2p);
    k_foldc<<<65, 256, 0, stream>>>(wpad, W1c, w2p, b2p2);
    k_foldw<<<60, 256, 0, stream>>>(wpad, Wf0, Wf1, Wf2, Wf3);
    k_x0<<<3125, 256, 0, stream>>>(features, flag, X0);
    // 768 blocks = 256 CU x 3 resident blocks (measured optimum; 4/CU regressed
    // via atomic cacheline contention, R3)
    k_pae<<<768, 256, 0, stream>>>(zin, wpad, W2s, b2p, ei, flag, ewf, d_out, dc);
    k_scan<<<1, 1024, 0, stream>>>(dc, offs, dis);
    k_csr<<<EE / 256, 256, 0, stream>>>(ei, ewf, dis, offs, cursor, csr_meta);

    // layer 0 (F=128)
    k_prop<128><<<12500, 256, 0, stream>>>(X0, csr_meta, offs, Tx1, nullptr, 1.f, 0.f);
    k_prop<128><<<12500, 256, 0, stream>>>(Tx1, csr_meta, offs, Tx2, X0, 2.f, -1.f);
    k_gemm<128><<<1563, 256, 0, stream>>>(X0, Tx1, Tx2, Wf0, h0, d_out, 0, flag);
    // layer 1 (F=64)
    k_prop<64><<<12500, 256, 0, stream>>>(h0, csr_meta, offs, Tx1, nullptr, 1.f, 0.f);
    k_prop<64><<<12500, 256, 0, stream>>>(Tx1, csr_meta, offs, Tx2, h0, 2.f, -1.f);
    k_gemm<64><<<1563, 256, 0, stream>>>(h0, Tx1, Tx2, Wf1, h1, d_out, 64, flag);
    // layer 2
    k_prop<64><<<12500, 256, 0, stream>>>(h1, csr_meta, offs, Tx1, nullptr, 1.f, 0.f);
    k_prop<64><<<12500, 256, 0, stream>>>(Tx1, csr_meta, offs, Tx2, h1, 2.f, -1.f);
    k_gemm<64><<<1563, 256, 0, stream>>>(h1, Tx1, Tx2, Wf2, h2, d_out, 128, flag);
    // layer 3
    k_prop<64><<<12500, 256, 0, stream>>>(h2, csr_meta, offs, Tx1, nullptr, 1.f, 0.f);
    k_prop<64><<<12500, 256, 0, stream>>>(Tx1, csr_meta, offs, Tx2, h2, 2.f, -1.f);
    k_gemm<64><<<1563, 256, 0, stream>>>(h2, Tx1, Tx2, Wf3, h3, d_out, 192, flag);

    // fused classifier (z never materialized)
    k_cls<<<1563, 256, 0, stream>>>(h0, h1, h2, h3, W1c, wpad, w2p, b2p2, flag, d_out);
    (void)in_sizes; (void)n_in; (void)out_size; (void)ws_size;
}

// Round 6
// 978.512 us; speedup vs baseline: 1.9761x; 1.0329x over previous
//
#include <hip/hip_runtime.h>

#define NN 50000
#define EE 1600000

using u16 = unsigned short;
using u32 = unsigned int;
using u64 = unsigned long long;

typedef float f32x4 __attribute__((ext_vector_type(4)));
typedef __bf16 bf16x8 __attribute__((ext_vector_type(8)));
typedef unsigned short u16x8 __attribute__((ext_vector_type(8)));

struct alignas(8) U16x4 { u16 a, b, c, d; };
struct PtrTab { const void* p[20]; };

// canonical fp32 weight-pad offsets
#define OW1 0
#define OB1 768
#define OG 896
#define OBB 1024
#define ORM 1152
#define ORV 1280
#define OW2 1408
#define OB2 17792
#define OCH0 17920
#define OCH1 42496
#define OCH2 54784
#define OCH3 67072
#define OCW1 79360
#define OCB1 144896
#define OCG 145152
#define OCBB 145408
#define OCRM 145664
#define OCRV 145920
#define OCW2 146176
#define OCB2 146688
#define OTOT 146690

// element offsets within d_out (dtype-independent in elements)
#define LG_OFF ((size_t)NN * 256)
#define EW_OFF ((size_t)NN * 256 + (size_t)NN * 2)

__device__ __forceinline__ float bf2f(u16 u) { return __builtin_bit_cast(float, (u32)u << 16); }
__device__ __forceinline__ float bfl(u32 u) { return __builtin_bit_cast(float, u << 16); }
__device__ __forceinline__ float bfh(u32 u) { return __builtin_bit_cast(float, u & 0xffff0000u); }
__device__ __forceinline__ u16 f2bf(float f) {
    u32 u = __builtin_bit_cast(u32, f);
    return (u16)((u + 0x7fffu + ((u >> 16) & 1u)) >> 16);
}

// Input dtype detector: flag=1 -> bf16 inputs, 0 -> fp32 inputs.
__global__ __launch_bounds__(256) void k_detect(const u16* __restrict__ f, int* __restrict__ flag) {
    __shared__ int bad;
    if (threadIdx.x == 0) bad = 0;
    __syncthreads();
    u16 u = f[threadIdx.x];
    int e = (u >> 7) & 0xFF;
    if (e >= 0x90) atomicAdd(&bad, 1);
    __syncthreads();
    if (threadIdx.x == 0) flag[0] = (bad < 16) ? 1 : 0;
}

// Convert all 20 weight arrays into canonical fp32 pad.
__global__ __launch_bounds__(256) void k_wconv(PtrTab tab, const int* __restrict__ flag,
                                               float* __restrict__ wpad) {
    const int SZ[20] = {768, 128, 128, 128, 128, 128, 16384, 128, 24576, 12288, 12288, 12288,
                        65536, 256, 256, 256, 256, 256, 512, 2};
    const int OF[20] = {OW1, OB1, OG, OBB, ORM, ORV, OW2, OB2, OCH0, OCH1, OCH2, OCH3,
                        OCW1, OCB1, OCG, OCBB, OCRM, OCRV, OCW2, OCB2};
    int a = blockIdx.x;
    int n = SZ[a];
    float* dst = wpad + OF[a];
    if (flag[0] != 0) {
        const u16* s = (const u16*)tab.p[a];
        for (int i = threadIdx.x; i < n; i += 256) dst[i] = bf2f(s[i]);
    } else {
        const float* s = (const float*)tab.p[a];
        for (int i = threadIdx.x; i < n; i += 256) dst[i] = s[i];
    }
}

// Fold PAE BN into W2 (MFMA B-frag swizzled bf16) + b2'.
// v6: k-row PERMUTATION changed to match the stage-1 MFMA output order in
// k_pae: slot (q, j) of chunk kc now holds k = kc*32 + (j<4 ? 4q+j : 16+4q+j-4)
// (was kc*32 + 8q + j). The second-stage contraction sums over all 32 k's of
// the chunk, so any bijective slot->k map is valid as long as A and B agree.
__global__ __launch_bounds__(128) void k_fold(const float* __restrict__ wpad,
                                              u16* __restrict__ W2s, float* __restrict__ b2p) {
    const float* g = wpad + OG;
    const float* b = wpad + OBB;
    const float* rm = wpad + ORM;
    const float* rv = wpad + ORV;
    const float* w2 = wpad + OW2;
    const float* b2 = wpad + OB2;
    int blk = blockIdx.x, tid = threadIdx.x;
    if (blk < 32) {
        int kc = blk >> 3, jt = blk & 7;
        int lane = tid & 63, jh = tid >> 6;
        int q = lane >> 4;
        for (int jj = 0; jj < 4; jj++) {
            int j = jh * 4 + jj;
            int k = kc * 32 + ((j < 4) ? (q * 4 + j) : (16 + q * 4 + (j - 4)));
            int jcol = jt * 16 + (lane & 15);
            float s = g[k] * rsqrtf(rv[k] + 1e-5f);
            W2s[((kc * 8 + jt) * 64 + lane) * 8 + j] = f2bf(s * w2[k * 128 + jcol]);
        }
    } else {
        if (tid < 128) {
            int j = tid;
            float acc = b2[j];
            for (int k = 0; k < 128; k++) {
                float s = g[k] * rsqrtf(rv[k] + 1e-5f);
                float t = b[k] - rm[k] * s;
                acc += t * w2[k * 128 + j];
            }
            b2p[j] = acc;
        }
    }
}

// Fold classifier weights: W1c = cls_w1 as MFMA B-fragments (bf16, phase-sliced),
// w2p[j][c] = s_j * cls_w2[j][c], b2p2[c] = cls_b2[c] + sum_j t_j * cls_w2[j][c].
__global__ __launch_bounds__(256) void k_foldc(const float* __restrict__ wpad,
                                               u16* __restrict__ W1c, float* __restrict__ w2p,
                                               float* __restrict__ b2p2) {
    int tid = threadIdx.x;
    if (blockIdx.x < 64) {
        const float* w1 = wpad + OCW1;
        int base = blockIdx.x * 1024 + tid * 4;
#pragma unroll
        for (int u = 0; u < 4; u++) {
            int gi = base + u;
            int j = gi & 7;
            int lane = (gi >> 3) & 63;
            int ct = (gi >> 9) & 15;
            int kc2 = (gi >> 13) & 1;
            int l = gi >> 14;
            int k = l * 64 + kc2 * 32 + ((lane >> 4) & 3) * 8 + j;
            int col = ct * 16 + (lane & 15);
            W1c[gi] = f2bf(w1[k * 256 + col]);
        }
    } else {
        __shared__ float red[8];
        int j = tid;
        float s = wpad[OCG + j] * rsqrtf(wpad[OCRV + j] + 1e-5f);
        float t = wpad[OCBB + j] - wpad[OCRM + j] * s;
        float w0 = wpad[OCW2 + j * 2], w1v = wpad[OCW2 + j * 2 + 1];
        w2p[j * 2] = s * w0;
        w2p[j * 2 + 1] = s * w1v;
        float c0 = t * w0, c1 = t * w1v;
#pragma unroll
        for (int off = 1; off < 64; off <<= 1) {
            c0 += __shfl_xor(c0, off);
            c1 += __shfl_xor(c1, off);
        }
        int wv = tid >> 6, lane = tid & 63;
        if (lane == 0) { red[wv * 2] = c0; red[wv * 2 + 1] = c1; }
        __syncthreads();
        if (tid == 0) b2p2[0] = wpad[OCB2] + red[0] + red[2] + red[4] + red[6];
        if (tid == 1) b2p2[1] = wpad[OCB2 + 1] + red[1] + red[3] + red[5] + red[7];
    }
}

// Fold ChebConv weights into MFMA B-fragment order (bf16).
__global__ __launch_bounds__(256) void k_foldw(const float* __restrict__ wpad,
                                               u16* __restrict__ Wf0, u16* __restrict__ Wf1,
                                               u16* __restrict__ Wf2, u16* __restrict__ Wf3) {
    int b = blockIdx.x, tid = threadIdx.x;
    const float* src;
    u16* dst;
    int nkt;
    if (b < 24)      { src = wpad + OCH0; dst = Wf0; nkt = 12; }
    else if (b < 36) { src = wpad + OCH1; dst = Wf1; b -= 24; nkt = 6; }
    else if (b < 48) { src = wpad + OCH2; dst = Wf2; b -= 36; nkt = 6; }
    else             { src = wpad + OCH3; dst = Wf3; b -= 48; nkt = 6; }
    int base = b * 1024 + tid * 4;
#pragma unroll
    for (int u = 0; u < 4; u++) {
        int gi = base + u;
        int jj = gi & 7;
        int lane = (gi >> 3) & 63;
        int ct = (gi >> 9) & 3;
        int kt = gi >> 11;
        if (kt < nkt) {
            int k = kt * 32 + ((lane >> 4) & 3) * 8 + jj;
            int col = ct * 16 + (lane & 15);
            dst[gi] = f2bf(src[k * 64 + col]);
        }
    }
}

// features (either dtype) -> bf16 X0.
__global__ __launch_bounds__(256) void k_x0(const void* __restrict__ feat, const int* __restrict__ flag,
                                            u16* __restrict__ X0) {
    int i = blockIdx.x * 256 + threadIdx.x;
    if (flag[0] != 0) {
        ((uint4*)X0)[i] = ((const uint4*)feat)[i];
    } else {
        const float4* f = (const float4*)feat;
        float4 a = f[2 * i], b = f[2 * i + 1];
        u16x8 o;
        o[0] = f2bf(a.x); o[1] = f2bf(a.y); o[2] = f2bf(a.z); o[3] = f2bf(a.w);
        o[4] = f2bf(b.x); o[5] = f2bf(b.y); o[6] = f2bf(b.z); o[7] = f2bf(b.w);
        ((uint4*)X0)[i] = __builtin_bit_cast(uint4, o);
    }
}

// PAE, v6: BOTH layers on MFMA.
// Stage 1: C[kout][edge] = W1^T Z^T + b1 via 8 mfma_16x16x32 per encoding:
//   A-frag = W1 tile (row=kout via lane&15; K=6 padded to 32, quads 1-3 zero;
//   loop-invariant, built once into 8 uint4). B-frag = z (col=edge via
//   lane&15, quad 0 slots 0..5, else zero). C-init = b1 broadcast (bias free).
// Output layout: lane (q,e) holds kout = {32kc+4q+r, 32kc+16+4q+r} -- a
// PERMUTED k-order. No lane exchange: k_fold permutes W2s rows identically
// (kappa(kc,q,j)), and sum_k h[k]w2[k] is order-invariant.
// Replaces 384 scalar fma + 64 ds_read_b128 per group with 16 MFMA + ~100 VALU.
// Grid stays 768 = 3 blocks/CU (4/CU regressed, R3); u64 deg|cnt atomic (R5).
__global__ __launch_bounds__(256, 3) void k_pae(const void* __restrict__ zin, const float* __restrict__ wpad,
                                                const u16* __restrict__ W2sg, const float* __restrict__ b2p,
                                                const int* __restrict__ ei, const int* __restrict__ flag,
                                                float* __restrict__ ewf, void* __restrict__ dout,
                                                u64* __restrict__ dc) {
    __shared__ __align__(16) u16 sW2[16384];
    __shared__ float sB2[128];
    int tid = threadIdx.x;
    for (int i = tid; i < 8192; i += 256) ((u32*)sW2)[i] = ((const u32*)W2sg)[i];
    if (tid < 128) sB2[tid] = b2p[tid];
    __syncthreads();

    bool isbf = flag[0] != 0;
    int wv = __builtin_amdgcn_readfirstlane(tid >> 6);
    int lane = tid & 63;
    int quad = lane >> 4, lrow = lane & 15, jc = lane & 15;
    u32 qm = (quad == 0) ? 0xffffffffu : 0u;  // B-frag mask: only quad 0 supplies z

    // loop-invariant stage-1 operands: W1 A-frags (8 tiles) + b1 C-inits
    uint4 w1f[8];
    f32x4 cb[8];
#pragma unroll
    for (int kt = 0; kt < 8; kt++) {
        u32 a = 0, b = 0, c = 0;
        if (quad == 0) {
            int col = kt * 16 + lrow;
            a = (u32)f2bf(wpad[OW1 + 0 * 128 + col]) | ((u32)f2bf(wpad[OW1 + 1 * 128 + col]) << 16);
            b = (u32)f2bf(wpad[OW1 + 2 * 128 + col]) | ((u32)f2bf(wpad[OW1 + 3 * 128 + col]) << 16);
            c = (u32)f2bf(wpad[OW1 + 4 * 128 + col]) | ((u32)f2bf(wpad[OW1 + 5 * 128 + col]) << 16);
        }
        w1f[kt] = (uint4){a, b, c, 0u};
#pragma unroll
        for (int r = 0; r < 4; r++) cb[kt][r] = wpad[OB1 + kt * 16 + quad * 4 + r];
    }

    int gw = blockIdx.x * 4 + wv;
    const int ngroups = EE / 16;
    const int gstep = gridDim.x * 4;

    uint2 pb0, pb1, pb2;       // bf16 Z prefetch (24B row)
    float4 pf0, pf1, pf2;      // fp32 Z prefetch (48B row)
    if (gw < ngroups) {
        if (isbf) {
            const uint2* zp = (const uint2*)((const u16*)zin + (size_t)(gw * 16 + lrow) * 12);
            pb0 = zp[0]; pb1 = zp[1]; pb2 = zp[2];
        } else {
            const float4* zp = (const float4*)((const float*)zin + (size_t)(gw * 16 + lrow) * 12);
            pf0 = zp[0]; pf1 = zp[1]; pf2 = zp[2];
        }
    }

#pragma unroll 1
    for (int gidx = gw; gidx < ngroups; gidx += gstep) {
        int e0 = gidx * 16;
        float z1[6], z2[6];
        if (isbf) {
            z1[0] = bfl(pb0.x); z1[1] = bfh(pb0.x); z1[2] = bfl(pb0.y); z1[3] = bfh(pb0.y);
            z1[4] = bfl(pb1.x); z1[5] = bfh(pb1.x);
            z2[0] = bfl(pb1.y); z2[1] = bfh(pb1.y); z2[2] = bfl(pb2.x); z2[3] = bfh(pb2.x);
            z2[4] = bfl(pb2.y); z2[5] = bfh(pb2.y);
        } else {
            z1[0] = pf0.x; z1[1] = pf0.y; z1[2] = pf0.z; z1[3] = pf0.w; z1[4] = pf1.x; z1[5] = pf1.y;
            z2[0] = pf1.z; z2[1] = pf1.w; z2[2] = pf2.x; z2[3] = pf2.y; z2[4] = pf2.z; z2[5] = pf2.w;
        }
        // issue next group's Z loads now -- they complete under this group's compute
        int gn = gidx + gstep;
        if (gn < ngroups) {
            if (isbf) {
                const uint2* zp = (const uint2*)((const u16*)zin + (size_t)(gn * 16 + lrow) * 12);
                pb0 = zp[0]; pb1 = zp[1]; pb2 = zp[2];
            } else {
                const float4* zp = (const float4*)((const float*)zin + (size_t)(gn * 16 + lrow) * 12);
                pf0 = zp[0]; pf1 = zp[1]; pf2 = zp[2];
            }
        }
        // hoist epilogue row indices
        int rows[4];
        if (jc == 0) {
#pragma unroll
            for (int r = 0; r < 4; r++) rows[r] = ei[e0 + quad * 4 + r];
        }

        // build z B-frags (quad 0 only; lossless round-trip for bf16 inputs)
        u32 za0, za1, za2, zb0, zb1, zb2;
        asm("v_cvt_pk_bf16_f32 %0, %1, %2" : "=v"(za0) : "v"(z1[0]), "v"(z1[1]));
        asm("v_cvt_pk_bf16_f32 %0, %1, %2" : "=v"(za1) : "v"(z1[2]), "v"(z1[3]));
        asm("v_cvt_pk_bf16_f32 %0, %1, %2" : "=v"(za2) : "v"(z1[4]), "v"(z1[5]));
        asm("v_cvt_pk_bf16_f32 %0, %1, %2" : "=v"(zb0) : "v"(z2[0]), "v"(z2[1]));
        asm("v_cvt_pk_bf16_f32 %0, %1, %2" : "=v"(zb1) : "v"(z2[2]), "v"(z2[3]));
        asm("v_cvt_pk_bf16_f32 %0, %1, %2" : "=v"(zb2) : "v"(z2[4]), "v"(z2[5]));
        uint4 zu1 = {za0 & qm, za1 & qm, za2 & qm, 0u};
        uint4 zu2 = {zb0 & qm, zb1 & qm, zb2 & qm, 0u};
        bf16x8 zf1 = __builtin_bit_cast(bf16x8, zu1);
        bf16x8 zf2 = __builtin_bit_cast(bf16x8, zu2);

        // stage 1 + pack, encoding 1
        bf16x8 a1f[4], a2f[4];
        {
            f32x4 c1[8];
#pragma unroll
            for (int kt = 0; kt < 8; kt++)
                c1[kt] = __builtin_amdgcn_mfma_f32_16x16x32_bf16(
                    __builtin_bit_cast(bf16x8, w1f[kt]), zf1, cb[kt], 0, 0, 0);
#pragma unroll
            for (int kc = 0; kc < 4; kc++) {
                float h0 = fmaxf(c1[2 * kc][0], 0.f), h1 = fmaxf(c1[2 * kc][1], 0.f);
                float h2 = fmaxf(c1[2 * kc][2], 0.f), h3 = fmaxf(c1[2 * kc][3], 0.f);
                float h4 = fmaxf(c1[2 * kc + 1][0], 0.f), h5 = fmaxf(c1[2 * kc + 1][1], 0.f);
                float h6 = fmaxf(c1[2 * kc + 1][2], 0.f), h7 = fmaxf(c1[2 * kc + 1][3], 0.f);
                u32 p0, p1, p2, p3;
                asm("v_cvt_pk_bf16_f32 %0, %1, %2" : "=v"(p0) : "v"(h0), "v"(h1));
                asm("v_cvt_pk_bf16_f32 %0, %1, %2" : "=v"(p1) : "v"(h2), "v"(h3));
                asm("v_cvt_pk_bf16_f32 %0, %1, %2" : "=v"(p2) : "v"(h4), "v"(h5));
                asm("v_cvt_pk_bf16_f32 %0, %1, %2" : "=v"(p3) : "v"(h6), "v"(h7));
                uint4 au = {p0, p1, p2, p3};
                a1f[kc] = __builtin_bit_cast(bf16x8, au);
            }
        }
        // stage 1 + pack, encoding 2
        {
            f32x4 c2[8];
#pragma unroll
            for (int kt = 0; kt < 8; kt++)
                c2[kt] = __builtin_amdgcn_mfma_f32_16x16x32_bf16(
                    __builtin_bit_cast(bf16x8, w1f[kt]), zf2, cb[kt], 0, 0, 0);
#pragma unroll
            for (int kc = 0; kc < 4; kc++) {
                float h0 = fmaxf(c2[2 * kc][0], 0.f), h1 = fmaxf(c2[2 * kc][1], 0.f);
                float h2 = fmaxf(c2[2 * kc][2], 0.f), h3 = fmaxf(c2[2 * kc][3], 0.f);
                float h4 = fmaxf(c2[2 * kc + 1][0], 0.f), h5 = fmaxf(c2[2 * kc + 1][1], 0.f);
                float h6 = fmaxf(c2[2 * kc + 1][2], 0.f), h7 = fmaxf(c2[2 * kc + 1][3], 0.f);
                u32 p0, p1, p2, p3;
                asm("v_cvt_pk_bf16_f32 %0, %1, %2" : "=v"(p0) : "v"(h0), "v"(h1));
                asm("v_cvt_pk_bf16_f32 %0, %1, %2" : "=v"(p1) : "v"(h2), "v"(h3));
                asm("v_cvt_pk_bf16_f32 %0, %1, %2" : "=v"(p2) : "v"(h4), "v"(h5));
                asm("v_cvt_pk_bf16_f32 %0, %1, %2" : "=v"(p3) : "v"(h6), "v"(h7));
                uint4 au = {p0, p1, p2, p3};
                a2f[kc] = __builtin_bit_cast(bf16x8, au);
            }
        }

        float num[4] = {0, 0, 0, 0}, q1[4] = {0, 0, 0, 0}, q2[4] = {0, 0, 0, 0};
        // jt NOT unrolled: keeps ds_read hoisting bounded (spill guard).
#pragma unroll 1
        for (int jt = 0; jt < 8; jt++) {
            f32x4 acc1 = {0.f, 0.f, 0.f, 0.f}, acc2 = {0.f, 0.f, 0.f, 0.f};
#pragma unroll
            for (int kc = 0; kc < 4; kc++) {
                bf16x8 bb = *reinterpret_cast<const bf16x8*>(&sW2[((kc * 8 + jt) * 64 + lane) * 8]);
                acc1 = __builtin_amdgcn_mfma_f32_16x16x32_bf16(a1f[kc], bb, acc1, 0, 0, 0);
                acc2 = __builtin_amdgcn_mfma_f32_16x16x32_bf16(a2f[kc], bb, acc2, 0, 0, 0);
            }
            float bbias = sB2[jt * 16 + jc];
#pragma unroll
            for (int r = 0; r < 4; r++) {
                float h1 = acc1[r] + bbias;
                float h2 = acc2[r] + bbias;
                num[r] = fmaf(h1, h2, num[r]);
                q1[r] = fmaf(h1, h1, q1[r]);
                q2[r] = fmaf(h2, h2, q2[r]);
            }
        }
#pragma unroll
        for (int off = 1; off < 16; off <<= 1) {
#pragma unroll
            for (int r = 0; r < 4; r++) {
                num[r] += __shfl_xor(num[r], off);
                q1[r] += __shfl_xor(q1[r], off);
                q2[r] += __shfl_xor(q2[r], off);
            }
        }
        if (jc == 0) {
#pragma unroll
            for (int r = 0; r < 4; r++) {
                int e = e0 + quad * 4 + r;
                float den = fmaxf(sqrtf(q1[r]) * sqrtf(q2[r]), 1e-8f);
                float wgt = (num[r] / den + 1.f) * 0.5f;
                if (!(wgt == wgt)) wgt = 0.5f;  // NaN guard: makes failures localizable
                ewf[e] = wgt;
                if (isbf) ((u16*)dout)[EW_OFF + e] = f2bf(wgt);
                else ((float*)dout)[EW_OFF + e] = wgt;
                // one u64 atomic: hi32 = count(+1), lo32 = wgt in 8.23 fixed point
                u32 fx = (u32)(wgt * 8388608.f + 0.5f);
                atomicAdd(dc + rows[r], (((u64)1) << 32) | (u64)fx);
            }
        }
    }
}

// Exclusive scan of cnt (hi32 of dc) -> offs; fused dis = rsqrt(deg) with
// deg = lo32 of dc * 2^-23.
__global__ __launch_bounds__(1024) void k_scan(const u64* __restrict__ dc,
                                               int* __restrict__ offs, float* __restrict__ dis) {
    __shared__ int wsum[16];
    __shared__ int carry;
    int tid = threadIdx.x;
    int wv = tid >> 6, lane = tid & 63;
    if (tid == 0) carry = 0;
    __syncthreads();
    for (int c = 0; c < 49; c++) {
        int i = c * 1024 + tid;
        u64 v64 = (i < NN) ? dc[i] : 0ull;
        int v = (int)(v64 >> 32);
        if (i < NN) {
            float d = (float)(u32)v64 * (1.f / 8388608.f);
            dis[i] = d > 0.f ? rsqrtf(d) : 0.f;
        }
        int x = v;
#pragma unroll
        for (int off = 1; off < 64; off <<= 1) {
            int t = __shfl_up(x, off);
            if (lane >= off) x += t;
        }
        if (lane == 63) wsum[wv] = x;
        __syncthreads();
        if (tid < 16) {
            int s = wsum[tid];
#pragma unroll
            for (int off = 1; off < 16; off <<= 1) {
                int t = __shfl_up(s, off, 16);
                if (tid >= off) s += t;
            }
            wsum[tid] = s;
        }
        __syncthreads();
        int base = carry + (wv > 0 ? wsum[wv - 1] : 0);
        if (i < NN) offs[i] = base + x - v;
        __syncthreads();
        if (tid == 0) carry += wsum[15];
        __syncthreads();
    }
    if (tid == 0) offs[NN] = carry;
}

// CSR scatter: fused (col, norm) uint2 metadata — one 8B load per edge in prop.
__global__ __launch_bounds__(256) void k_csr(const int* __restrict__ ei, const float* __restrict__ ewf,
                                             const float* __restrict__ dis, const int* __restrict__ offs,
                                             int* __restrict__ cursor, uint2* __restrict__ csr_meta) {
    int e = blockIdx.x * 256 + threadIdx.x;
    int r = ei[e], c = ei[EE + e];
    float wgt = ewf[e];
    int pos = offs[r] + atomicAdd(cursor + r, 1);
    float nrm = -dis[r] * wgt * dis[c];
    csr_meta[pos] = make_uint2((u32)c, __builtin_bit_cast(u32, nrm));
}

// Propagation over bf16 node features, fp32 accumulate. One wave per node.
// depth-1 csr_meta software pipeline (R4).
template <int F>
__global__ __launch_bounds__(256) void k_prop(const u16* __restrict__ src, const uint2* __restrict__ csr_meta,
                                              const int* __restrict__ offs,
                                              u16* __restrict__ out, const u16* __restrict__ base,
                                              float alpha, float beta) {
    int lane = threadIdx.x & 63;
    int wv = threadIdx.x >> 6;
    int node = blockIdx.x * 4 + wv;
    int s = offs[node], e = offs[node + 1];

    if (F == 128) {
        int sub = lane >> 4;   // which of 4 edges this lane group handles
        int fl = lane & 15;    // position within the feature row
        const uint4* sv = (const uint4*)src;  // row = 16 uint4 (128 bf16)
        float a[8] = {0, 0, 0, 0, 0, 0, 0, 0};
        int p = s;
        if (p + 7 < e) {
            uint2 m0 = csr_meta[p + sub];
            uint2 m1 = csr_meta[p + 4 + sub];
            while (true) {
                uint4 v0 = sv[(size_t)m0.x * 16 + fl];
                uint4 v1 = sv[(size_t)m1.x * 16 + fl];
                float w0 = __builtin_bit_cast(float, m0.y);
                float w1 = __builtin_bit_cast(float, m1.y);
                p += 8;
                bool more = (p + 7 < e);
                if (more) {
                    m0 = csr_meta[p + sub];
                    m1 = csr_meta[p + 4 + sub];
                }
                a[0] = fmaf(w0, bfl(v0.x), a[0]); a[1] = fmaf(w0, bfh(v0.x), a[1]);
                a[2] = fmaf(w0, bfl(v0.y), a[2]); a[3] = fmaf(w0, bfh(v0.y), a[3]);
                a[4] = fmaf(w0, bfl(v0.z), a[4]); a[5] = fmaf(w0, bfh(v0.z), a[5]);
                a[6] = fmaf(w0, bfl(v0.w), a[6]); a[7] = fmaf(w0, bfh(v0.w), a[7]);
                a[0] = fmaf(w1, bfl(v1.x), a[0]); a[1] = fmaf(w1, bfh(v1.x), a[1]);
                a[2] = fmaf(w1, bfl(v1.y), a[2]); a[3] = fmaf(w1, bfh(v1.y), a[3]);
                a[4] = fmaf(w1, bfl(v1.z), a[4]); a[5] = fmaf(w1, bfh(v1.z), a[5]);
                a[6] = fmaf(w1, bfl(v1.w), a[6]); a[7] = fmaf(w1, bfh(v1.w), a[7]);
                if (!more) break;
            }
        }
        if (p + 3 < e) {
            uint2 m0 = csr_meta[p + sub];
            uint4 v0 = sv[(size_t)m0.x * 16 + fl];
            float w0 = __builtin_bit_cast(float, m0.y);
            a[0] = fmaf(w0, bfl(v0.x), a[0]); a[1] = fmaf(w0, bfh(v0.x), a[1]);
            a[2] = fmaf(w0, bfl(v0.y), a[2]); a[3] = fmaf(w0, bfh(v0.y), a[3]);
            a[4] = fmaf(w0, bfl(v0.z), a[4]); a[5] = fmaf(w0, bfh(v0.z), a[5]);
            a[6] = fmaf(w0, bfl(v0.w), a[6]); a[7] = fmaf(w0, bfh(v0.w), a[7]);
            p += 4;
        }
#pragma unroll
        for (int i = 0; i < 8; i++) {
            a[i] += __shfl_xor(a[i], 16);
            a[i] += __shfl_xor(a[i], 32);
        }
        if (sub == 0) {
            for (; p < e; p++) {
                uint2 m0 = csr_meta[p];
                uint4 v = sv[(size_t)m0.x * 16 + fl];
                float w = __builtin_bit_cast(float, m0.y);
                a[0] = fmaf(w, bfl(v.x), a[0]); a[1] = fmaf(w, bfh(v.x), a[1]);
                a[2] = fmaf(w, bfl(v.y), a[2]); a[3] = fmaf(w, bfh(v.y), a[3]);
                a[4] = fmaf(w, bfl(v.z), a[4]); a[5] = fmaf(w, bfh(v.z), a[5]);
                a[6] = fmaf(w, bfl(v.w), a[6]); a[7] = fmaf(w, bfh(v.w), a[7]);
            }
            float o[8];
#pragma unroll
            for (int i = 0; i < 8; i++) o[i] = alpha * a[i];
            if (beta != 0.f) {
                uint4 bv = ((const uint4*)base)[(size_t)node * 16 + fl];
                o[0] = fmaf(beta, bfl(bv.x), o[0]); o[1] = fmaf(beta, bfh(bv.x), o[1]);
                o[2] = fmaf(beta, bfl(bv.y), o[2]); o[3] = fmaf(beta, bfh(bv.y), o[3]);
                o[4] = fmaf(beta, bfl(bv.z), o[4]); o[5] = fmaf(beta, bfh(bv.z), o[5]);
                o[6] = fmaf(beta, bfl(bv.w), o[6]); o[7] = fmaf(beta, bfh(bv.w), o[7]);
            }
            uint4 ov;
            ov.x = (u32)f2bf(o[0]) | ((u32)f2bf(o[1]) << 16);
            ov.y = (u32)f2bf(o[2]) | ((u32)f2bf(o[3]) << 16);
            ov.z = (u32)f2bf(o[4]) | ((u32)f2bf(o[5]) << 16);
            ov.w = (u32)f2bf(o[6]) | ((u32)f2bf(o[7]) << 16);
            ((uint4*)out)[(size_t)node * 16 + fl] = ov;
        }
    } else {
        int sub = lane >> 3;   // which of 8 edges this lane group handles
        int fl = lane & 7;     // position within the feature row (uint4 units)
        const uint4* sv = (const uint4*)src;  // row = 8 uint4 (64 bf16)
        float a[8] = {0, 0, 0, 0, 0, 0, 0, 0};
        int p = s;
        if (p + 15 < e) {
            uint2 m0 = csr_meta[p + sub];
            uint2 m1 = csr_meta[p + 8 + sub];
            while (true) {
                uint4 v0 = sv[(size_t)m0.x * 8 + fl];
                uint4 v1 = sv[(size_t)m1.x * 8 + fl];
                float w0 = __builtin_bit_cast(float, m0.y);
                float w1 = __builtin_bit_cast(float, m1.y);
                p += 16;
                bool more = (p + 15 < e);
                if (more) {
                    m0 = csr_meta[p + sub];
                    m1 = csr_meta[p + 8 + sub];
                }
                a[0] = fmaf(w0, bfl(v0.x), a[0]); a[1] = fmaf(w0, bfh(v0.x), a[1]);
                a[2] = fmaf(w0, bfl(v0.y), a[2]); a[3] = fmaf(w0, bfh(v0.y), a[3]);
                a[4] = fmaf(w0, bfl(v0.z), a[4]); a[5] = fmaf(w0, bfh(v0.z), a[5]);
                a[6] = fmaf(w0, bfl(v0.w), a[6]); a[7] = fmaf(w0, bfh(v0.w), a[7]);
                a[0] = fmaf(w1, bfl(v1.x), a[0]); a[1] = fmaf(w1, bfh(v1.x), a[1]);
                a[2] = fmaf(w1, bfl(v1.y), a[2]); a[3] = fmaf(w1, bfh(v1.y), a[3]);
                a[4] = fmaf(w1, bfl(v1.z), a[4]); a[5] = fmaf(w1, bfh(v1.z), a[5]);
                a[6] = fmaf(w1, bfl(v1.w), a[6]); a[7] = fmaf(w1, bfh(v1.w), a[7]);
                if (!more) break;
            }
        }
        if (p + 7 < e) {
            uint2 m0 = csr_meta[p + sub];
            uint4 v0 = sv[(size_t)m0.x * 8 + fl];
            float w0 = __builtin_bit_cast(float, m0.y);
            a[0] = fmaf(w0, bfl(v0.x), a[0]); a[1] = fmaf(w0, bfh(v0.x), a[1]);
            a[2] = fmaf(w0, bfl(v0.y), a[2]); a[3] = fmaf(w0, bfh(v0.y), a[3]);
            a[4] = fmaf(w0, bfl(v0.z), a[4]); a[5] = fmaf(w0, bfh(v0.z), a[5]);
            a[6] = fmaf(w0, bfl(v0.w), a[6]); a[7] = fmaf(w0, bfh(v0.w), a[7]);
            p += 8;
        }
#pragma unroll
        for (int i = 0; i < 8; i++) {
            a[i] += __shfl_xor(a[i], 8);
            a[i] += __shfl_xor(a[i], 16);
            a[i] += __shfl_xor(a[i], 32);
        }
        if (sub == 0) {
            for (; p < e; p++) {
                uint2 m0 = csr_meta[p];
                uint4 v = sv[(size_t)m0.x * 8 + fl];
                float w = __builtin_bit_cast(float, m0.y);
                a[0] = fmaf(w, bfl(v.x), a[0]); a[1] = fmaf(w, bfh(v.x), a[1]);
                a[2] = fmaf(w, bfl(v.y), a[2]); a[3] = fmaf(w, bfh(v.y), a[3]);
                a[4] = fmaf(w, bfl(v.z), a[4]); a[5] = fmaf(w, bfh(v.z), a[5]);
                a[6] = fmaf(w, bfl(v.w), a[6]); a[7] = fmaf(w, bfh(v.w), a[7]);
            }
            float o[8];
#pragma unroll
            for (int i = 0; i < 8; i++) o[i] = alpha * a[i];
            if (beta != 0.f) {
                uint4 bv = ((const uint4*)base)[(size_t)node * 8 + fl];
                o[0] = fmaf(beta, bfl(bv.x), o[0]); o[1] = fmaf(beta, bfh(bv.x), o[1]);
                o[2] = fmaf(beta, bfl(bv.y), o[2]); o[3] = fmaf(beta, bfh(bv.y), o[3]);
                o[4] = fmaf(beta, bfl(bv.z), o[4]); o[5] = fmaf(beta, bfh(bv.z), o[5]);
                o[6] = fmaf(beta, bfl(bv.w), o[6]); o[7] = fmaf(beta, bfh(bv.w), o[7]);
            }
            uint4 ov;
            ov.x = (u32)f2bf(o[0]) | ((u32)f2bf(o[1]) << 16);
            ov.y = (u32)f2bf(o[2]) | ((u32)f2bf(o[3]) << 16);
            ov.z = (u32)f2bf(o[4]) | ((u32)f2bf(o[5]) << 16);
            ov.w = (u32)f2bf(o[6]) | ((u32)f2bf(o[7]) << 16);
            ((uint4*)out)[(size_t)node * 8 + fl] = ov;
        }
    }
}

// ChebConv mix via MFMA -> bf16 h + jk slice (out dtype).
template <int F>
__global__ __launch_bounds__(256) void k_gemm(const u16* __restrict__ X0, const u16* __restrict__ X1,
                                              const u16* __restrict__ X2, const u16* __restrict__ Wf,
                                              u16* __restrict__ Hout, void* __restrict__ jk, int jkoff,
                                              const int* __restrict__ flag) {
    constexpr int KT = (3 * F) / 32;  // 12 (F=128) or 6 (F=64)
    __shared__ __align__(16) u16 sB[KT * 4 * 64 * 8];
    int tid = threadIdx.x;
    for (int i = tid; i < KT * 4 * 64 * 4; i += 256) ((u32*)sB)[i] = ((const u32*)Wf)[i];
    __syncthreads();

    bool isbf = flag[0] != 0;
    int wv = __builtin_amdgcn_readfirstlane(tid >> 6);
    int lane = tid & 63;
    int quad = lane >> 4, jc = lane & 15;
    int pair = wv >> 1;   // row group
    int half = wv & 1;    // column half (32 cols)
    int nb = blockIdx.x * 32 + pair * 16;
    int row = nb + jc;
    if (row > NN - 1) row = NN - 1;

    // prefetch all A-fragments (row = lane&15, k = kt*32 + quad*8 + j)
    uint4 av[KT];
#pragma unroll
    for (int kt = 0; kt < KT; kt++) {
        int kg = kt * 32 + quad * 8;
        const u16* Xp;
        int kk;
        if (kg < F) { Xp = X0; kk = kg; }
        else if (kg < 2 * F) { Xp = X1; kk = kg - F; }
        else { Xp = X2; kk = kg - 2 * F; }
        av[kt] = *(const uint4*)(Xp + (size_t)row * F + kk);
    }

    f32x4 acc0 = {0.f, 0.f, 0.f, 0.f}, acc1 = {0.f, 0.f, 0.f, 0.f};
#pragma unroll
    for (int kt = 0; kt < KT; kt++) {
        bf16x8 af = __builtin_bit_cast(bf16x8, av[kt]);
        bf16x8 b0 = *reinterpret_cast<const bf16x8*>(&sB[((kt * 4 + half * 2 + 0) * 64 + lane) * 8]);
        bf16x8 b1 = *reinterpret_cast<const bf16x8*>(&sB[((kt * 4 + half * 2 + 1) * 64 + lane) * 8]);
        acc0 = __builtin_amdgcn_mfma_f32_16x16x32_bf16(af, b0, acc0, 0, 0, 0);
        acc1 = __builtin_amdgcn_mfma_f32_16x16x32_bf16(af, b1, acc1, 0, 0, 0);
    }

#pragma unroll
    for (int ct = 0; ct < 2; ct++) {
        f32x4 a = ct ? acc1 : acc0;
        int j = (half * 2 + ct) * 16 + jc;
#pragma unroll
        for (int r = 0; r < 4; r++) {
            int n = nb + quad * 4 + r;
            if (n < NN) {
                float v = fmaxf(a[r], 0.f);
                Hout[(size_t)n * 64 + j] = f2bf(v);
                if (isbf) ((u16*)jk)[(size_t)n * 256 + jkoff + j] = f2bf(v);
                else ((float*)jk)[(size_t)n * 256 + jkoff + j] = v;
            }
        }
    }
}

// Fused classifier: logit = (relu(jk@W1+b1)*s+t)@w2 + b2, z never materialized.
__global__ __launch_bounds__(256) void k_cls(const u16* __restrict__ h0, const u16* __restrict__ h1,
                                             const u16* __restrict__ h2, const u16* __restrict__ h3,
                                             const u16* __restrict__ W1c, const float* __restrict__ wpad,
                                             const float* __restrict__ w2p, const float* __restrict__ b2p2,
                                             const int* __restrict__ flag, void* __restrict__ dout) {
    __shared__ __align__(16) u16 sB[16384];  // one phase slice of W1c (32KB)
    __shared__ float sb1[256];
    __shared__ float sw2[512];
    __shared__ float sb2[2];
    __shared__ float part[4][16][2];
    int tid = threadIdx.x;
    if (tid < 256) sb1[tid] = wpad[OCB1 + tid];
    for (int i = tid; i < 512; i += 256) sw2[i] = w2p[i];
    if (tid < 2) sb2[tid] = b2p2[tid];

    int wv = __builtin_amdgcn_readfirstlane(tid >> 6);
    int lane = tid & 63;
    int quad = lane >> 4, jc = lane & 15;
    int pair = wv >> 1;      // row group (0/1)
    int half = wv & 1;       // column half (0/1)
    int nb = blockIdx.x * 32 + pair * 16;

    f32x4 acc[8] = {{0.f, 0.f, 0.f, 0.f}, {0.f, 0.f, 0.f, 0.f}, {0.f, 0.f, 0.f, 0.f}, {0.f, 0.f, 0.f, 0.f},
                    {0.f, 0.f, 0.f, 0.f}, {0.f, 0.f, 0.f, 0.f}, {0.f, 0.f, 0.f, 0.f}, {0.f, 0.f, 0.f, 0.f}};
    const u16* hs[4] = {h0, h1, h2, h3};

    int row = nb + jc;
    if (row > NN - 1) row = NN - 1;

#pragma unroll 1
    for (int l = 0; l < 4; l++) {
        __syncthreads();
        const u32* src = (const u32*)W1c + l * 8192;
        for (int i = tid; i < 8192; i += 256) ((u32*)sB)[i] = src[i];
        __syncthreads();
        const uint4* rp = (const uint4*)(hs[l] + (size_t)row * 64);
        uint4 a0u = rp[quad], a1u = rp[4 + quad];
        bf16x8 af0 = __builtin_bit_cast(bf16x8, a0u);
        bf16x8 af1 = __builtin_bit_cast(bf16x8, a1u);
#pragma unroll
        for (int jt = 0; jt < 8; jt++) {
            int ct = half * 8 + jt;
            bf16x8 b0 = *reinterpret_cast<const bf16x8*>(&sB[((0 * 16 + ct) * 64 + lane) * 8]);
            bf16x8 b1f = *reinterpret_cast<const bf16x8*>(&sB[((1 * 16 + ct) * 64 + lane) * 8]);
            acc[jt] = __builtin_amdgcn_mfma_f32_16x16x32_bf16(af0, b0, acc[jt], 0, 0, 0);
            acc[jt] = __builtin_amdgcn_mfma_f32_16x16x32_bf16(af1, b1f, acc[jt], 0, 0, 0);
        }
    }

    // epilogue: relu(acc+b1) dot w2' -> per-row logit partials
    float p0[4] = {0, 0, 0, 0}, p1[4] = {0, 0, 0, 0};
#pragma unroll
    for (int jt = 0; jt < 8; jt++) {
        int j = (half * 8 + jt) * 16 + jc;
        float b1v = sb1[j], wa = sw2[2 * j], wb = sw2[2 * j + 1];
#pragma unroll
        for (int r = 0; r < 4; r++) {
            float h = fmaxf(acc[jt][r] + b1v, 0.f);
            p0[r] = fmaf(h, wa, p0[r]);
            p1[r] = fmaf(h, wb, p1[r]);
        }
    }
#pragma unroll
    for (int off = 1; off < 16; off <<= 1) {
#pragma unroll
        for (int r = 0; r < 4; r++) {
            p0[r] += __shfl_xor(p0[r], off);
            p1[r] += __shfl_xor(p1[r], off);
        }
    }
    if (jc == 0) {
#pragma unroll
        for (int r = 0; r < 4; r++) {
            part[wv][quad * 4 + r][0] = p0[r];
            part[wv][quad * 4 + r][1] = p1[r];
        }
    }
    __syncthreads();
    if (tid < 32) {
        int rl = tid & 15, p = tid >> 4;
        int n = blockIdx.x * 32 + tid;
        if (n < NN) {
            float l0 = part[2 * p][rl][0] + part[2 * p + 1][rl][0] + sb2[0];
            float l1 = part[2 * p][rl][1] + part[2 * p + 1][rl][1] + sb2[1];
            if (flag[0] != 0) {
                u32 pack = (u32)f2bf(l0) | ((u32)f2bf(l1) << 16);
                *(u32*)((u16*)dout + LG_OFF + (size_t)n * 2) = pack;
            } else {
                float2 o = {l0, l1};
                *(float2*)((float*)dout + LG_OFF + (size_t)n * 2) = o;
            }
        }
    }
}

extern "C" void kernel_launch(void* const* d_in, const int* in_sizes, int n_in,
                              void* d_out, int out_size, void* d_ws, size_t ws_size,
                              hipStream_t stream) {
    const void* features = d_in[0];
    const int* ei = (const int*)d_in[1];
    const void* zin = d_in[2];

    char* w = (char*)d_ws;
    auto alloc = [&](size_t bytes) -> void* {
        void* p = (void*)w;
        w += (bytes + 255) & ~(size_t)255;
        return p;
    };
    u16* X0 = (u16*)alloc((size_t)NN * 128 * 2);
    u16* Tx1 = (u16*)alloc((size_t)NN * 128 * 2);
    u16* Tx2 = (u16*)alloc((size_t)NN * 128 * 2);
    u16* h0 = (u16*)alloc((size_t)NN * 64 * 2);
    u16* h1 = (u16*)alloc((size_t)NN * 64 * 2);
    u16* h2 = (u16*)alloc((size_t)NN * 64 * 2);
    u16* h3 = (u16*)alloc((size_t)NN * 64 * 2);
    float* ewf = (float*)alloc((size_t)EE * 4);
    uint2* csr_meta = (uint2*)alloc((size_t)EE * 8);
    u64* dc = (u64*)alloc((size_t)NN * 8);       // packed (cnt<<32 | deg fixed-point)
    int* cursor = (int*)alloc((size_t)NN * 4);
    float* dis = (float*)alloc((size_t)NN * 4);
    int* offs = (int*)alloc((size_t)(NN + 1) * 4);
    u16* W2s = (u16*)alloc((size_t)16384 * 2);
    float* b2p = (float*)alloc((size_t)128 * 4);
    u16* W1c = (u16*)alloc((size_t)65536 * 2);
    float* w2p = (float*)alloc((size_t)512 * 4);
    float* b2p2 = (float*)alloc((size_t)2 * 4);
    u16* Wf0 = (u16*)alloc((size_t)24576 * 2);
    u16* Wf1 = (u16*)alloc((size_t)12288 * 2);
    u16* Wf2 = (u16*)alloc((size_t)12288 * 2);
    u16* Wf3 = (u16*)alloc((size_t)12288 * 2);
    float* wpad = (float*)alloc((size_t)OTOT * 4);
    int* flag = (int*)alloc(256);

    // zero dc + cursor (contiguous allocations)
    hipMemsetAsync(dc, 0, (size_t)((char*)dis - (char*)dc), stream);

    PtrTab tab;
    for (int i = 0; i < 20; i++) tab.p[i] = d_in[3 + i];

    k_detect<<<1, 256, 0, stream>>>((const u16*)features, flag);
    k_wconv<<<20, 256, 0, stream>>>(tab, flag, wpad);
    k_fold<<<33, 128, 0, stream>>>(wpad, W2s, b2p);
    k_foldc<<<65, 256, 0, stream>>>(wpad, W1c, w2p, b2p2);
    k_foldw<<<60, 256, 0, stream>>>(wpad, Wf0, Wf1, Wf2, Wf3);
    k_x0<<<3125, 256, 0, stream>>>(features, flag, X0);
    // 768 blocks = 256 CU x 3 resident blocks (measured optimum; 4/CU regressed
    // via atomic cacheline contention, R3)
    k_pae<<<768, 256, 0, stream>>>(zin, wpad, W2s, b2p, ei, flag, ewf, d_out, dc);
    k_scan<<<1, 1024, 0, stream>>>(dc, offs, dis);
    k_csr<<<EE / 256, 256, 0, stream>>>(ei, ewf, dis, offs, cursor, csr_meta);

    // layer 0 (F=128)
    k_prop<128><<<12500, 256, 0, stream>>>(X0, csr_meta, offs, Tx1, nullptr, 1.f, 0.f);
    k_prop<128><<<12500, 256, 0, stream>>>(Tx1, csr_meta, offs, Tx2, X0, 2.f, -1.f);
    k_gemm<128><<<1563, 256, 0, stream>>>(X0, Tx1, Tx2, Wf0, h0, d_out, 0, flag);
    // layer 1 (F=64)
    k_prop<64><<<12500, 256, 0, stream>>>(h0, csr_meta, offs, Tx1, nullptr, 1.f, 0.f);
    k_prop<64><<<12500, 256, 0, stream>>>(Tx1, csr_meta, offs, Tx2, h0, 2.f, -1.f);
    k_gemm<64><<<1563, 256, 0, stream>>>(h0, Tx1, Tx2, Wf1, h1, d_out, 64, flag);
    // layer 2
    k_prop<64><<<12500, 256, 0, stream>>>(h1, csr_meta, offs, Tx1, nullptr, 1.f, 0.f);
    k_prop<64><<<12500, 256, 0, stream>>>(Tx1, csr_meta, offs, Tx2, h1, 2.f, -1.f);
    k_gemm<64><<<1563, 256, 0, stream>>>(h1, Tx1, Tx2, Wf2, h2, d_out, 128, flag);
    // layer 3
    k_prop<64><<<12500, 256, 0, stream>>>(h2, csr_meta, offs, Tx1, nullptr, 1.f, 0.f);
    k_prop<64><<<12500, 256, 0, stream>>>(Tx1, csr_meta, offs, Tx2, h2, 2.f, -1.f);
    k_gemm<64><<<1563, 256, 0, stream>>>(h2, Tx1, Tx2, Wf3, h3, d_out, 192, flag);

    // fused classifier (z never materialized)
    k_cls<<<1563, 256, 0, stream>>>(h0, h1, h2, h3, W1c, wpad, w2p, b2p2, flag, d_out);
    (void)in_sizes; (void)n_in; (void)out_size; (void)ws_size;
}